// Round 3
// baseline (1331.703 us; speedup 1.0000x reference)
//
#include <hip/hip_runtime.h>
#include <cstdint>
#include <cstddef>

#define EPG 160
#define HC  3072
#define DD  1024

typedef _Float16 f16x8 __attribute__((ext_vector_type(8)));
typedef float    f32x4 __attribute__((ext_vector_type(4)));

__device__ __forceinline__ unsigned fenc(float f){
  unsigned u = __float_as_uint(f);
  return (u & 0x80000000u) ? ~u : (u | 0x80000000u);
}
__device__ __forceinline__ float fdec(unsigned u){
  return (u & 0x80000000u) ? __uint_as_float(u ^ 0x80000000u) : __uint_as_float(~u);
}

__device__ __forceinline__ void gload16(const void* g, void* l) {
  __builtin_amdgcn_global_load_lds((const __attribute__((address_space(1))) void*)g,
                                   (__attribute__((address_space(3))) void*)l, 16, 0, 0);
}

// ---------------- weight transpose + fp16 split ----------------
// W[K][Nn] fp32 -> WTh/WTl laid out as [K/32 tiles][Nn rows][32 halfs], where the
// 4 16B-chunks within each 64B row are stored at swizzled position c ^ ((n>>1)&3).
// This matches mfma_gemm's swizzled ds_read while letting global_load_lds write linearly.
__global__ __launch_bounds__(256) void wtrans_kernel(
    const float* __restrict__ W, _Float16* __restrict__ WTh, _Float16* __restrict__ WTl,
    int K, int Nn)
{
  __shared__ float t[32][33];
  const int tx = threadIdx.x, ty = threadIdx.y;
  const int n0 = blockIdx.x * 32, k0 = blockIdx.y * 32;
  #pragma unroll
  for (int i = 0; i < 4; i++) {
    int k = k0 + ty + i * 8;
    t[ty + i * 8][tx] = (k < K) ? W[(size_t)k * Nn + n0 + tx] : 0.f;
  }
  __syncthreads();
  const int kt = k0 >> 5;
  const int c  = tx >> 3;          // chunk of this k within the row
  const int w8 = tx & 7;
  #pragma unroll
  for (int i = 0; i < 4; i++) {
    int n = n0 + ty + i * 8;
    float v = t[tx][ty + i * 8];
    _Float16 h = (_Float16)v;
    float r = v - (float)h;
    int c2 = c ^ ((n >> 1) & 3);
    size_t addr = ((size_t)kt * Nn + n) * 32 + c2 * 8 + w8;
    WTh[addr] = h;
    WTl[addr] = (_Float16)r;
  }
}

// ---------------- split-fp16 MFMA GEMM ----------------
// C[M,N] = A[M,K] @ B[K,N] (+bias), A fp32 (split in regs), B pre-split/transposed.
// Optional fused epilogues: (avs,avd,als,ald) per-row attention dots; (pvec,scv) score dot.
__global__ __launch_bounds__(256) void mfma_gemm(
    const float* __restrict__ A, const _Float16* __restrict__ BTh, const _Float16* __restrict__ BTl,
    const float* __restrict__ bias, float* __restrict__ C,
    int M, int N, int K,
    const float* __restrict__ avs, const float* __restrict__ avd,
    float* __restrict__ als, float* __restrict__ ald,
    const float* __restrict__ pvec, float* __restrict__ scv)
{
  __shared__ _Float16 sAh[128 * 32];
  __shared__ _Float16 sAl[128 * 32];
  __shared__ _Float16 sBh[128 * 32];
  __shared__ _Float16 sBl[128 * 32];

  // ---- XCD-aware remap: co-locate all col-blocks of one row-panel on one XCD ----
  const int gx = N >> 7, gy = M >> 7;
  const int lid = blockIdx.x + gx * blockIdx.y;
  int vx, vy;
  const int G = gy & ~7;
  if (lid < gx * G) {
    const int sub = lid & 7, rest = lid >> 3;
    vx = rest % gx;
    vy = (rest / gx) * 8 + sub;
  } else {
    const int r = lid - gx * G;
    vx = r % gx;
    vy = G + r / gx;
  }
  const int brow = vy << 7, bcol = vx << 7;

  const int tid  = threadIdx.x;
  const int lane = tid & 63;
  const int w    = tid >> 6;
  const int srow = (w << 5) + (lane & 31);   // staging row 0..127
  const int skh  = (lane >> 5) << 4;         // staging k-offset in halfs: 0 or 16
  const int fr   = lane & 15;
  const int g4   = lane >> 4;                // k-group 0..3
  const int wr   = (w >> 1) << 6;
  const int wc   = (w & 1) << 6;

  f32x4 acc[4][4];
  #pragma unroll
  for (int m = 0; m < 4; m++)
    #pragma unroll
    for (int n = 0; n < 4; n++) acc[m][n] = (f32x4)0.0f;

  // precomputed swizzled LDS byte offsets for fragment reads
  int aoff[4], boff[4];
  #pragma unroll
  for (int m = 0; m < 4; m++) {
    int r = wr + m * 16 + fr;
    aoff[m] = r * 64 + ((g4 ^ ((r >> 1) & 3)) << 4);
  }
  #pragma unroll
  for (int n = 0; n < 4; n++) {
    int r = wc + n * 16 + fr;
    boff[n] = r * 64 + ((g4 ^ ((r >> 1) & 3)) << 4);
  }
  // swizzled A staging write positions (chunks c0, c0+1)
  const int c0 = (lane >> 5) << 1;
  const int sw0 = srow * 64 + ((c0 ^ ((srow >> 1) & 3)) << 4);
  const int sw1 = srow * 64 + (((c0 + 1) ^ ((srow >> 1) & 3)) << 4);

  const size_t arow = (size_t)(brow + srow) * K;
  const int ktiles = (K + 31) >> 5;

#define LOADA(dst, k0v)                                                          \
  do {                                                                           \
    if ((k0v) + 32 <= K) {                                                       \
      _Pragma("unroll")                                                          \
      for (int q = 0; q < 4; q++)                                                \
        *(float4*)&dst[q * 4] = *(const float4*)&A[arow + (k0v) + skh + q * 4];  \
    } else {                                                                     \
      _Pragma("unroll")                                                          \
      for (int j = 0; j < 16; j++) {                                             \
        int kk2 = (k0v) + skh + j;                                               \
        dst[j] = (kk2 < K) ? A[arow + kk2] : 0.f;                                \
      }                                                                          \
    }                                                                            \
  } while (0)

  float av[16];
  LOADA(av, 0);

  for (int kt = 0; kt < ktiles; kt++) {
    // ---- split current A regs ----
    f16x8 ah0, ah1, al0, al1;
    #pragma unroll
    for (int j = 0; j < 8; j++) {
      float v  = av[j];
      _Float16 h = (_Float16)v;
      ah0[j] = h; al0[j] = (_Float16)(v - (float)h);
      float v2 = av[j + 8];
      _Float16 h2 = (_Float16)v2;
      ah1[j] = h2; al1[j] = (_Float16)(v2 - (float)h2);
    }

    __syncthreads();   // all waves done reading previous tile

    // ---- B: async global->LDS (pre-swizzled source, linear dest) ----
    {
      const size_t gbase = (((size_t)kt * N + bcol + (w << 5)) << 6);
      const char* gh = (const char*)BTh + gbase + lane * 16;
      const char* gl = (const char*)BTl + gbase + lane * 16;
      char* dh = (char*)sBh + (w << 11);
      char* dl = (char*)sBl + (w << 11);
      gload16(gh,        dh);
      gload16(gh + 1024, dh + 1024);
      gload16(gl,        dl);
      gload16(gl + 1024, dl + 1024);
    }

    // ---- A: swizzled LDS writes ----
    *(f16x8*)((char*)sAh + sw0) = ah0;
    *(f16x8*)((char*)sAh + sw1) = ah1;
    *(f16x8*)((char*)sAl + sw0) = al0;
    *(f16x8*)((char*)sAl + sw1) = al1;

    __syncthreads();   // drains vmcnt (B) + lgkm (A); tile visible

    // ---- prefetch next A tile into regs (hides under MFMA phase) ----
    float av2[16];
    const bool more = (kt + 1 < ktiles);
    if (more) LOADA(av2, (kt + 1) * 32);

    // ---- MFMA: hh + lh + hl ----
    f16x8 bh[4], bl[4];
    #pragma unroll
    for (int n = 0; n < 4; n++) {
      bh[n] = *(const f16x8*)((const char*)sBh + boff[n]);
      bl[n] = *(const f16x8*)((const char*)sBl + boff[n]);
    }
    #pragma unroll
    for (int m = 0; m < 4; m++) {
      const f16x8 ah = *(const f16x8*)((const char*)sAh + aoff[m]);
      const f16x8 al = *(const f16x8*)((const char*)sAl + aoff[m]);
      #pragma unroll
      for (int n = 0; n < 4; n++) {
        acc[m][n] = __builtin_amdgcn_mfma_f32_16x16x32_f16(ah, bh[n], acc[m][n], 0, 0, 0);
        acc[m][n] = __builtin_amdgcn_mfma_f32_16x16x32_f16(al, bh[n], acc[m][n], 0, 0, 0);
        acc[m][n] = __builtin_amdgcn_mfma_f32_16x16x32_f16(ah, bl[n], acc[m][n], 0, 0, 0);
      }
    }
    if (more) {
      #pragma unroll
      for (int j = 0; j < 16; j++) av[j] = av2[j];
    }
  }
#undef LOADA

  // ---- epilogue: C/D layout col=lane&15, row=(lane>>4)*4+q ----
  const int crow0 = brow + wr + g4 * 4;
  const int ccol0 = bcol + wc + fr;
  #pragma unroll
  for (int n = 0; n < 4; n++) {
    const int col = ccol0 + n * 16;
    const float bv = bias ? bias[col] : 0.f;
    #pragma unroll
    for (int m = 0; m < 4; m++) {
      const int row = crow0 + m * 16;
      #pragma unroll
      for (int q = 0; q < 4; q++)
        C[(size_t)(row + q) * N + col] = acc[m][n][q] + bv;
    }
  }

  // ---- fused attention-dot partials (g-GEMMs): als/ald[row][head] ----
  if (als) {
    const int h3 = bcol >> 10;
    #pragma unroll
    for (int m = 0; m < 4; m++) {
      #pragma unroll
      for (int q = 0; q < 4; q++) {
        float ps = 0.f, pd = 0.f;
        #pragma unroll
        for (int n = 0; n < 4; n++) {
          const int col = ccol0 + n * 16;
          const float v = acc[m][n][q];
          ps += v * avs[col]; pd += v * avd[col];
        }
        #pragma unroll
        for (int mk = 1; mk <= 8; mk <<= 1) {
          ps += __shfl_xor(ps, mk);
          pd += __shfl_xor(pd, mk);
        }
        if (fr == 0) {
          const int row = crow0 + m * 16 + q;
          atomicAdd(&als[row * 3 + h3], ps);
          atomicAdd(&ald[row * 3 + h3], pd);
        }
      }
    }
  }
  // ---- fused score-dot partials (t-GEMMs): scv[row] += sum (v+bias)*p[col] ----
  if (scv) {
    #pragma unroll
    for (int m = 0; m < 4; m++) {
      #pragma unroll
      for (int q = 0; q < 4; q++) {
        float pp = 0.f;
        #pragma unroll
        for (int n = 0; n < 4; n++) {
          const int col = ccol0 + n * 16;
          pp += (acc[m][n][q] + bias[col]) * pvec[col];
        }
        #pragma unroll
        for (int mk = 1; mk <= 8; mk <<= 1) pp += __shfl_xor(pp, mk);
        if (fr == 0) atomicAdd(&scv[crow0 + m * 16 + q], pp);
      }
    }
  }
}

// ---------------- fp32 SGEMM (head l1 GEMM only) ----------------
__global__ __launch_bounds__(256) void sgemm_kernel(
    const float* __restrict__ A, const float* __restrict__ B,
    const float* __restrict__ bias, float* __restrict__ C,
    int M, int N, int K, int relu)
{
  __shared__ float As[16][132];
  __shared__ float Bs[16][132];
  const int tid  = threadIdx.x;
  const int brow = blockIdx.y * 128;
  const int bcol = blockIdx.x * 128;
  const int trow = (tid >> 4) * 8;
  const int tcol = (tid & 15) * 8;
  const int ar = tid >> 2, ac = (tid & 3) * 4;
  const int br = tid >> 5, bc = (tid & 31) * 4;
  float acc[8][8];
  #pragma unroll
  for (int i = 0; i < 8; i++)
    #pragma unroll
    for (int j = 0; j < 8; j++) acc[i][j] = 0.f;
  for (int k0 = 0; k0 < K; k0 += 16) {
    #pragma unroll
    for (int i = 0; i < 2; i++) {
      int r = ar + i * 64;
      const float4 v = *(const float4*)&A[(size_t)(brow + r) * K + k0 + ac];
      As[ac + 0][r] = v.x; As[ac + 1][r] = v.y; As[ac + 2][r] = v.z; As[ac + 3][r] = v.w;
    }
    #pragma unroll
    for (int i = 0; i < 2; i++) {
      int r = br + i * 8;
      *(float4*)&Bs[r][bc] = *(const float4*)&B[(size_t)(k0 + r) * N + bcol + bc];
    }
    __syncthreads();
    #pragma unroll
    for (int kk = 0; kk < 16; kk++) {
      float a[8], b[8];
      *(float4*)&a[0] = *(const float4*)&As[kk][trow];
      *(float4*)&a[4] = *(const float4*)&As[kk][trow + 4];
      *(float4*)&b[0] = *(const float4*)&Bs[kk][tcol];
      *(float4*)&b[4] = *(const float4*)&Bs[kk][tcol + 4];
      #pragma unroll
      for (int i = 0; i < 8; i++)
        #pragma unroll
        for (int j = 0; j < 8; j++) acc[i][j] += a[i] * b[j];
    }
    __syncthreads();
  }
  #pragma unroll
  for (int i = 0; i < 8; i++) {
    const size_t row = (size_t)(brow + trow + i) * N + bcol + tcol;
    #pragma unroll
    for (int j0 = 0; j0 < 8; j0 += 4) {
      float4 v;
      float* pv = &v.x;
      #pragma unroll
      for (int q = 0; q < 4; q++) {
        float t = acc[i][j0 + q];
        if (bias) t += bias[bcol + tcol + j0 + q];
        if (relu) t = t > 0.f ? t : 0.f;
        pv[q] = t;
      }
      *(float4*)&C[row + j0] = v;
    }
  }
}

// ---------------- ||p_i|| ----------------
__global__ __launch_bounds__(256) void norm_kernel(
    const float* __restrict__ p1, const float* __restrict__ p2,
    const float* __restrict__ p3, float* __restrict__ nrm)
{
  const float* p = blockIdx.x == 0 ? p1 : (blockIdx.x == 1 ? p2 : p3);
  __shared__ float red[4];
  int tid = threadIdx.x;
  float s = 0.f;
  for (int i = tid; i < DD; i += 256) { float v = p[i]; s += v * v; }
  #pragma unroll
  for (int off = 32; off; off >>= 1) s += __shfl_down(s, off);
  if ((tid & 63) == 0) red[tid >> 6] = s;
  __syncthreads();
  if (tid == 0) nrm[blockIdx.x] = sqrtf(red[0] + red[1] + red[2] + red[3]);
}

// ---------------- fused GAT attention + aggregation (LDS-staged slice) ----------------
__global__ __launch_bounds__(256) void gat_agg(
    const float* __restrict__ xl, const float* __restrict__ als, const float* __restrict__ ald,
    const int* __restrict__ esrc, const int* __restrict__ edst, const int* __restrict__ emask,
    const float* __restrict__ gbias, float* __restrict__ out, int npg)
{
  const int g = blockIdx.x;
  const int h = blockIdx.y;
  const int tid = threadIdx.x;
  const int base = g * npg;
  __shared__ float sxl[32 * 1024];       // this graph+head's slice (<=128KB)
  __shared__ float s_as[32], s_ad[32], s_mx[32], s_den[32], s_self[32];
  __shared__ unsigned s_mxu[32];
  __shared__ float s_alpha[EPG];
  __shared__ int s_srcl[EPG];
  __shared__ int s_start[33];
  __shared__ int s_cnt[32], s_cur[32];
  __shared__ int s_list[EPG];

  // stage slice: rows base..base+npg, cols [h*1024, h*1024+1024)
  for (int n = 0; n < npg; n++) {
    *(float4*)&sxl[(n << 10) + (tid << 2)] =
        *(const float4*)&xl[(size_t)(base + n) * HC + h * DD + (tid << 2)];
  }

  if (tid < npg) {
    s_as[tid] = als[(size_t)(base + tid) * 3 + h];
    s_ad[tid] = ald[(size_t)(base + tid) * 3 + h];
    s_mxu[tid] = 0u;
    s_den[tid] = 0.f;
    s_cnt[tid] = 0;
    s_cur[tid] = 0;
  }
  __syncthreads();

  int ok = 0, dl = 0;
  float lg = 0.f;
  if (tid < EPG) {
    int ei = g * EPG + tid;
    ok = emask ? emask[ei] : 1;
    if (ok) {
      int sl = esrc[ei] - base;
      dl = edst[ei] - base;
      s_srcl[tid] = sl;
      float v = s_as[sl] + s_ad[dl];
      lg = v > 0.f ? v : 0.2f * v;
      atomicMax(&s_mxu[dl], fenc(lg));
      atomicAdd(&s_cnt[dl], 1);
    }
  }
  float slg = 0.f;
  if (tid < npg) {
    float v = s_as[tid] + s_ad[tid];
    slg = v > 0.f ? v : 0.2f * v;
    atomicMax(&s_mxu[tid], fenc(slg));
  }
  __syncthreads();

  if (tid < npg) s_mx[tid] = fdec(s_mxu[tid]);
  if (tid == 0) {
    int run = 0;
    for (int n = 0; n < npg; n++) { s_start[n] = run; run += s_cnt[n]; }
    s_start[npg] = run;
  }
  __syncthreads();

  float ex = 0.f;
  if (tid < EPG && ok) {
    ex = expf(lg - s_mx[dl]);
    atomicAdd(&s_den[dl], ex);
    int p = s_start[dl] + atomicAdd(&s_cur[dl], 1);
    s_list[p] = tid;
  }
  if (tid < npg) {
    float e2 = expf(slg - s_mx[tid]);
    s_self[tid] = e2;
    atomicAdd(&s_den[tid], e2);
  }
  __syncthreads();

  if (tid < EPG && ok) s_alpha[tid] = ex / s_den[dl];
  if (tid < npg) s_self[tid] = s_self[tid] / s_den[tid];
  __syncthreads();

  const int c = h * DD + (tid << 2);
  const float4 b4 = *(const float4*)&gbias[c];
  for (int n = 0; n < npg; n++) {
    const float4 v = *(const float4*)&sxl[(n << 10) + (tid << 2)];
    float a0 = s_self[n];
    float4 acc;
    acc.x = a0 * v.x; acc.y = a0 * v.y; acc.z = a0 * v.z; acc.w = a0 * v.w;
    const int st = s_start[n], en = s_start[n + 1];
    for (int q = st; q < en; q++) {
      int e = s_list[q];
      float a = s_alpha[e];
      const float4 u = *(const float4*)&sxl[(s_srcl[e] << 10) + (tid << 2)];
      acc.x += a * u.x; acc.y += a * u.y; acc.z += a * u.z; acc.w += a * u.w;
    }
    acc.x += b4.x; acc.y += b4.y; acc.z += b4.z; acc.w += b4.w;
    *(float4*)&out[(size_t)(base + n) * HC + c] = acc;
  }
}

// ---------------- TopK pool (tanh applied here; stable sort desc, index asc) ----------------
__global__ __launch_bounds__(256) void pool_kernel(
    const float* __restrict__ hbuf, const float* __restrict__ sc,
    const int* __restrict__ cs, const int* __restrict__ cd, const int* __restrict__ cm,
    int npg, int k,
    float* __restrict__ xnew, float* __restrict__ gap,
    int* __restrict__ ns, int* __restrict__ nd, int* __restrict__ nm,
    const float* __restrict__ nrm, int stage)
{
  int g = blockIdx.x, tid = threadIdx.x;
  __shared__ float ssc[32];
  __shared__ int sord[32];
  __shared__ int snp[32];
  if (tid < npg) ssc[tid] = tanhf(sc[g * npg + tid] / nrm[stage]);
  __syncthreads();
  if (tid == 0) {
    for (int i = 0; i < npg; i++) sord[i] = i;
    for (int i = 1; i < npg; i++) {
      int oi = sord[i]; float v = ssc[oi]; int j = i - 1;
      while (j >= 0 && ssc[sord[j]] < v) { sord[j + 1] = sord[j]; j--; }
      sord[j + 1] = oi;
    }
  }
  __syncthreads();
  if (tid < npg) snp[tid] = -1;
  __syncthreads();
  if (tid < k) snp[sord[tid]] = tid;
  __syncthreads();

  float acc0 = 0.f, acc1 = 0.f, acc2 = 0.f, acc3 = 0.f;
  for (int r = 0; r < k; r++) {
    int ol = sord[r];
    float s = ssc[ol];
    const float* hr = hbuf + (size_t)(g * npg + ol) * DD;
    float* xr = xnew + (size_t)(g * k + r) * DD;
    float v0 = hr[tid] * s, v1 = hr[tid + 256] * s, v2 = hr[tid + 512] * s, v3 = hr[tid + 768] * s;
    xr[tid] = v0; xr[tid + 256] = v1; xr[tid + 512] = v2; xr[tid + 768] = v3;
    acc0 += v0; acc1 += v1; acc2 += v2; acc3 += v3;
  }
  float fk = (float)k;
  gap[(size_t)g * DD + tid]       = acc0 / fk;
  gap[(size_t)g * DD + tid + 256] = acc1 / fk;
  gap[(size_t)g * DD + tid + 512] = acc2 / fk;
  gap[(size_t)g * DD + tid + 768] = acc3 / fk;

  for (int e = tid; e < EPG; e += 256) {
    int ei = g * EPG + e;
    int ok = cm ? cm[ei] : 1;
    int m2 = 0, a = 0, b2 = 0;
    if (ok) {
      int sl = cs[ei] - g * npg, dl = cd[ei] - g * npg;
      int nsl = snp[sl], ndl = snp[dl];
      if (nsl >= 0 && ndl >= 0) { m2 = 1; a = g * k + nsl; b2 = g * k + ndl; }
    }
    ns[ei] = a; nd[ei] = b2; nm[ei] = m2;
  }
}

__global__ __launch_bounds__(256) void zadd_kernel(
    const float* __restrict__ a, const float* __restrict__ b,
    const float* __restrict__ c, float* __restrict__ o)
{
  int i = blockIdx.x * 256 + threadIdx.x;
  o[i] = a[i] + b[i] + c[i];
}

__global__ __launch_bounds__(256) void l2_kernel(
    const float* __restrict__ z2, const float* __restrict__ w,
    const float* __restrict__ b, float* __restrict__ out)
{
  int row = (blockIdx.x * 256 + threadIdx.x) >> 6;
  int lane = threadIdx.x & 63;
  if (row >= 256) return;
  const float* r = z2 + (size_t)row * DD;
  float s = 0.f;
  #pragma unroll 4
  for (int i = lane; i < DD; i += 64) s += r[i] * w[i];
  #pragma unroll
  for (int off = 32; off; off >>= 1) s += __shfl_down(s, off);
  if (lane == 0) out[row] = s + b[0];
}

extern "C" void kernel_launch(void* const* d_in, const int* in_sizes, int n_in,
                              void* d_out, int out_size, void* d_ws, size_t ws_size,
                              hipStream_t stream)
{
  (void)in_sizes; (void)n_in; (void)out_size; (void)ws_size;
  const float* x    = (const float*)d_in[0];
  const int*   eidx = (const int*)d_in[2];
  const float* g1W = (const float*)d_in[4];
  const float* g1as= (const float*)d_in[5];
  const float* g1ad= (const float*)d_in[6];
  const float* g1b = (const float*)d_in[7];
  const float* t1W = (const float*)d_in[8];
  const float* t1b = (const float*)d_in[9];
  const float* p1  = (const float*)d_in[10];
  const float* g2W = (const float*)d_in[11];
  const float* g2as= (const float*)d_in[12];
  const float* g2ad= (const float*)d_in[13];
  const float* g2b = (const float*)d_in[14];
  const float* t2W = (const float*)d_in[15];
  const float* t2b = (const float*)d_in[16];
  const float* p2  = (const float*)d_in[17];
  const float* g3W = (const float*)d_in[18];
  const float* g3as= (const float*)d_in[19];
  const float* g3ad= (const float*)d_in[20];
  const float* g3b = (const float*)d_in[21];
  const float* t3W = (const float*)d_in[22];
  const float* t3b = (const float*)d_in[23];
  const float* p3  = (const float*)d_in[24];
  const float* l1W = (const float*)d_in[25];
  const float* l1b = (const float*)d_in[26];
  const float* l2W = (const float*)d_in[27];
  const float* l2b = (const float*)d_in[28];
  float* outp = (float*)d_out;

  float* W = (float*)d_ws;
  size_t o = 0;
  float* bufA = W + o; o += (size_t)8192 * HC;
  float* bufB = W + o; o += (size_t)8192 * HC;
  float* ALS = W + o; o += 8192 * 3;
  float* ALD = W + o; o += 8192 * 3;
  float* SC  = W + o; o += 8192;
  float* NRM = W + o; o += 4;
  float* X1  = W + o; o += 256 * DD;
  float* X2  = W + o; o += 256 * DD;
  float* X3  = W + o; o += 256 * DD;
  float* ZB  = W + o; o += 256 * DD;
  float* Z2  = W + o; o += 256 * DD;
  int* E0s = (int*)(W + o); o += 40960;
  int* E0d = (int*)(W + o); o += 40960;
  int* E0m = (int*)(W + o); o += 40960;
  int* E1s = (int*)(W + o); o += 40960;
  int* E1d = (int*)(W + o); o += 40960;
  int* E1m = (int*)(W + o); o += 40960;
  _Float16* WTH = (_Float16*)(W + o); o += (3200 * 1024) / 2;
  _Float16* WTL = (_Float16*)(W + o); o += (3200 * 1024) / 2;

  const int* es1 = eidx;
  const int* ed1 = eidx + 40960;

  norm_kernel<<<3, 256, 0, stream>>>(p1, p2, p3, NRM);

  // -------- stage 1: N=8192 nodes, npg=32 -> k=26 --------
  hipMemsetAsync(ALS, 0, 8192 * 3 * 4, stream);
  hipMemsetAsync(ALD, 0, 8192 * 3 * 4, stream);
  hipMemsetAsync(SC,  0, 8192 * 4, stream);
  wtrans_kernel<<<dim3(96, 1), dim3(32, 8), 0, stream>>>(g1W, WTH, WTL, 30, HC);
  mfma_gemm<<<dim3(24, 64), 256, 0, stream>>>(x, WTH, WTL, nullptr, bufA, 8192, HC, 30,
                                              g1as, g1ad, ALS, ALD, nullptr, nullptr);
  gat_agg<<<dim3(256, 3), 256, 0, stream>>>(bufA, ALS, ALD, es1, ed1, nullptr, g1b, bufB, 32);
  wtrans_kernel<<<dim3(32, 96), dim3(32, 8), 0, stream>>>(t1W, WTH, WTL, HC, DD);
  mfma_gemm<<<dim3(8, 64), 256, 0, stream>>>(bufB, WTH, WTL, t1b, bufA, 8192, DD, HC,
                                             nullptr, nullptr, nullptr, nullptr, p1, SC);
  pool_kernel<<<256, 256, 0, stream>>>(bufA, SC, es1, ed1, nullptr, 32, 26, bufB, X1,
                                       E0s, E0d, E0m, NRM, 0);

  // -------- stage 2: npg=26 -> k=13 --------
  hipMemsetAsync(ALS, 0, 6656 * 3 * 4, stream);
  hipMemsetAsync(ALD, 0, 6656 * 3 * 4, stream);
  hipMemsetAsync(SC,  0, 6656 * 4, stream);
  wtrans_kernel<<<dim3(96, 32), dim3(32, 8), 0, stream>>>(g2W, WTH, WTL, DD, HC);
  mfma_gemm<<<dim3(24, 52), 256, 0, stream>>>(bufB, WTH, WTL, nullptr, bufA, 6656, HC, DD,
                                              g2as, g2ad, ALS, ALD, nullptr, nullptr);
  gat_agg<<<dim3(256, 3), 256, 0, stream>>>(bufA, ALS, ALD, E0s, E0d, E0m, g2b, bufB, 26);
  wtrans_kernel<<<dim3(32, 96), dim3(32, 8), 0, stream>>>(t2W, WTH, WTL, HC, DD);
  mfma_gemm<<<dim3(8, 52), 256, 0, stream>>>(bufB, WTH, WTL, t2b, bufA, 6656, DD, HC,
                                             nullptr, nullptr, nullptr, nullptr, p2, SC);
  pool_kernel<<<256, 256, 0, stream>>>(bufA, SC, E0s, E0d, E0m, 26, 13, bufB, X2,
                                       E1s, E1d, E1m, NRM, 1);

  // -------- stage 3: npg=13 -> k=4 --------
  hipMemsetAsync(ALS, 0, 3328 * 3 * 4, stream);
  hipMemsetAsync(ALD, 0, 3328 * 3 * 4, stream);
  hipMemsetAsync(SC,  0, 3328 * 4, stream);
  wtrans_kernel<<<dim3(96, 32), dim3(32, 8), 0, stream>>>(g3W, WTH, WTL, DD, HC);
  mfma_gemm<<<dim3(24, 26), 256, 0, stream>>>(bufB, WTH, WTL, nullptr, bufA, 3328, HC, DD,
                                              g3as, g3ad, ALS, ALD, nullptr, nullptr);
  gat_agg<<<dim3(256, 3), 256, 0, stream>>>(bufA, ALS, ALD, E1s, E1d, E1m, g3b, bufB, 13);
  wtrans_kernel<<<dim3(32, 96), dim3(32, 8), 0, stream>>>(t3W, WTH, WTL, HC, DD);
  mfma_gemm<<<dim3(8, 26), 256, 0, stream>>>(bufB, WTH, WTL, t3b, bufA, 3328, DD, HC,
                                             nullptr, nullptr, nullptr, nullptr, p3, SC);
  pool_kernel<<<256, 256, 0, stream>>>(bufA, SC, E1s, E1d, E1m, 13, 4, bufB, X3,
                                       E0s, E0d, E0m, NRM, 2);

  // -------- head --------
  zadd_kernel<<<1024, 256, 0, stream>>>(X1, X2, X3, ZB);
  sgemm_kernel<<<dim3(8, 2), 256, 0, stream>>>(ZB, l1W, l1b, Z2, 256, DD, DD, 1);
  l2_kernel<<<64, 256, 0, stream>>>(Z2, l2W, l2b, outp);
}

// Round 4
// 1191.096 us; speedup vs baseline: 1.1180x; 1.1180x over previous
//
#include <hip/hip_runtime.h>
#include <cstdint>
#include <cstddef>

#define EPG 160
#define HC  3072
#define DD  1024

typedef _Float16 f16x8 __attribute__((ext_vector_type(8)));
typedef float    f32x4 __attribute__((ext_vector_type(4)));

__device__ __forceinline__ unsigned fenc(float f){
  unsigned u = __float_as_uint(f);
  return (u & 0x80000000u) ? ~u : (u | 0x80000000u);
}
__device__ __forceinline__ float fdec(unsigned u){
  return (u & 0x80000000u) ? __uint_as_float(u ^ 0x80000000u) : __uint_as_float(~u);
}

__device__ __forceinline__ void gload16(const void* g, void* l) {
  __builtin_amdgcn_global_load_lds((const __attribute__((address_space(1))) void*)g,
                                   (__attribute__((address_space(3))) void*)l, 16, 0, 0);
}

// ---------------- weight transpose + fp16 split ----------------
// W[K][Nn] fp32 -> WTh/WTl as [K/32 tiles][Nn rows][32 halfs]; the 4 16B-chunks of
// each 64B row are stored pre-swizzled at c ^ ((n>>1)&3) so global_load_lds can write
// linearly while mfma_gemm reads swizzled (conflict-free).
__global__ __launch_bounds__(256) void wtrans_kernel(
    const float* __restrict__ W, _Float16* __restrict__ WTh, _Float16* __restrict__ WTl,
    int K, int Nn)
{
  __shared__ float t[32][33];
  const int tx = threadIdx.x, ty = threadIdx.y;
  const int n0 = blockIdx.x * 32, k0 = blockIdx.y * 32;
  #pragma unroll
  for (int i = 0; i < 4; i++) {
    int k = k0 + ty + i * 8;
    t[ty + i * 8][tx] = (k < K) ? W[(size_t)k * Nn + n0 + tx] : 0.f;
  }
  __syncthreads();
  const int kt = k0 >> 5;
  const int c  = tx >> 3;
  const int w8 = tx & 7;
  #pragma unroll
  for (int i = 0; i < 4; i++) {
    int n = n0 + ty + i * 8;
    float v = t[tx][ty + i * 8];
    _Float16 h = (_Float16)v;
    float r = v - (float)h;
    int c2 = c ^ ((n >> 1) & 3);
    size_t addr = ((size_t)kt * Nn + n) * 32 + c2 * 8 + w8;
    WTh[addr] = h;
    WTl[addr] = (_Float16)r;
  }
}

// ---------------- split-fp16 MFMA GEMM, double-buffered single-barrier pipeline ----------------
// C[M,N] = A[M,K] @ B[K,N] (+bias). Optional deterministic fused epilogues:
//   alsp/aldp[row*48 + head*16 + slot]  (g-GEMMs, N=3072)
//   scp[row*16 + slot]                  (t-GEMMs, N=1024), slot = 64-col strip id
__global__ __launch_bounds__(256) void mfma_gemm(
    const float* __restrict__ A, const _Float16* __restrict__ BTh, const _Float16* __restrict__ BTl,
    const float* __restrict__ bias, float* __restrict__ C,
    int M, int N, int K,
    const float* __restrict__ avs, const float* __restrict__ avd,
    float* __restrict__ alsp, float* __restrict__ aldp,
    const float* __restrict__ pvec, float* __restrict__ scp)
{
  // buffer halves at +0 / +32768; within a half: Ah +0, Al +8192, Bh +16384, Bl +24576
  __shared__ __align__(16) char smem[65536];

  // XCD-aware remap: each XCD keeps one 8-row-group's A-panel L2-resident
  const int gx = N >> 7, gy = M >> 7;
  const int lid = blockIdx.x + gx * blockIdx.y;
  int vx, vy;
  const int G = gy & ~7;
  if (lid < gx * G) {
    const int sub = lid & 7, rest = lid >> 3;
    vx = rest % gx;
    vy = (rest / gx) * 8 + sub;
  } else {
    const int r = lid - gx * G;
    vx = r % gx;
    vy = G + r / gx;
  }
  const int brow = vy << 7, bcol = vx << 7;

  const int tid  = threadIdx.x;
  const int lane = tid & 63;
  const int w    = tid >> 6;
  const int srow = (w << 5) + (lane & 31);
  const int skh  = (lane >> 5) << 4;     // 0 or 16 halfs
  const int fr   = lane & 15;
  const int g4   = lane >> 4;
  const int wr   = (w >> 1) << 6;
  const int wc   = (w & 1) << 6;

  f32x4 acc[4][4];
  #pragma unroll
  for (int m = 0; m < 4; m++)
    #pragma unroll
    for (int n = 0; n < 4; n++) acc[m][n] = (f32x4)0.0f;

  // swizzled byte offsets (within an 8KB region) for fragment reads
  int aoff[4], boff[4];
  #pragma unroll
  for (int m = 0; m < 4; m++) {
    int r = wr + m * 16 + fr;
    aoff[m] = r * 64 + ((g4 ^ ((r >> 1) & 3)) << 4);
  }
  #pragma unroll
  for (int n = 0; n < 4; n++) {
    int r = wc + n * 16 + fr;
    boff[n] = r * 64 + ((g4 ^ ((r >> 1) & 3)) << 4);
  }
  // swizzled A staging write offsets (chunks c0, c0+1)
  const int c0 = (lane >> 5) << 1;
  const int sw0 = srow * 64 + ((c0 ^ ((srow >> 1) & 3)) << 4);
  const int sw1 = srow * 64 + (((c0 + 1) ^ ((srow >> 1) & 3)) << 4);

  const size_t arow = (size_t)(brow + srow) * K;
  const int ktiles = (K + 31) >> 5;

#define LOADA(dst, k0v)                                                          \
  do {                                                                           \
    if ((k0v) + 32 <= K) {                                                       \
      _Pragma("unroll")                                                          \
      for (int q = 0; q < 4; q++)                                                \
        *(float4*)&dst[q * 4] = *(const float4*)&A[arow + (k0v) + skh + q * 4];  \
    } else {                                                                     \
      _Pragma("unroll")                                                          \
      for (int j = 0; j < 16; j++) {                                             \
        int kk2 = (k0v) + skh + j;                                               \
        dst[j] = (kk2 < K) ? A[arow + kk2] : 0.f;                                \
      }                                                                          \
    }                                                                            \
  } while (0)

#define STAGE_B(ktv, buf)                                                \
  do {                                                                   \
    const size_t gb = (((size_t)(ktv) * N + bcol + (w << 5)) << 6);      \
    const char* gh = (const char*)BTh + gb + lane * 16;                  \
    const char* gl = (const char*)BTl + gb + lane * 16;                  \
    char* dh = (char*)(buf) + 16384 + (w << 11);                         \
    char* dl = (char*)(buf) + 24576 + (w << 11);                         \
    gload16(gh, dh); gload16(gh + 1024, dh + 1024);                      \
    gload16(gl, dl); gload16(gl + 1024, dl + 1024);                      \
  } while (0)

#define SPLIT_WRITE(buf)                                                 \
  do {                                                                   \
    f16x8 ah0, ah1, al0, al1;                                            \
    _Pragma("unroll")                                                    \
    for (int j = 0; j < 8; j++) {                                        \
      float v = av[j];                                                   \
      _Float16 hh = (_Float16)v;                                         \
      ah0[j] = hh; al0[j] = (_Float16)(v - (float)hh);                   \
      float v2 = av[j + 8];                                              \
      _Float16 h2 = (_Float16)v2;                                        \
      ah1[j] = h2; al1[j] = (_Float16)(v2 - (float)h2);                  \
    }                                                                    \
    *(f16x8*)((char*)(buf) + sw0) = ah0;                                 \
    *(f16x8*)((char*)(buf) + sw1) = ah1;                                 \
    *(f16x8*)((char*)(buf) + 8192 + sw0) = al0;                          \
    *(f16x8*)((char*)(buf) + 8192 + sw1) = al1;                          \
  } while (0)

  float av[16], av2[16];
  // ---- prologue: stage tile 0 into buf0; preload tile 1 into regs ----
  LOADA(av, 0);
  STAGE_B(0, smem);
  SPLIT_WRITE(smem);
  if (ktiles > 1) LOADA(av, 32);
  __syncthreads();   // buf0 visible (drains gload_lds + ds_write + reg loads)

  for (int kt = 0; kt < ktiles; kt++) {
    char* curb   = smem + ((kt & 1) << 15);
    char* otherb = smem + (((kt + 1) & 1) << 15);

    // stage tile kt+1 into the other half (latency hidden under MFMA below)
    if (kt + 2 < ktiles) LOADA(av2, (kt + 2) * 32);   // regs for next-next tile
    if (kt + 1 < ktiles) {
      STAGE_B(kt + 1, otherb);
      SPLIT_WRITE(otherb);      // av holds tile kt+1
    }

    // ---- compute tile kt ----
    f16x8 ah[4], al[4], bh[4], bl[4];
    #pragma unroll
    for (int n = 0; n < 4; n++) {
      bh[n] = *(const f16x8*)(curb + 16384 + boff[n]);
      bl[n] = *(const f16x8*)(curb + 24576 + boff[n]);
    }
    #pragma unroll
    for (int m = 0; m < 4; m++) {
      ah[m] = *(const f16x8*)(curb + aoff[m]);
      al[m] = *(const f16x8*)(curb + 8192 + aoff[m]);
    }
    __builtin_amdgcn_s_setprio(1);
    #pragma unroll
    for (int m = 0; m < 4; m++) {
      #pragma unroll
      for (int n = 0; n < 4; n++) {
        acc[m][n] = __builtin_amdgcn_mfma_f32_16x16x32_f16(ah[m], bh[n], acc[m][n], 0, 0, 0);
        acc[m][n] = __builtin_amdgcn_mfma_f32_16x16x32_f16(al[m], bh[n], acc[m][n], 0, 0, 0);
        acc[m][n] = __builtin_amdgcn_mfma_f32_16x16x32_f16(ah[m], bl[n], acc[m][n], 0, 0, 0);
      }
    }
    __builtin_amdgcn_s_setprio(0);
    if (kt + 2 < ktiles) {
      #pragma unroll
      for (int j = 0; j < 16; j++) av[j] = av2[j];
    }
    __syncthreads();   // one barrier per K-step: next iter may overwrite curb
  }
#undef LOADA
#undef STAGE_B
#undef SPLIT_WRITE

  // ---- epilogue: C/D layout col=lane&15, row=(lane>>4)*4+q ----
  const int crow0 = brow + wr + g4 * 4;
  const int ccol0 = bcol + wc + fr;
  #pragma unroll
  for (int n = 0; n < 4; n++) {
    const int col = ccol0 + n * 16;
    const float bv = bias ? bias[col] : 0.f;
    #pragma unroll
    for (int m = 0; m < 4; m++) {
      const int row = crow0 + m * 16;
      #pragma unroll
      for (int q = 0; q < 4; q++)
        C[(size_t)(row + q) * N + col] = acc[m][n][q] + bv;
    }
  }

  // ---- deterministic fused attention-dot partials (g-GEMMs) ----
  if (alsp) {
    const int h3 = bcol >> 10;
    const int slot = (((bcol & 1023) >> 7) << 1) + (wc >> 6);   // 16 strips/head
    #pragma unroll
    for (int m = 0; m < 4; m++) {
      #pragma unroll
      for (int q = 0; q < 4; q++) {
        float ps = 0.f, pd = 0.f;
        #pragma unroll
        for (int n = 0; n < 4; n++) {
          const int col = ccol0 + n * 16;
          const float v = acc[m][n][q];
          ps += v * avs[col]; pd += v * avd[col];
        }
        #pragma unroll
        for (int mk = 1; mk <= 8; mk <<= 1) {
          ps += __shfl_xor(ps, mk);
          pd += __shfl_xor(pd, mk);
        }
        if (fr == 0) {
          const int row = crow0 + m * 16 + q;
          alsp[row * 48 + h3 * 16 + slot] = ps;
          aldp[row * 48 + h3 * 16 + slot] = pd;
        }
      }
    }
  }
  // ---- deterministic fused score-dot partials (t-GEMMs) ----
  if (scp) {
    const int slot = ((bcol >> 7) << 1) + (wc >> 6);            // 16 strips
    #pragma unroll
    for (int m = 0; m < 4; m++) {
      #pragma unroll
      for (int q = 0; q < 4; q++) {
        float pp = 0.f;
        #pragma unroll
        for (int n = 0; n < 4; n++) {
          const int col = ccol0 + n * 16;
          pp += (acc[m][n][q] + bias[col]) * pvec[col];
        }
        #pragma unroll
        for (int mk = 1; mk <= 8; mk <<= 1) pp += __shfl_xor(pp, mk);
        if (fr == 0) scp[(crow0 + m * 16 + q) * 16 + slot] = pp;
      }
    }
  }
}

// ---------------- fp32 SGEMM (head l1 GEMM only) ----------------
__global__ __launch_bounds__(256) void sgemm_kernel(
    const float* __restrict__ A, const float* __restrict__ B,
    const float* __restrict__ bias, float* __restrict__ C,
    int M, int N, int K, int relu)
{
  __shared__ float As[16][132];
  __shared__ float Bs[16][132];
  const int tid  = threadIdx.x;
  const int brow = blockIdx.y * 128;
  const int bcol = blockIdx.x * 128;
  const int trow = (tid >> 4) * 8;
  const int tcol = (tid & 15) * 8;
  const int ar = tid >> 2, ac = (tid & 3) * 4;
  const int br = tid >> 5, bc = (tid & 31) * 4;
  float acc[8][8];
  #pragma unroll
  for (int i = 0; i < 8; i++)
    #pragma unroll
    for (int j = 0; j < 8; j++) acc[i][j] = 0.f;
  for (int k0 = 0; k0 < K; k0 += 16) {
    #pragma unroll
    for (int i = 0; i < 2; i++) {
      int r = ar + i * 64;
      const float4 v = *(const float4*)&A[(size_t)(brow + r) * K + k0 + ac];
      As[ac + 0][r] = v.x; As[ac + 1][r] = v.y; As[ac + 2][r] = v.z; As[ac + 3][r] = v.w;
    }
    #pragma unroll
    for (int i = 0; i < 2; i++) {
      int r = br + i * 8;
      *(float4*)&Bs[r][bc] = *(const float4*)&B[(size_t)(k0 + r) * N + bcol + bc];
    }
    __syncthreads();
    #pragma unroll
    for (int kk = 0; kk < 16; kk++) {
      float a[8], b[8];
      *(float4*)&a[0] = *(const float4*)&As[kk][trow];
      *(float4*)&a[4] = *(const float4*)&As[kk][trow + 4];
      *(float4*)&b[0] = *(const float4*)&Bs[kk][tcol];
      *(float4*)&b[4] = *(const float4*)&Bs[kk][tcol + 4];
      #pragma unroll
      for (int i = 0; i < 8; i++)
        #pragma unroll
        for (int j = 0; j < 8; j++) acc[i][j] += a[i] * b[j];
    }
    __syncthreads();
  }
  #pragma unroll
  for (int i = 0; i < 8; i++) {
    const size_t row = (size_t)(brow + trow + i) * N + bcol + tcol;
    #pragma unroll
    for (int j0 = 0; j0 < 8; j0 += 4) {
      float4 v;
      float* pv = &v.x;
      #pragma unroll
      for (int q = 0; q < 4; q++) {
        float t = acc[i][j0 + q];
        if (bias) t += bias[bcol + tcol + j0 + q];
        if (relu) t = t > 0.f ? t : 0.f;
        pv[q] = t;
      }
      *(float4*)&C[row + j0] = v;
    }
  }
}

// ---------------- ||p_i|| ----------------
__global__ __launch_bounds__(256) void norm_kernel(
    const float* __restrict__ p1, const float* __restrict__ p2,
    const float* __restrict__ p3, float* __restrict__ nrm)
{
  const float* p = blockIdx.x == 0 ? p1 : (blockIdx.x == 1 ? p2 : p3);
  __shared__ float red[4];
  int tid = threadIdx.x;
  float s = 0.f;
  for (int i = tid; i < DD; i += 256) { float v = p[i]; s += v * v; }
  #pragma unroll
  for (int off = 32; off; off >>= 1) s += __shfl_down(s, off);
  if ((tid & 63) == 0) red[tid >> 6] = s;
  __syncthreads();
  if (tid == 0) nrm[blockIdx.x] = sqrtf(red[0] + red[1] + red[2] + red[3]);
}

// ---------------- fused GAT attention + aggregation (LDS-staged slice) ----------------
__global__ __launch_bounds__(256) void gat_agg(
    const float* __restrict__ xl, const float* __restrict__ alsp, const float* __restrict__ aldp,
    const int* __restrict__ esrc, const int* __restrict__ edst, const int* __restrict__ emask,
    const float* __restrict__ gbias, float* __restrict__ out, int npg)
{
  const int g = blockIdx.x;
  const int h = blockIdx.y;
  const int tid = threadIdx.x;
  const int base = g * npg;
  __shared__ float sxl[32 * 1024];
  __shared__ float s_as[32], s_ad[32], s_mx[32], s_den[32], s_self[32];
  __shared__ unsigned s_mxu[32];
  __shared__ float s_alpha[EPG];
  __shared__ int s_srcl[EPG];
  __shared__ int s_start[33];
  __shared__ int s_cnt[32], s_cur[32];
  __shared__ int s_list[EPG];

  for (int n = 0; n < npg; n++) {
    *(float4*)&sxl[(n << 10) + (tid << 2)] =
        *(const float4*)&xl[(size_t)(base + n) * HC + h * DD + (tid << 2)];
  }

  if (tid < npg) {
    const float* ps = alsp + (size_t)(base + tid) * 48 + h * 16;
    const float* pdp = aldp + (size_t)(base + tid) * 48 + h * 16;
    float ss = 0.f, dd2 = 0.f;
    #pragma unroll
    for (int s = 0; s < 16; s++) { ss += ps[s]; dd2 += pdp[s]; }
    s_as[tid] = ss;
    s_ad[tid] = dd2;
    s_mxu[tid] = 0u;
    s_den[tid] = 0.f;
    s_cnt[tid] = 0;
    s_cur[tid] = 0;
  }
  __syncthreads();

  int ok = 0, dl = 0;
  float lg = 0.f;
  if (tid < EPG) {
    int ei = g * EPG + tid;
    ok = emask ? emask[ei] : 1;
    if (ok) {
      int sl = esrc[ei] - base;
      dl = edst[ei] - base;
      s_srcl[tid] = sl;
      float v = s_as[sl] + s_ad[dl];
      lg = v > 0.f ? v : 0.2f * v;
      atomicMax(&s_mxu[dl], fenc(lg));
      atomicAdd(&s_cnt[dl], 1);
    }
  }
  float slg = 0.f;
  if (tid < npg) {
    float v = s_as[tid] + s_ad[tid];
    slg = v > 0.f ? v : 0.2f * v;
    atomicMax(&s_mxu[tid], fenc(slg));
  }
  __syncthreads();

  if (tid < npg) s_mx[tid] = fdec(s_mxu[tid]);
  if (tid == 0) {
    int run = 0;
    for (int n = 0; n < npg; n++) { s_start[n] = run; run += s_cnt[n]; }
    s_start[npg] = run;
  }
  __syncthreads();

  float ex = 0.f;
  if (tid < EPG && ok) {
    ex = expf(lg - s_mx[dl]);
    atomicAdd(&s_den[dl], ex);
    int p = s_start[dl] + atomicAdd(&s_cur[dl], 1);
    s_list[p] = tid;
  }
  if (tid < npg) {
    float e2 = expf(slg - s_mx[tid]);
    s_self[tid] = e2;
    atomicAdd(&s_den[tid], e2);
  }
  __syncthreads();

  if (tid < EPG && ok) s_alpha[tid] = ex / s_den[dl];
  if (tid < npg) s_self[tid] = s_self[tid] / s_den[tid];
  __syncthreads();

  const int c = h * DD + (tid << 2);
  const float4 b4 = *(const float4*)&gbias[c];
  for (int n = 0; n < npg; n++) {
    const float4 v = *(const float4*)&sxl[(n << 10) + (tid << 2)];
    float a0 = s_self[n];
    float4 acc;
    acc.x = a0 * v.x; acc.y = a0 * v.y; acc.z = a0 * v.z; acc.w = a0 * v.w;
    const int st = s_start[n], en = s_start[n + 1];
    for (int q = st; q < en; q++) {
      int e = s_list[q];
      float a = s_alpha[e];
      const float4 u = *(const float4*)&sxl[(s_srcl[e] << 10) + (tid << 2)];
      acc.x += a * u.x; acc.y += a * u.y; acc.z += a * u.z; acc.w += a * u.w;
    }
    acc.x += b4.x; acc.y += b4.y; acc.z += b4.z; acc.w += b4.w;
    *(float4*)&out[(size_t)(base + n) * HC + c] = acc;
  }
}

// ---------------- TopK pool (sums score partials, tanh, stable sort desc/index asc) --------
__global__ __launch_bounds__(256) void pool_kernel(
    const float* __restrict__ hbuf, const float* __restrict__ scp,
    const int* __restrict__ cs, const int* __restrict__ cd, const int* __restrict__ cm,
    int npg, int k,
    float* __restrict__ xnew, float* __restrict__ gap,
    int* __restrict__ ns, int* __restrict__ nd, int* __restrict__ nm,
    const float* __restrict__ nrm, int stage)
{
  int g = blockIdx.x, tid = threadIdx.x;
  __shared__ float ssc[32];
  __shared__ int sord[32];
  __shared__ int snp[32];
  if (tid < npg) {
    const float* sp = scp + (size_t)(g * npg + tid) * 16;
    float s = 0.f;
    #pragma unroll
    for (int q = 0; q < 16; q++) s += sp[q];
    ssc[tid] = tanhf(s / nrm[stage]);
  }
  __syncthreads();
  if (tid == 0) {
    for (int i = 0; i < npg; i++) sord[i] = i;
    for (int i = 1; i < npg; i++) {
      int oi = sord[i]; float v = ssc[oi]; int j = i - 1;
      while (j >= 0 && ssc[sord[j]] < v) { sord[j + 1] = sord[j]; j--; }
      sord[j + 1] = oi;
    }
  }
  __syncthreads();
  if (tid < npg) snp[tid] = -1;
  __syncthreads();
  if (tid < k) snp[sord[tid]] = tid;
  __syncthreads();

  float acc0 = 0.f, acc1 = 0.f, acc2 = 0.f, acc3 = 0.f;
  for (int r = 0; r < k; r++) {
    int ol = sord[r];
    float s = ssc[ol];
    const float* hr = hbuf + (size_t)(g * npg + ol) * DD;
    float* xr = xnew + (size_t)(g * k + r) * DD;
    float v0 = hr[tid] * s, v1 = hr[tid + 256] * s, v2 = hr[tid + 512] * s, v3 = hr[tid + 768] * s;
    xr[tid] = v0; xr[tid + 256] = v1; xr[tid + 512] = v2; xr[tid + 768] = v3;
    acc0 += v0; acc1 += v1; acc2 += v2; acc3 += v3;
  }
  float fk = (float)k;
  gap[(size_t)g * DD + tid]       = acc0 / fk;
  gap[(size_t)g * DD + tid + 256] = acc1 / fk;
  gap[(size_t)g * DD + tid + 512] = acc2 / fk;
  gap[(size_t)g * DD + tid + 768] = acc3 / fk;

  for (int e = tid; e < EPG; e += 256) {
    int ei = g * EPG + e;
    int ok = cm ? cm[ei] : 1;
    int m2 = 0, a = 0, b2 = 0;
    if (ok) {
      int sl = cs[ei] - g * npg, dl = cd[ei] - g * npg;
      int nsl = snp[sl], ndl = snp[dl];
      if (nsl >= 0 && ndl >= 0) { m2 = 1; a = g * k + nsl; b2 = g * k + ndl; }
    }
    ns[ei] = a; nd[ei] = b2; nm[ei] = m2;
  }
}

__global__ __launch_bounds__(256) void zadd_kernel(
    const float* __restrict__ a, const float* __restrict__ b,
    const float* __restrict__ c, float* __restrict__ o)
{
  int i = blockIdx.x * 256 + threadIdx.x;
  o[i] = a[i] + b[i] + c[i];
}

__global__ __launch_bounds__(256) void l2_kernel(
    const float* __restrict__ z2, const float* __restrict__ w,
    const float* __restrict__ b, float* __restrict__ out)
{
  int row = (blockIdx.x * 256 + threadIdx.x) >> 6;
  int lane = threadIdx.x & 63;
  if (row >= 256) return;
  const float* r = z2 + (size_t)row * DD;
  float s = 0.f;
  #pragma unroll 4
  for (int i = lane; i < DD; i += 64) s += r[i] * w[i];
  #pragma unroll
  for (int off = 32; off; off >>= 1) s += __shfl_down(s, off);
  if (lane == 0) out[row] = s + b[0];
}

extern "C" void kernel_launch(void* const* d_in, const int* in_sizes, int n_in,
                              void* d_out, int out_size, void* d_ws, size_t ws_size,
                              hipStream_t stream)
{
  (void)in_sizes; (void)n_in; (void)out_size; (void)ws_size;
  const float* x    = (const float*)d_in[0];
  const int*   eidx = (const int*)d_in[2];
  const float* g1W = (const float*)d_in[4];
  const float* g1as= (const float*)d_in[5];
  const float* g1ad= (const float*)d_in[6];
  const float* g1b = (const float*)d_in[7];
  const float* t1W = (const float*)d_in[8];
  const float* t1b = (const float*)d_in[9];
  const float* p1  = (const float*)d_in[10];
  const float* g2W = (const float*)d_in[11];
  const float* g2as= (const float*)d_in[12];
  const float* g2ad= (const float*)d_in[13];
  const float* g2b = (const float*)d_in[14];
  const float* t2W = (const float*)d_in[15];
  const float* t2b = (const float*)d_in[16];
  const float* p2  = (const float*)d_in[17];
  const float* g3W = (const float*)d_in[18];
  const float* g3as= (const float*)d_in[19];
  const float* g3ad= (const float*)d_in[20];
  const float* g3b = (const float*)d_in[21];
  const float* t3W = (const float*)d_in[22];
  const float* t3b = (const float*)d_in[23];
  const float* p3  = (const float*)d_in[24];
  const float* l1W = (const float*)d_in[25];
  const float* l1b = (const float*)d_in[26];
  const float* l2W = (const float*)d_in[27];
  const float* l2b = (const float*)d_in[28];
  float* outp = (float*)d_out;

  float* W = (float*)d_ws;
  size_t o = 0;
  float* bufA = W + o; o += (size_t)8192 * HC;
  float* bufB = W + o; o += (size_t)8192 * HC;
  float* ALSp = W + o; o += 8192 * 48;
  float* ALDp = W + o; o += 8192 * 48;
  float* SCp  = W + o; o += 8192 * 16;
  float* NRM = W + o; o += 4;
  float* X1  = W + o; o += 256 * DD;
  float* X2  = W + o; o += 256 * DD;
  float* X3  = W + o; o += 256 * DD;
  float* ZB  = W + o; o += 256 * DD;
  float* Z2  = W + o; o += 256 * DD;
  int* E0s = (int*)(W + o); o += 40960;
  int* E0d = (int*)(W + o); o += 40960;
  int* E0m = (int*)(W + o); o += 40960;
  int* E1s = (int*)(W + o); o += 40960;
  int* E1d = (int*)(W + o); o += 40960;
  int* E1m = (int*)(W + o); o += 40960;
  _Float16* WTH = (_Float16*)(W + o); o += (3200 * 1024) / 2;
  _Float16* WTL = (_Float16*)(W + o); o += (3200 * 1024) / 2;

  const int* es1 = eidx;
  const int* ed1 = eidx + 40960;

  norm_kernel<<<3, 256, 0, stream>>>(p1, p2, p3, NRM);

  // -------- stage 1: npg=32 -> k=26 --------
  wtrans_kernel<<<dim3(96, 1), dim3(32, 8), 0, stream>>>(g1W, WTH, WTL, 30, HC);
  mfma_gemm<<<dim3(24, 64), 256, 0, stream>>>(x, WTH, WTL, nullptr, bufA, 8192, HC, 30,
                                              g1as, g1ad, ALSp, ALDp, nullptr, nullptr);
  gat_agg<<<dim3(256, 3), 256, 0, stream>>>(bufA, ALSp, ALDp, es1, ed1, nullptr, g1b, bufB, 32);
  wtrans_kernel<<<dim3(32, 96), dim3(32, 8), 0, stream>>>(t1W, WTH, WTL, HC, DD);
  mfma_gemm<<<dim3(8, 64), 256, 0, stream>>>(bufB, WTH, WTL, t1b, bufA, 8192, DD, HC,
                                             nullptr, nullptr, nullptr, nullptr, p1, SCp);
  pool_kernel<<<256, 256, 0, stream>>>(bufA, SCp, es1, ed1, nullptr, 32, 26, bufB, X1,
                                       E0s, E0d, E0m, NRM, 0);

  // -------- stage 2: npg=26 -> k=13 --------
  wtrans_kernel<<<dim3(96, 32), dim3(32, 8), 0, stream>>>(g2W, WTH, WTL, DD, HC);
  mfma_gemm<<<dim3(24, 52), 256, 0, stream>>>(bufB, WTH, WTL, nullptr, bufA, 6656, HC, DD,
                                              g2as, g2ad, ALSp, ALDp, nullptr, nullptr);
  gat_agg<<<dim3(256, 3), 256, 0, stream>>>(bufA, ALSp, ALDp, E0s, E0d, E0m, g2b, bufB, 26);
  wtrans_kernel<<<dim3(32, 96), dim3(32, 8), 0, stream>>>(t2W, WTH, WTL, HC, DD);
  mfma_gemm<<<dim3(8, 52), 256, 0, stream>>>(bufB, WTH, WTL, t2b, bufA, 6656, DD, HC,
                                             nullptr, nullptr, nullptr, nullptr, p2, SCp);
  pool_kernel<<<256, 256, 0, stream>>>(bufA, SCp, E0s, E0d, E0m, 26, 13, bufB, X2,
                                       E1s, E1d, E1m, NRM, 1);

  // -------- stage 3: npg=13 -> k=4 --------
  wtrans_kernel<<<dim3(96, 32), dim3(32, 8), 0, stream>>>(g3W, WTH, WTL, DD, HC);
  mfma_gemm<<<dim3(24, 26), 256, 0, stream>>>(bufB, WTH, WTL, nullptr, bufA, 3328, HC, DD,
                                              g3as, g3ad, ALSp, ALDp, nullptr, nullptr);
  gat_agg<<<dim3(256, 3), 256, 0, stream>>>(bufA, ALSp, ALDp, E1s, E1d, E1m, g3b, bufB, 13);
  wtrans_kernel<<<dim3(32, 96), dim3(32, 8), 0, stream>>>(t3W, WTH, WTL, HC, DD);
  mfma_gemm<<<dim3(8, 26), 256, 0, stream>>>(bufB, WTH, WTL, t3b, bufA, 3328, DD, HC,
                                             nullptr, nullptr, nullptr, nullptr, p3, SCp);
  pool_kernel<<<256, 256, 0, stream>>>(bufA, SCp, E1s, E1d, E1m, 13, 4, bufB, X3,
                                       E0s, E0d, E0m, NRM, 2);

  // -------- head --------
  zadd_kernel<<<1024, 256, 0, stream>>>(X1, X2, X3, ZB);
  sgemm_kernel<<<dim3(8, 2), 256, 0, stream>>>(ZB, l1W, l1b, Z2, 256, DD, DD, 1);
  l2_kernel<<<64, 256, 0, stream>>>(Z2, l2W, l2b, outp);
}

// Round 5
// 1169.828 us; speedup vs baseline: 1.1384x; 1.0182x over previous
//
#include <hip/hip_runtime.h>
#include <cstdint>
#include <cstddef>

#define EPG 160
#define HC  3072
#define DD  1024

typedef _Float16 f16x8 __attribute__((ext_vector_type(8)));
typedef _Float16 f16x4 __attribute__((ext_vector_type(4)));
typedef float    f32x4 __attribute__((ext_vector_type(4)));

__device__ __forceinline__ unsigned fenc(float f){
  unsigned u = __float_as_uint(f);
  return (u & 0x80000000u) ? ~u : (u | 0x80000000u);
}
__device__ __forceinline__ float fdec(unsigned u){
  return (u & 0x80000000u) ? __uint_as_float(u ^ 0x80000000u) : __uint_as_float(~u);
}

__device__ __forceinline__ void gload16(const void* g, void* l) {
  __builtin_amdgcn_global_load_lds((const __attribute__((address_space(1))) void*)g,
                                   (__attribute__((address_space(3))) void*)l, 16, 0, 0);
}

// ---------------- weight transpose + fp16 split ----------------
// W[K][Nn] fp32 -> WTh/WTl as [K/32 tiles][Nn rows][32 halfs]; 16B chunks pre-swizzled
// at c ^ ((n>>1)&3) so global_load_lds writes linearly while GEMM reads swizzled.
__global__ __launch_bounds__(256) void wtrans_kernel(
    const float* __restrict__ W, _Float16* __restrict__ WTh, _Float16* __restrict__ WTl,
    int K, int Nn)
{
  __shared__ float t[32][33];
  const int tx = threadIdx.x, ty = threadIdx.y;
  const int n0 = blockIdx.x * 32, k0 = blockIdx.y * 32;
  #pragma unroll
  for (int i = 0; i < 4; i++) {
    int k = k0 + ty + i * 8;
    t[ty + i * 8][tx] = (k < K) ? W[(size_t)k * Nn + n0 + tx] : 0.f;
  }
  __syncthreads();
  const int kt = k0 >> 5;
  const int c  = tx >> 3;
  const int w8 = tx & 7;
  #pragma unroll
  for (int i = 0; i < 4; i++) {
    int n = n0 + ty + i * 8;
    float v = t[tx][ty + i * 8];
    _Float16 h = (_Float16)v;
    float r = v - (float)h;
    int c2 = c ^ ((n >> 1) & 3);
    size_t addr = ((size_t)kt * Nn + n) * 32 + c2 * 8 + w8;
    WTh[addr] = h;
    WTl[addr] = (_Float16)r;
  }
}

// ---------------- split input x into pre-swizzled fp16 h/l (K=30 padded to 32) ----------------
__global__ __launch_bounds__(256) void xsplit_kernel(
    const float* __restrict__ x, _Float16* __restrict__ ATh, _Float16* __restrict__ ATl, int M)
{
  int r = blockIdx.x * 256 + threadIdx.x;
  if (r >= M) return;
  const float* xr = x + (size_t)r * 30;
  float v[32];
  #pragma unroll
  for (int j = 0; j < 32; j++) v[j] = (j < 30) ? xr[j] : 0.f;
  const int sz = (r >> 1) & 3;
  #pragma unroll
  for (int ch = 0; ch < 4; ch++) {
    int c2 = ch ^ sz;
    f16x8 hh, ll;
    #pragma unroll
    for (int j = 0; j < 8; j++) {
      float vv = v[ch * 8 + j];
      _Float16 hv = (_Float16)vv;
      hh[j] = hv; ll[j] = (_Float16)(vv - (float)hv);
    }
    *(f16x8*)&ATh[(size_t)r * 32 + c2 * 8] = hh;
    *(f16x8*)&ATl[(size_t)r * 32 + c2 * 8] = ll;
  }
}

// ---------------- split-fp16 MFMA GEMM: 256x128 tile, 8 waves, 3-deep counted-vmcnt ----------------
// A,B both pre-split fp16 h/l, pre-swizzled [kt][rows][32]; all staging via global_load_lds.
// NOTE: the K-loop contains NO other VM ops, so vmcnt counts are exact (6 loads/stage/wave).
__global__ __launch_bounds__(512) void mfma_gemm(
    const _Float16* __restrict__ ATh, const _Float16* __restrict__ ATl,
    const _Float16* __restrict__ BTh, const _Float16* __restrict__ BTl,
    const float* __restrict__ bias, float* __restrict__ C,
    int M, int N, int K,
    const float* __restrict__ avs, const float* __restrict__ avd,
    float* __restrict__ alsp, float* __restrict__ aldp,
    const float* __restrict__ pvec, float* __restrict__ scp)
{
  // 3 buffer sets of 48KB: Ah +0 (16K), Al +16384, Bh +32768 (8K), Bl +40960
  __shared__ __align__(16) char smem[3 * 49152];

  const int gx = N >> 7, gy = M >> 8;
  const int lid = blockIdx.x + gx * blockIdx.y;
  int vx, vy;
  const int G = gy & ~7;
  if (lid < gx * G) {
    const int sub = lid & 7, rest = lid >> 3;
    vx = rest % gx; vy = (rest / gx) * 8 + sub;
  } else {
    const int r = lid - gx * G;
    vx = r % gx; vy = G + r / gx;
  }
  const int brow = vy << 8, bcol = vx << 7;

  const int tid  = threadIdx.x;
  const int lane = tid & 63;
  const int w    = tid >> 6;          // 0..7
  const int wm   = w & 3, wn = w >> 2;
  const int wr   = wm << 6, wc = wn << 6;
  const int fr   = lane & 15, g4 = lane >> 4;

  f32x4 acc[4][4];
  #pragma unroll
  for (int m = 0; m < 4; m++)
    #pragma unroll
    for (int n = 0; n < 4; n++) acc[m][n] = (f32x4)0.0f;

  int aoff[4], boff[4];
  #pragma unroll
  for (int m = 0; m < 4; m++) {
    int r = wr + m * 16 + fr;
    aoff[m] = r * 64 + ((g4 ^ ((r >> 1) & 3)) << 4);
  }
  #pragma unroll
  for (int n = 0; n < 4; n++) {
    int r = wc + n * 16 + fr;
    boff[n] = r * 64 + ((g4 ^ ((r >> 1) & 3)) << 4);
  }

  const int ktiles = (K + 31) >> 5;

#define STAGE(ktv, sbuf)                                                   \
  do {                                                                     \
    char* base = smem + (sbuf) * 49152;                                    \
    const size_t ab = (((size_t)(ktv) * M + brow) << 6) + ((size_t)w << 11);\
    const size_t bb = (((size_t)(ktv) * N + bcol) << 6) + ((size_t)w << 10);\
    const char* gah = (const char*)ATh + ab + lane * 16;                   \
    const char* gal = (const char*)ATl + ab + lane * 16;                   \
    const char* gbh = (const char*)BTh + bb + lane * 16;                   \
    const char* gbl = (const char*)BTl + bb + lane * 16;                   \
    gload16(gah,        base + (w << 11));                                 \
    gload16(gah + 1024, base + (w << 11) + 1024);                          \
    gload16(gal,        base + 16384 + (w << 11));                         \
    gload16(gal + 1024, base + 16384 + (w << 11) + 1024);                  \
    gload16(gbh,        base + 32768 + (w << 10));                         \
    gload16(gbl,        base + 40960 + (w << 10));                         \
  } while (0)

  STAGE(0, 0);
  if (ktiles > 1) STAGE(1, 1);

  for (int kt = 0; kt < ktiles; kt++) {
    const int s = kt % 3;
    if (kt + 2 < ktiles) {
      STAGE(kt + 2, (kt + 2) % 3);
      asm volatile("s_waitcnt vmcnt(12)" ::: "memory");  // tile kt's 6 loads landed
    } else if (kt + 1 < ktiles) {
      asm volatile("s_waitcnt vmcnt(6)" ::: "memory");
    } else {
      asm volatile("s_waitcnt vmcnt(0)" ::: "memory");
    }
    __builtin_amdgcn_s_barrier();      // all waves' tile-kt loads are in LDS
    asm volatile("" ::: "memory");

    const char* cb = smem + s * 49152;
    f16x8 ah[4], al[4], bh[4], bl[4];
    #pragma unroll
    for (int n = 0; n < 4; n++) {
      bh[n] = *(const f16x8*)(cb + 32768 + boff[n]);
      bl[n] = *(const f16x8*)(cb + 40960 + boff[n]);
    }
    #pragma unroll
    for (int m = 0; m < 4; m++) {
      ah[m] = *(const f16x8*)(cb + aoff[m]);
      al[m] = *(const f16x8*)(cb + 16384 + aoff[m]);
    }
    __builtin_amdgcn_s_setprio(1);
    #pragma unroll
    for (int m = 0; m < 4; m++) {
      #pragma unroll
      for (int n = 0; n < 4; n++) {
        acc[m][n] = __builtin_amdgcn_mfma_f32_16x16x32_f16(ah[m], bh[n], acc[m][n], 0, 0, 0);
        acc[m][n] = __builtin_amdgcn_mfma_f32_16x16x32_f16(al[m], bh[n], acc[m][n], 0, 0, 0);
        acc[m][n] = __builtin_amdgcn_mfma_f32_16x16x32_f16(ah[m], bl[n], acc[m][n], 0, 0, 0);
      }
    }
    __builtin_amdgcn_s_setprio(0);
    asm volatile("" ::: "memory");
    __builtin_amdgcn_s_barrier();      // reads of buf s done -> may be overwritten next iter
  }
#undef STAGE

  // ---- epilogue: C/D layout col=lane&15, row=(lane>>4)*4+q ----
  const int crow0 = brow + wr + g4 * 4;
  const int ccol0 = bcol + wc + fr;
  #pragma unroll
  for (int n = 0; n < 4; n++) {
    const int col = ccol0 + n * 16;
    const float bv = bias ? bias[col] : 0.f;
    #pragma unroll
    for (int m = 0; m < 4; m++) {
      const int row = crow0 + m * 16;
      #pragma unroll
      for (int q = 0; q < 4; q++)
        C[(size_t)(row + q) * N + col] = acc[m][n][q] + bv;
    }
  }

  // ---- deterministic fused attention-dot partials (g-GEMMs, N=3072) ----
  if (alsp) {
    const int h3 = bcol >> 10;
    const int slot = ((bcol & 1023) >> 6) + wn;   // 16 strips of 64 cols per head
    #pragma unroll
    for (int m = 0; m < 4; m++) {
      #pragma unroll
      for (int q = 0; q < 4; q++) {
        float ps = 0.f, pd = 0.f;
        #pragma unroll
        for (int n = 0; n < 4; n++) {
          const int col = ccol0 + n * 16;
          const float v = acc[m][n][q];
          ps += v * avs[col]; pd += v * avd[col];
        }
        #pragma unroll
        for (int mk = 1; mk <= 8; mk <<= 1) {
          ps += __shfl_xor(ps, mk);
          pd += __shfl_xor(pd, mk);
        }
        if (fr == 0) {
          const int row = crow0 + m * 16 + q;
          alsp[row * 48 + h3 * 16 + slot] = ps;
          aldp[row * 48 + h3 * 16 + slot] = pd;
        }
      }
    }
  }
  // ---- deterministic fused score-dot partials (t-GEMMs, N=1024) ----
  if (scp) {
    const int slot = (bcol >> 6) + wn;            // 16 strips of 64 cols
    #pragma unroll
    for (int m = 0; m < 4; m++) {
      #pragma unroll
      for (int q = 0; q < 4; q++) {
        float pp = 0.f;
        #pragma unroll
        for (int n = 0; n < 4; n++) {
          const int col = ccol0 + n * 16;
          pp += (acc[m][n][q] + bias[col]) * pvec[col];
        }
        #pragma unroll
        for (int mk = 1; mk <= 8; mk <<= 1) pp += __shfl_xor(pp, mk);
        if (fr == 0) scp[(crow0 + m * 16 + q) * 16 + slot] = pp;
      }
    }
  }
}

// ---------------- fp32 SGEMM (head l1 GEMM only) ----------------
__global__ __launch_bounds__(256) void sgemm_kernel(
    const float* __restrict__ A, const float* __restrict__ B,
    const float* __restrict__ bias, float* __restrict__ C,
    int M, int N, int K, int relu)
{
  __shared__ float As[16][132];
  __shared__ float Bs[16][132];
  const int tid  = threadIdx.x;
  const int brow = blockIdx.y * 128;
  const int bcol = blockIdx.x * 128;
  const int trow = (tid >> 4) * 8;
  const int tcol = (tid & 15) * 8;
  const int ar = tid >> 2, ac = (tid & 3) * 4;
  const int br = tid >> 5, bc = (tid & 31) * 4;
  float acc[8][8];
  #pragma unroll
  for (int i = 0; i < 8; i++)
    #pragma unroll
    for (int j = 0; j < 8; j++) acc[i][j] = 0.f;
  for (int k0 = 0; k0 < K; k0 += 16) {
    #pragma unroll
    for (int i = 0; i < 2; i++) {
      int r = ar + i * 64;
      const float4 v = *(const float4*)&A[(size_t)(brow + r) * K + k0 + ac];
      As[ac + 0][r] = v.x; As[ac + 1][r] = v.y; As[ac + 2][r] = v.z; As[ac + 3][r] = v.w;
    }
    #pragma unroll
    for (int i = 0; i < 2; i++) {
      int r = br + i * 8;
      *(float4*)&Bs[r][bc] = *(const float4*)&B[(size_t)(k0 + r) * N + bcol + bc];
    }
    __syncthreads();
    #pragma unroll
    for (int kk = 0; kk < 16; kk++) {
      float a[8], b[8];
      *(float4*)&a[0] = *(const float4*)&As[kk][trow];
      *(float4*)&a[4] = *(const float4*)&As[kk][trow + 4];
      *(float4*)&b[0] = *(const float4*)&Bs[kk][tcol];
      *(float4*)&b[4] = *(const float4*)&Bs[kk][tcol + 4];
      #pragma unroll
      for (int i = 0; i < 8; i++)
        #pragma unroll
        for (int j = 0; j < 8; j++) acc[i][j] += a[i] * b[j];
    }
    __syncthreads();
  }
  #pragma unroll
  for (int i = 0; i < 8; i++) {
    const size_t row = (size_t)(brow + trow + i) * N + bcol + tcol;
    #pragma unroll
    for (int j0 = 0; j0 < 8; j0 += 4) {
      float4 v;
      float* pv = &v.x;
      #pragma unroll
      for (int q = 0; q < 4; q++) {
        float t = acc[i][j0 + q];
        if (bias) t += bias[bcol + tcol + j0 + q];
        if (relu) t = t > 0.f ? t : 0.f;
        pv[q] = t;
      }
      *(float4*)&C[row + j0] = v;
    }
  }
}

// ---------------- ||p_i|| ----------------
__global__ __launch_bounds__(256) void norm_kernel(
    const float* __restrict__ p1, const float* __restrict__ p2,
    const float* __restrict__ p3, float* __restrict__ nrm)
{
  const float* p = blockIdx.x == 0 ? p1 : (blockIdx.x == 1 ? p2 : p3);
  __shared__ float red[4];
  int tid = threadIdx.x;
  float s = 0.f;
  for (int i = tid; i < DD; i += 256) { float v = p[i]; s += v * v; }
  #pragma unroll
  for (int off = 32; off; off >>= 1) s += __shfl_down(s, off);
  if ((tid & 63) == 0) red[tid >> 6] = s;
  __syncthreads();
  if (tid == 0) nrm[blockIdx.x] = sqrtf(red[0] + red[1] + red[2] + red[3]);
}

// ---------------- fused GAT attention + aggregation; writes split fp16 A for t-GEMM ----------------
__global__ __launch_bounds__(256) void gat_agg(
    const float* __restrict__ xl, const float* __restrict__ alsp, const float* __restrict__ aldp,
    const int* __restrict__ esrc, const int* __restrict__ edst, const int* __restrict__ emask,
    const float* __restrict__ gbias, _Float16* __restrict__ ATh, _Float16* __restrict__ ATl,
    int npg, int Mtot)
{
  const int g = blockIdx.x;
  const int h = blockIdx.y;
  const int tid = threadIdx.x;
  const int base = g * npg;
  __shared__ float sxl[32 * 1024];
  __shared__ float s_as[32], s_ad[32], s_mx[32], s_den[32], s_self[32];
  __shared__ unsigned s_mxu[32];
  __shared__ float s_alpha[EPG];
  __shared__ int s_srcl[EPG];
  __shared__ int s_start[33];
  __shared__ int s_cnt[32], s_cur[32];
  __shared__ int s_list[EPG];

  for (int n = 0; n < npg; n++) {
    *(float4*)&sxl[(n << 10) + (tid << 2)] =
        *(const float4*)&xl[(size_t)(base + n) * HC + h * DD + (tid << 2)];
  }

  if (tid < npg) {
    const float* ps = alsp + (size_t)(base + tid) * 48 + h * 16;
    const float* pdp = aldp + (size_t)(base + tid) * 48 + h * 16;
    float ss = 0.f, dd2 = 0.f;
    #pragma unroll
    for (int s = 0; s < 16; s++) { ss += ps[s]; dd2 += pdp[s]; }
    s_as[tid] = ss;
    s_ad[tid] = dd2;
    s_mxu[tid] = 0u;
    s_den[tid] = 0.f;
    s_cnt[tid] = 0;
    s_cur[tid] = 0;
  }
  __syncthreads();

  int ok = 0, dl = 0;
  float lg = 0.f;
  if (tid < EPG) {
    int ei = g * EPG + tid;
    ok = emask ? emask[ei] : 1;
    if (ok) {
      int sl = esrc[ei] - base;
      dl = edst[ei] - base;
      s_srcl[tid] = sl;
      float v = s_as[sl] + s_ad[dl];
      lg = v > 0.f ? v : 0.2f * v;
      atomicMax(&s_mxu[dl], fenc(lg));
      atomicAdd(&s_cnt[dl], 1);
    }
  }
  float slg = 0.f;
  if (tid < npg) {
    float v = s_as[tid] + s_ad[tid];
    slg = v > 0.f ? v : 0.2f * v;
    atomicMax(&s_mxu[tid], fenc(slg));
  }
  __syncthreads();

  if (tid < npg) s_mx[tid] = fdec(s_mxu[tid]);
  if (tid == 0) {
    int run = 0;
    for (int n = 0; n < npg; n++) { s_start[n] = run; run += s_cnt[n]; }
    s_start[npg] = run;
  }
  __syncthreads();

  float ex = 0.f;
  if (tid < EPG && ok) {
    ex = expf(lg - s_mx[dl]);
    atomicAdd(&s_den[dl], ex);
    int p = s_start[dl] + atomicAdd(&s_cur[dl], 1);
    s_list[p] = tid;
  }
  if (tid < npg) {
    float e2 = expf(slg - s_mx[tid]);
    s_self[tid] = e2;
    atomicAdd(&s_den[tid], e2);
  }
  __syncthreads();

  if (tid < EPG && ok) s_alpha[tid] = ex / s_den[dl];
  if (tid < npg) s_self[tid] = s_self[tid] / s_den[tid];
  __syncthreads();

  const int c = h * DD + (tid << 2);
  const float4 b4 = *(const float4*)&gbias[c];
  const int kt = c >> 5;
  const int ch = (c >> 3) & 3;
  const int j4 = c & 7;                 // 0 or 4
  for (int n = 0; n < npg; n++) {
    const float4 v = *(const float4*)&sxl[(n << 10) + (tid << 2)];
    float a0 = s_self[n];
    float4 acc;
    acc.x = a0 * v.x; acc.y = a0 * v.y; acc.z = a0 * v.z; acc.w = a0 * v.w;
    const int st = s_start[n], en = s_start[n + 1];
    for (int q = st; q < en; q++) {
      int e = s_list[q];
      float a = s_alpha[e];
      const float4 u = *(const float4*)&sxl[(s_srcl[e] << 10) + (tid << 2)];
      acc.x += a * u.x; acc.y += a * u.y; acc.z += a * u.z; acc.w += a * u.w;
    }
    acc.x += b4.x; acc.y += b4.y; acc.z += b4.z; acc.w += b4.w;
    const int R = base + n;
    const int c2 = ch ^ ((R >> 1) & 3);
    const size_t ad = ((size_t)kt * Mtot + R) * 32 + c2 * 8 + j4;
    f16x4 hh, ll;
    _Float16 h0 = (_Float16)acc.x; hh[0] = h0; ll[0] = (_Float16)(acc.x - (float)h0);
    _Float16 h1 = (_Float16)acc.y; hh[1] = h1; ll[1] = (_Float16)(acc.y - (float)h1);
    _Float16 h2 = (_Float16)acc.z; hh[2] = h2; ll[2] = (_Float16)(acc.z - (float)h2);
    _Float16 h3v= (_Float16)acc.w; hh[3] = h3v; ll[3] = (_Float16)(acc.w - (float)h3v);
    *(f16x4*)&ATh[ad] = hh;
    *(f16x4*)&ATl[ad] = ll;
  }
}

// ---------------- TopK pool: scores, stable sort, gate -> split fp16 A for next g-GEMM ----------------
__global__ __launch_bounds__(256) void pool_kernel(
    const float* __restrict__ hbuf, const float* __restrict__ scp,
    const int* __restrict__ cs, const int* __restrict__ cd, const int* __restrict__ cm,
    int npg, int k, int Mnext,
    _Float16* __restrict__ ATh, _Float16* __restrict__ ATl,
    float* __restrict__ gap,
    int* __restrict__ ns, int* __restrict__ nd, int* __restrict__ nm,
    const float* __restrict__ nrm, int stage)
{
  int g = blockIdx.x, tid = threadIdx.x;
  __shared__ float ssc[32];
  __shared__ int sord[32];
  __shared__ int snp[32];
  __shared__ float sgp[2][1024];
  if (tid < npg) {
    const float* sp = scp + (size_t)(g * npg + tid) * 16;
    float s = 0.f;
    #pragma unroll
    for (int q = 0; q < 16; q++) s += sp[q];
    ssc[tid] = tanhf(s / nrm[stage]);
  }
  __syncthreads();
  if (tid == 0) {
    for (int i = 0; i < npg; i++) sord[i] = i;
    for (int i = 1; i < npg; i++) {
      int oi = sord[i]; float v = ssc[oi]; int j = i - 1;
      while (j >= 0 && ssc[sord[j]] < v) { sord[j + 1] = sord[j]; j--; }
      sord[j + 1] = oi;
    }
  }
  __syncthreads();
  if (tid < npg) snp[tid] = -1;
  __syncthreads();
  if (tid < k) snp[sord[tid]] = tid;
  __syncthreads();

  const int col0 = (tid & 127) << 3;
  const int rr = tid >> 7;
  const int kt = col0 >> 5;
  const int ch = (col0 >> 3) & 3;
  float part[8];
  #pragma unroll
  for (int j = 0; j < 8; j++) part[j] = 0.f;
  for (int r = rr; r < k; r += 2) {
    int ol = sord[r];
    float s = ssc[ol];
    const float* hr = hbuf + (size_t)(g * npg + ol) * DD + col0;
    float4 v0 = *(const float4*)hr;
    float4 v1 = *(const float4*)(hr + 4);
    float gv[8] = {v0.x * s, v0.y * s, v0.z * s, v0.w * s,
                   v1.x * s, v1.y * s, v1.z * s, v1.w * s};
    #pragma unroll
    for (int j = 0; j < 8; j++) part[j] += gv[j];
    if (ATh) {
      int R = g * k + r;
      int c2 = ch ^ ((R >> 1) & 3);
      size_t ad = ((size_t)kt * Mnext + R) * 32 + c2 * 8;
      f16x8 hh, ll;
      #pragma unroll
      for (int j = 0; j < 8; j++) {
        _Float16 hv = (_Float16)gv[j];
        hh[j] = hv; ll[j] = (_Float16)(gv[j] - (float)hv);
      }
      *(f16x8*)&ATh[ad] = hh;
      *(f16x8*)&ATl[ad] = ll;
    }
  }
  #pragma unroll
  for (int j = 0; j < 8; j++) sgp[rr][col0 + j] = part[j];
  __syncthreads();
  const float fk = (float)k;
  #pragma unroll
  for (int j = 0; j < 4; j++) {
    int cc = tid * 4 + j;
    gap[(size_t)g * DD + cc] = (sgp[0][cc] + sgp[1][cc]) / fk;
  }

  for (int e = tid; e < EPG; e += 256) {
    int ei = g * EPG + e;
    int ok = cm ? cm[ei] : 1;
    int m2 = 0, a = 0, b2 = 0;
    if (ok) {
      int sl = cs[ei] - g * npg, dl = cd[ei] - g * npg;
      int nsl = snp[sl], ndl = snp[dl];
      if (nsl >= 0 && ndl >= 0) { m2 = 1; a = g * k + nsl; b2 = g * k + ndl; }
    }
    ns[ei] = a; nd[ei] = b2; nm[ei] = m2;
  }
}

__global__ __launch_bounds__(256) void zadd_kernel(
    const float* __restrict__ a, const float* __restrict__ b,
    const float* __restrict__ c, float* __restrict__ o)
{
  int i = blockIdx.x * 256 + threadIdx.x;
  o[i] = a[i] + b[i] + c[i];
}

__global__ __launch_bounds__(256) void l2_kernel(
    const float* __restrict__ z2, const float* __restrict__ w,
    const float* __restrict__ b, float* __restrict__ out)
{
  int row = (blockIdx.x * 256 + threadIdx.x) >> 6;
  int lane = threadIdx.x & 63;
  if (row >= 256) return;
  const float* r = z2 + (size_t)row * DD;
  float s = 0.f;
  #pragma unroll 4
  for (int i = lane; i < DD; i += 64) s += r[i] * w[i];
  #pragma unroll
  for (int off = 32; off; off >>= 1) s += __shfl_down(s, off);
  if (lane == 0) out[row] = s + b[0];
}

extern "C" void kernel_launch(void* const* d_in, const int* in_sizes, int n_in,
                              void* d_out, int out_size, void* d_ws, size_t ws_size,
                              hipStream_t stream)
{
  (void)in_sizes; (void)n_in; (void)out_size; (void)ws_size;
  const float* x    = (const float*)d_in[0];
  const int*   eidx = (const int*)d_in[2];
  const float* g1W = (const float*)d_in[4];
  const float* g1as= (const float*)d_in[5];
  const float* g1ad= (const float*)d_in[6];
  const float* g1b = (const float*)d_in[7];
  const float* t1W = (const float*)d_in[8];
  const float* t1b = (const float*)d_in[9];
  const float* p1  = (const float*)d_in[10];
  const float* g2W = (const float*)d_in[11];
  const float* g2as= (const float*)d_in[12];
  const float* g2ad= (const float*)d_in[13];
  const float* g2b = (const float*)d_in[14];
  const float* t2W = (const float*)d_in[15];
  const float* t2b = (const float*)d_in[16];
  const float* p2  = (const float*)d_in[17];
  const float* g3W = (const float*)d_in[18];
  const float* g3as= (const float*)d_in[19];
  const float* g3ad= (const float*)d_in[20];
  const float* g3b = (const float*)d_in[21];
  const float* t3W = (const float*)d_in[22];
  const float* t3b = (const float*)d_in[23];
  const float* p3  = (const float*)d_in[24];
  const float* l1W = (const float*)d_in[25];
  const float* l1b = (const float*)d_in[26];
  const float* l2W = (const float*)d_in[27];
  const float* l2b = (const float*)d_in[28];
  float* outp = (float*)d_out;

  float* W = (float*)d_ws;
  size_t o = 0;
  float* bufA = W + o; o += (size_t)8192 * HC;          // g-GEMM C (fp32)
  float* bufB = W + o; o += (size_t)8192 * DD;          // t-GEMM C (fp32)
  _Float16* ATh = (_Float16*)(W + o); o += (size_t)96 * 8192 * 32 / 2;  // split A (h)
  _Float16* ATl = (_Float16*)(W + o); o += (size_t)96 * 8192 * 32 / 2;  // split A (l)
  float* ALSp = W + o; o += 8192 * 48;
  float* ALDp = W + o; o += 8192 * 48;
  float* SCp  = W + o; o += 8192 * 16;
  float* NRM = W + o; o += 4;
  float* X1  = W + o; o += 256 * DD;
  float* X2  = W + o; o += 256 * DD;
  float* X3  = W + o; o += 256 * DD;
  float* ZB  = W + o; o += 256 * DD;
  float* Z2  = W + o; o += 256 * DD;
  int* E0s = (int*)(W + o); o += 40960;
  int* E0d = (int*)(W + o); o += 40960;
  int* E0m = (int*)(W + o); o += 40960;
  int* E1s = (int*)(W + o); o += 40960;
  int* E1d = (int*)(W + o); o += 40960;
  int* E1m = (int*)(W + o); o += 40960;
  _Float16* WTH = (_Float16*)(W + o); o += (3200 * 1024) / 2;
  _Float16* WTL = (_Float16*)(W + o); o += (3200 * 1024) / 2;

  const int* es1 = eidx;
  const int* ed1 = eidx + 40960;

  norm_kernel<<<3, 256, 0, stream>>>(p1, p2, p3, NRM);

  // -------- stage 1: M=8192, npg=32 -> k=26 --------
  xsplit_kernel<<<32, 256, 0, stream>>>(x, ATh, ATl, 8192);
  wtrans_kernel<<<dim3(96, 1), dim3(32, 8), 0, stream>>>(g1W, WTH, WTL, 30, HC);
  mfma_gemm<<<dim3(24, 32), 512, 0, stream>>>(ATh, ATl, WTH, WTL, nullptr, bufA, 8192, HC, 30,
                                              g1as, g1ad, ALSp, ALDp, nullptr, nullptr);
  gat_agg<<<dim3(256, 3), 256, 0, stream>>>(bufA, ALSp, ALDp, es1, ed1, nullptr, g1b,
                                            ATh, ATl, 32, 8192);
  wtrans_kernel<<<dim3(32, 96), dim3(32, 8), 0, stream>>>(t1W, WTH, WTL, HC, DD);
  mfma_gemm<<<dim3(8, 32), 512, 0, stream>>>(ATh, ATl, WTH, WTL, t1b, bufB, 8192, DD, HC,
                                             nullptr, nullptr, nullptr, nullptr, p1, SCp);
  pool_kernel<<<256, 256, 0, stream>>>(bufB, SCp, es1, ed1, nullptr, 32, 26, 6656,
                                       ATh, ATl, X1, E0s, E0d, E0m, NRM, 0);

  // -------- stage 2: M=6656, npg=26 -> k=13 --------
  wtrans_kernel<<<dim3(96, 32), dim3(32, 8), 0, stream>>>(g2W, WTH, WTL, DD, HC);
  mfma_gemm<<<dim3(24, 26), 512, 0, stream>>>(ATh, ATl, WTH, WTL, nullptr, bufA, 6656, HC, DD,
                                              g2as, g2ad, ALSp, ALDp, nullptr, nullptr);
  gat_agg<<<dim3(256, 3), 256, 0, stream>>>(bufA, ALSp, ALDp, E0s, E0d, E0m, g2b,
                                            ATh, ATl, 26, 6656);
  wtrans_kernel<<<dim3(32, 96), dim3(32, 8), 0, stream>>>(t2W, WTH, WTL, HC, DD);
  mfma_gemm<<<dim3(8, 26), 512, 0, stream>>>(ATh, ATl, WTH, WTL, t2b, bufB, 6656, DD, HC,
                                             nullptr, nullptr, nullptr, nullptr, p2, SCp);
  pool_kernel<<<256, 256, 0, stream>>>(bufB, SCp, E0s, E0d, E0m, 26, 13, 3328,
                                       ATh, ATl, X2, E1s, E1d, E1m, NRM, 1);

  // -------- stage 3: M=3328, npg=13 -> k=4 --------
  wtrans_kernel<<<dim3(96, 32), dim3(32, 8), 0, stream>>>(g3W, WTH, WTL, DD, HC);
  mfma_gemm<<<dim3(24, 13), 512, 0, stream>>>(ATh, ATl, WTH, WTL, nullptr, bufA, 3328, HC, DD,
                                              g3as, g3ad, ALSp, ALDp, nullptr, nullptr);
  gat_agg<<<dim3(256, 3), 256, 0, stream>>>(bufA, ALSp, ALDp, E1s, E1d, E1m, g3b,
                                            ATh, ATl, 13, 3328);
  wtrans_kernel<<<dim3(32, 96), dim3(32, 8), 0, stream>>>(t3W, WTH, WTL, HC, DD);
  mfma_gemm<<<dim3(8, 13), 512, 0, stream>>>(ATh, ATl, WTH, WTL, t3b, bufB, 3328, DD, HC,
                                             nullptr, nullptr, nullptr, nullptr, p3, SCp);
  pool_kernel<<<256, 256, 0, stream>>>(bufB, SCp, E1s, E1d, E1m, 13, 4, 1024,
                                       nullptr, nullptr, X3, E0s, E0d, E0m, NRM, 2);

  // -------- head --------
  zadd_kernel<<<1024, 256, 0, stream>>>(X1, X2, X3, ZB);
  sgemm_kernel<<<dim3(8, 2), 256, 0, stream>>>(ZB, l1W, l1b, Z2, 256, DD, DD, 1);
  l2_kernel<<<64, 256, 0, stream>>>(Z2, l2W, l2b, outp);
}

// Round 6
// 1029.817 us; speedup vs baseline: 1.2931x; 1.1360x over previous
//
#include <hip/hip_runtime.h>
#include <cstdint>
#include <cstddef>

#define EPG 160
#define HC  3072
#define DD  1024

typedef _Float16 f16x8 __attribute__((ext_vector_type(8)));
typedef _Float16 f16x2 __attribute__((ext_vector_type(2)));
typedef float    f32x4 __attribute__((ext_vector_type(4)));

__device__ __forceinline__ unsigned fenc(float f){
  unsigned u = __float_as_uint(f);
  return (u & 0x80000000u) ? ~u : (u | 0x80000000u);
}
__device__ __forceinline__ float fdec(unsigned u){
  return (u & 0x80000000u) ? __uint_as_float(u ^ 0x80000000u) : __uint_as_float(~u);
}

__device__ __forceinline__ void gload16(const void* g, void* l) {
  __builtin_amdgcn_global_load_lds((const __attribute__((address_space(1))) void*)g,
                                   (__attribute__((address_space(3))) void*)l, 16, 0, 0);
}

// ---------------- weight transpose + fp16 split ----------------
// W[K][Nn] fp32 -> WTh/WTl as [K/32 tiles][Nn rows][32 halfs]; 16B chunks pre-swizzled
// at c ^ ((n>>1)&3) so global_load_lds writes linearly while GEMM reads swizzled.
__global__ __launch_bounds__(256) void wtrans_kernel(
    const float* __restrict__ W, _Float16* __restrict__ WTh, _Float16* __restrict__ WTl,
    int K, int Nn)
{
  __shared__ float t[32][33];
  const int tx = threadIdx.x, ty = threadIdx.y;
  const int n0 = blockIdx.x * 32, k0 = blockIdx.y * 32;
  #pragma unroll
  for (int i = 0; i < 4; i++) {
    int k = k0 + ty + i * 8;
    t[ty + i * 8][tx] = (k < K) ? W[(size_t)k * Nn + n0 + tx] : 0.f;
  }
  __syncthreads();
  const int kt = k0 >> 5;
  const int c  = tx >> 3;
  const int w8 = tx & 7;
  #pragma unroll
  for (int i = 0; i < 4; i++) {
    int n = n0 + ty + i * 8;
    float v = t[tx][ty + i * 8];
    _Float16 h = (_Float16)v;
    float r = v - (float)h;
    int c2 = c ^ ((n >> 1) & 3);
    size_t addr = ((size_t)kt * Nn + n) * 32 + c2 * 8 + w8;
    WTh[addr] = h;
    WTl[addr] = (_Float16)r;
  }
}

// ---------------- split input x into pre-swizzled fp16 h/l (K=30 padded to 32) ----------------
__global__ __launch_bounds__(256) void xsplit_kernel(
    const float* __restrict__ x, _Float16* __restrict__ ATh, _Float16* __restrict__ ATl, int M)
{
  int r = blockIdx.x * 256 + threadIdx.x;
  if (r >= M) return;
  const float* xr = x + (size_t)r * 30;
  float v[32];
  #pragma unroll
  for (int j = 0; j < 32; j++) v[j] = (j < 30) ? xr[j] : 0.f;
  const int sz = (r >> 1) & 3;
  #pragma unroll
  for (int ch = 0; ch < 4; ch++) {
    int c2 = ch ^ sz;
    f16x8 hh, ll;
    #pragma unroll
    for (int j = 0; j < 8; j++) {
      float vv = v[ch * 8 + j];
      _Float16 hv = (_Float16)vv;
      hh[j] = hv; ll[j] = (_Float16)(vv - (float)hv);
    }
    *(f16x8*)&ATh[(size_t)r * 32 + c2 * 8] = hh;
    *(f16x8*)&ATl[(size_t)r * 32 + c2 * 8] = ll;
  }
}

// ---------------- split-fp16 MFMA GEMM: 128x128 tile, 4 waves, 2-deep counted-vmcnt ----------------
// A,B pre-split fp16 h/l, pre-swizzled [kt][rows][32]; all staging via global_load_lds.
// LDS = 2 x 32KB -> exactly 64KB -> 2 blocks/CU (cross-block overlap fills barrier drains).
// K-loop has NO other VM ops, so vmcnt counts are exact (8 loads/thread per stage).
__global__ __launch_bounds__(256) void mfma_gemm(
    const _Float16* __restrict__ ATh, const _Float16* __restrict__ ATl,
    const _Float16* __restrict__ BTh, const _Float16* __restrict__ BTl,
    const float* __restrict__ bias, float* __restrict__ C,
    int M, int N, int K,
    const float* __restrict__ avs, const float* __restrict__ avd,
    float* __restrict__ alsp, float* __restrict__ aldp,
    const float* __restrict__ pvec, float* __restrict__ scp)
{
  // per 32KB buffer: Ah +0, Al +8192, Bh +16384, Bl +24576
  __shared__ __align__(16) char smem[2 * 32768];

  const int gx = N >> 7, gy = M >> 7;
  const int lid = blockIdx.x + gx * blockIdx.y;
  int vx, vy;
  const int G = gy & ~7;
  if (lid < gx * G) {
    const int sub = lid & 7, rest = lid >> 3;
    vx = rest % gx; vy = (rest / gx) * 8 + sub;
  } else {
    const int r = lid - gx * G;
    vx = r % gx; vy = G + r / gx;
  }
  const int brow = vy << 7, bcol = vx << 7;

  const int tid  = threadIdx.x;
  const int lane = tid & 63;
  const int w    = tid >> 6;          // 0..3
  const int wr   = (w >> 1) << 6, wc = (w & 1) << 6;
  const int wn   = w & 1;
  const int fr   = lane & 15, g4 = lane >> 4;

  f32x4 acc[4][4];
  #pragma unroll
  for (int m = 0; m < 4; m++)
    #pragma unroll
    for (int n = 0; n < 4; n++) acc[m][n] = (f32x4)0.0f;

  int aoff[4], boff[4];
  #pragma unroll
  for (int m = 0; m < 4; m++) {
    int r = wr + m * 16 + fr;
    aoff[m] = r * 64 + ((g4 ^ ((r >> 1) & 3)) << 4);
  }
  #pragma unroll
  for (int n = 0; n < 4; n++) {
    int r = wc + n * 16 + fr;
    boff[n] = r * 64 + ((g4 ^ ((r >> 1) & 3)) << 4);
  }

  const int ktiles = (K + 31) >> 5;

#define STAGE(ktv, buf)                                                    \
  do {                                                                     \
    char* bse = (buf);                                                     \
    const size_t ab = ((size_t)(ktv) * M + brow) << 6;                     \
    const size_t bb = ((size_t)(ktv) * N + bcol) << 6;                     \
    const char* gah = (const char*)ATh + ab + tid * 16;                    \
    const char* gal = (const char*)ATl + ab + tid * 16;                    \
    const char* gbh = (const char*)BTh + bb + tid * 16;                    \
    const char* gbl = (const char*)BTl + bb + tid * 16;                    \
    gload16(gah,        bse + tid * 16);                                   \
    gload16(gah + 4096, bse + tid * 16 + 4096);                            \
    gload16(gal,        bse + 8192 + tid * 16);                            \
    gload16(gal + 4096, bse + 8192 + tid * 16 + 4096);                     \
    gload16(gbh,        bse + 16384 + tid * 16);                           \
    gload16(gbh + 4096, bse + 16384 + tid * 16 + 4096);                    \
    gload16(gbl,        bse + 24576 + tid * 16);                           \
    gload16(gbl + 4096, bse + 24576 + tid * 16 + 4096);                    \
  } while (0)

  STAGE(0, smem);
  if (ktiles > 1) STAGE(1, smem + 32768);

  for (int kt = 0; kt < ktiles; kt++) {
    char* curb = smem + ((kt & 1) << 15);
    if (kt + 1 < ktiles) {
      asm volatile("s_waitcnt vmcnt(8)" ::: "memory");   // tile kt's 8 loads landed
    } else {
      asm volatile("s_waitcnt vmcnt(0)" ::: "memory");
    }
    __builtin_amdgcn_s_barrier();      // tile kt visible block-wide
    asm volatile("" ::: "memory");

    f16x8 ah[4], al[4], bh[4], bl[4];
    #pragma unroll
    for (int n = 0; n < 4; n++) {
      bh[n] = *(const f16x8*)(curb + 16384 + boff[n]);
      bl[n] = *(const f16x8*)(curb + 24576 + boff[n]);
    }
    #pragma unroll
    for (int m = 0; m < 4; m++) {
      ah[m] = *(const f16x8*)(curb + aoff[m]);
      al[m] = *(const f16x8*)(curb + 8192 + aoff[m]);
    }
    asm volatile("s_waitcnt lgkmcnt(0)" ::: "memory");   // this wave's LDS reads retired
    __builtin_amdgcn_sched_barrier(0);
    __builtin_amdgcn_s_barrier();      // all waves done reading curb -> safe to overwrite
    asm volatile("" ::: "memory");

    if (kt + 2 < ktiles) STAGE(kt + 2, curb);  // hides under the MFMA cluster below

    __builtin_amdgcn_s_setprio(1);
    #pragma unroll
    for (int m = 0; m < 4; m++) {
      #pragma unroll
      for (int n = 0; n < 4; n++) {
        acc[m][n] = __builtin_amdgcn_mfma_f32_16x16x32_f16(ah[m], bh[n], acc[m][n], 0, 0, 0);
        acc[m][n] = __builtin_amdgcn_mfma_f32_16x16x32_f16(al[m], bh[n], acc[m][n], 0, 0, 0);
        acc[m][n] = __builtin_amdgcn_mfma_f32_16x16x32_f16(ah[m], bl[n], acc[m][n], 0, 0, 0);
      }
    }
    __builtin_amdgcn_s_setprio(0);
    asm volatile("" ::: "memory");
  }
#undef STAGE

  // ---- epilogue: C/D layout col=lane&15, row=(lane>>4)*4+q ----
  const int crow0 = brow + wr + g4 * 4;
  const int ccol0 = bcol + wc + fr;
  #pragma unroll
  for (int n = 0; n < 4; n++) {
    const int col = ccol0 + n * 16;
    const float bv = bias ? bias[col] : 0.f;
    #pragma unroll
    for (int m = 0; m < 4; m++) {
      const int row = crow0 + m * 16;
      #pragma unroll
      for (int q = 0; q < 4; q++)
        C[(size_t)(row + q) * N + col] = acc[m][n][q] + bv;
    }
  }

  // ---- deterministic fused attention-dot partials (g-GEMMs, N=3072) ----
  if (alsp) {
    const int h3 = bcol >> 10;
    const int slot = ((bcol & 1023) >> 6) + wn;   // 16 strips of 64 cols per head
    #pragma unroll
    for (int m = 0; m < 4; m++) {
      #pragma unroll
      for (int q = 0; q < 4; q++) {
        float ps = 0.f, pd = 0.f;
        #pragma unroll
        for (int n = 0; n < 4; n++) {
          const int col = ccol0 + n * 16;
          const float v = acc[m][n][q];
          ps += v * avs[col]; pd += v * avd[col];
        }
        #pragma unroll
        for (int mk = 1; mk <= 8; mk <<= 1) {
          ps += __shfl_xor(ps, mk);
          pd += __shfl_xor(pd, mk);
        }
        if (fr == 0) {
          const int row = crow0 + m * 16 + q;
          alsp[row * 48 + h3 * 16 + slot] = ps;
          aldp[row * 48 + h3 * 16 + slot] = pd;
        }
      }
    }
  }
  // ---- deterministic fused score-dot partials (t-GEMMs, N=1024) ----
  if (scp) {
    const int slot = (bcol >> 6) + wn;            // 16 strips of 64 cols
    #pragma unroll
    for (int m = 0; m < 4; m++) {
      #pragma unroll
      for (int q = 0; q < 4; q++) {
        float pp = 0.f;
        #pragma unroll
        for (int n = 0; n < 4; n++) {
          const int col = ccol0 + n * 16;
          pp += (acc[m][n][q] + bias[col]) * pvec[col];
        }
        #pragma unroll
        for (int mk = 1; mk <= 8; mk <<= 1) pp += __shfl_xor(pp, mk);
        if (fr == 0) scp[(crow0 + m * 16 + q) * 16 + slot] = pp;
      }
    }
  }
}

// ---------------- fp32 SGEMM (head l1 GEMM only) ----------------
__global__ __launch_bounds__(256) void sgemm_kernel(
    const float* __restrict__ A, const float* __restrict__ B,
    const float* __restrict__ bias, float* __restrict__ C,
    int M, int N, int K, int relu)
{
  __shared__ float As[16][132];
  __shared__ float Bs[16][132];
  const int tid  = threadIdx.x;
  const int brow = blockIdx.y * 128;
  const int bcol = blockIdx.x * 128;
  const int trow = (tid >> 4) * 8;
  const int tcol = (tid & 15) * 8;
  const int ar = tid >> 2, ac = (tid & 3) * 4;
  const int br = tid >> 5, bc = (tid & 31) * 4;
  float acc[8][8];
  #pragma unroll
  for (int i = 0; i < 8; i++)
    #pragma unroll
    for (int j = 0; j < 8; j++) acc[i][j] = 0.f;
  for (int k0 = 0; k0 < K; k0 += 16) {
    #pragma unroll
    for (int i = 0; i < 2; i++) {
      int r = ar + i * 64;
      const float4 v = *(const float4*)&A[(size_t)(brow + r) * K + k0 + ac];
      As[ac + 0][r] = v.x; As[ac + 1][r] = v.y; As[ac + 2][r] = v.z; As[ac + 3][r] = v.w;
    }
    #pragma unroll
    for (int i = 0; i < 2; i++) {
      int r = br + i * 8;
      *(float4*)&Bs[r][bc] = *(const float4*)&B[(size_t)(k0 + r) * N + bcol + bc];
    }
    __syncthreads();
    #pragma unroll
    for (int kk = 0; kk < 16; kk++) {
      float a[8], b[8];
      *(float4*)&a[0] = *(const float4*)&As[kk][trow];
      *(float4*)&a[4] = *(const float4*)&As[kk][trow + 4];
      *(float4*)&b[0] = *(const float4*)&Bs[kk][tcol];
      *(float4*)&b[4] = *(const float4*)&Bs[kk][tcol + 4];
      #pragma unroll
      for (int i = 0; i < 8; i++)
        #pragma unroll
        for (int j = 0; j < 8; j++) acc[i][j] += a[i] * b[j];
    }
    __syncthreads();
  }
  #pragma unroll
  for (int i = 0; i < 8; i++) {
    const size_t row = (size_t)(brow + trow + i) * N + bcol + tcol;
    #pragma unroll
    for (int j0 = 0; j0 < 8; j0 += 4) {
      float4 v;
      float* pv = &v.x;
      #pragma unroll
      for (int q = 0; q < 4; q++) {
        float t = acc[i][j0 + q];
        if (bias) t += bias[bcol + tcol + j0 + q];
        if (relu) t = t > 0.f ? t : 0.f;
        pv[q] = t;
      }
      *(float4*)&C[row + j0] = v;
    }
  }
}

// ---------------- ||p_i|| ----------------
__global__ __launch_bounds__(256) void norm_kernel(
    const float* __restrict__ p1, const float* __restrict__ p2,
    const float* __restrict__ p3, float* __restrict__ nrm)
{
  const float* p = blockIdx.x == 0 ? p1 : (blockIdx.x == 1 ? p2 : p3);
  __shared__ float red[4];
  int tid = threadIdx.x;
  float s = 0.f;
  for (int i = tid; i < DD; i += 256) { float v = p[i]; s += v * v; }
  #pragma unroll
  for (int off = 32; off; off >>= 1) s += __shfl_down(s, off);
  if ((tid & 63) == 0) red[tid >> 6] = s;
  __syncthreads();
  if (tid == 0) nrm[blockIdx.x] = sqrtf(red[0] + red[1] + red[2] + red[3]);
}

// ---------------- fused GAT attention + aggregation (column-half blocks, 2/CU) --------------
// grid = (256 graphs, 6): head = y>>1, column half = y&1. Writes split fp16 A for t-GEMM.
__global__ __launch_bounds__(256) void gat_agg(
    const float* __restrict__ xl, const float* __restrict__ alsp, const float* __restrict__ aldp,
    const int* __restrict__ esrc, const int* __restrict__ edst, const int* __restrict__ emask,
    const float* __restrict__ gbias, _Float16* __restrict__ ATh, _Float16* __restrict__ ATl,
    int npg, int Mtot)
{
  const int g = blockIdx.x;
  const int h = blockIdx.y >> 1;
  const int half = blockIdx.y & 1;
  const int tid = threadIdx.x;
  const int base = g * npg;
  __shared__ float sxl[32 * 512];        // 64KB -> 2 blocks/CU
  __shared__ float s_as[32], s_ad[32], s_mx[32], s_den[32], s_self[32];
  __shared__ unsigned s_mxu[32];
  __shared__ float s_alpha[EPG];
  __shared__ int s_srcl[EPG];
  __shared__ int s_start[33];
  __shared__ int s_cnt[32], s_cur[32];
  __shared__ int s_list[EPG];

  const int colb = h * DD + (half << 9);      // global col base of this block's 512 cols
  for (int n = 0; n < npg; n++) {
    *(float2*)&sxl[(n << 9) + (tid << 1)] =
        *(const float2*)&xl[(size_t)(base + n) * HC + colb + (tid << 1)];
  }

  if (tid < npg) {
    const float* ps = alsp + (size_t)(base + tid) * 48 + h * 16;
    const float* pdp = aldp + (size_t)(base + tid) * 48 + h * 16;
    float ss = 0.f, dd2 = 0.f;
    #pragma unroll
    for (int s = 0; s < 16; s++) { ss += ps[s]; dd2 += pdp[s]; }
    s_as[tid] = ss;
    s_ad[tid] = dd2;
    s_mxu[tid] = 0u;
    s_den[tid] = 0.f;
    s_cnt[tid] = 0;
    s_cur[tid] = 0;
  }
  __syncthreads();

  int ok = 0, dl = 0;
  float lg = 0.f;
  if (tid < EPG) {
    int ei = g * EPG + tid;
    ok = emask ? emask[ei] : 1;
    if (ok) {
      int sl = esrc[ei] - base;
      dl = edst[ei] - base;
      s_srcl[tid] = sl;
      float v = s_as[sl] + s_ad[dl];
      lg = v > 0.f ? v : 0.2f * v;
      atomicMax(&s_mxu[dl], fenc(lg));
      atomicAdd(&s_cnt[dl], 1);
    }
  }
  float slg = 0.f;
  if (tid < npg) {
    float v = s_as[tid] + s_ad[tid];
    slg = v > 0.f ? v : 0.2f * v;
    atomicMax(&s_mxu[tid], fenc(slg));
  }
  __syncthreads();

  if (tid < npg) s_mx[tid] = fdec(s_mxu[tid]);
  if (tid == 0) {
    int run = 0;
    for (int n = 0; n < npg; n++) { s_start[n] = run; run += s_cnt[n]; }
    s_start[npg] = run;
  }
  __syncthreads();

  float ex = 0.f;
  if (tid < EPG && ok) {
    ex = expf(lg - s_mx[dl]);
    atomicAdd(&s_den[dl], ex);
    int p = s_start[dl] + atomicAdd(&s_cur[dl], 1);
    s_list[p] = tid;
  }
  if (tid < npg) {
    float e2 = expf(slg - s_mx[tid]);
    s_self[tid] = e2;
    atomicAdd(&s_den[tid], e2);
  }
  __syncthreads();

  if (tid < EPG && ok) s_alpha[tid] = ex / s_den[dl];
  if (tid < npg) s_self[tid] = s_self[tid] / s_den[tid];
  __syncthreads();

  const int c = colb + (tid << 1);            // this thread's 2 global cols
  const float b0 = gbias[c], b1 = gbias[c + 1];
  const int kt = c >> 5;
  const int ch = (c >> 3) & 3;
  const int j2 = c & 7;                       // 0,2,4,6
  for (int n = 0; n < npg; n++) {
    const float2 v = *(const float2*)&sxl[(n << 9) + (tid << 1)];
    float a0 = s_self[n];
    float ax = a0 * v.x, ay = a0 * v.y;
    const int st = s_start[n], en = s_start[n + 1];
    for (int q = st; q < en; q++) {
      int e = s_list[q];
      float a = s_alpha[e];
      const float2 u = *(const float2*)&sxl[(s_srcl[e] << 9) + (tid << 1)];
      ax += a * u.x; ay += a * u.y;
    }
    ax += b0; ay += b1;
    const int R = base + n;
    const int c2 = ch ^ ((R >> 1) & 3);
    const size_t ad = ((size_t)kt * Mtot + R) * 32 + c2 * 8 + j2;
    f16x2 hh, ll;
    _Float16 h0 = (_Float16)ax; hh[0] = h0; ll[0] = (_Float16)(ax - (float)h0);
    _Float16 h1 = (_Float16)ay; hh[1] = h1; ll[1] = (_Float16)(ay - (float)h1);
    *(f16x2*)&ATh[ad] = hh;
    *(f16x2*)&ATl[ad] = ll;
  }
}

// ---------------- TopK pool: scores, stable sort, gate -> split fp16 A for next g-GEMM ----------------
__global__ __launch_bounds__(256) void pool_kernel(
    const float* __restrict__ hbuf, const float* __restrict__ scp,
    const int* __restrict__ cs, const int* __restrict__ cd, const int* __restrict__ cm,
    int npg, int k, int Mnext,
    _Float16* __restrict__ ATh, _Float16* __restrict__ ATl,
    float* __restrict__ gap,
    int* __restrict__ ns, int* __restrict__ nd, int* __restrict__ nm,
    const float* __restrict__ nrm, int stage)
{
  int g = blockIdx.x, tid = threadIdx.x;
  __shared__ float ssc[32];
  __shared__ int sord[32];
  __shared__ int snp[32];
  __shared__ float sgp[2][1024];
  if (tid < npg) {
    const float* sp = scp + (size_t)(g * npg + tid) * 16;
    float s = 0.f;
    #pragma unroll
    for (int q = 0; q < 16; q++) s += sp[q];
    ssc[tid] = tanhf(s / nrm[stage]);
  }
  __syncthreads();
  if (tid == 0) {
    for (int i = 0; i < npg; i++) sord[i] = i;
    for (int i = 1; i < npg; i++) {
      int oi = sord[i]; float v = ssc[oi]; int j = i - 1;
      while (j >= 0 && ssc[sord[j]] < v) { sord[j + 1] = sord[j]; j--; }
      sord[j + 1] = oi;
    }
  }
  __syncthreads();
  if (tid < npg) snp[tid] = -1;
  __syncthreads();
  if (tid < k) snp[sord[tid]] = tid;
  __syncthreads();

  const int col0 = (tid & 127) << 3;
  const int rr = tid >> 7;
  const int kt = col0 >> 5;
  const int ch = (col0 >> 3) & 3;
  float part[8];
  #pragma unroll
  for (int j = 0; j < 8; j++) part[j] = 0.f;
  for (int r = rr; r < k; r += 2) {
    int ol = sord[r];
    float s = ssc[ol];
    const float* hr = hbuf + (size_t)(g * npg + ol) * DD + col0;
    float4 v0 = *(const float4*)hr;
    float4 v1 = *(const float4*)(hr + 4);
    float gv[8] = {v0.x * s, v0.y * s, v0.z * s, v0.w * s,
                   v1.x * s, v1.y * s, v1.z * s, v1.w * s};
    #pragma unroll
    for (int j = 0; j < 8; j++) part[j] += gv[j];
    if (ATh) {
      int R = g * k + r;
      int c2 = ch ^ ((R >> 1) & 3);
      size_t ad = ((size_t)kt * Mnext + R) * 32 + c2 * 8;
      f16x8 hh, ll;
      #pragma unroll
      for (int j = 0; j < 8; j++) {
        _Float16 hv = (_Float16)gv[j];
        hh[j] = hv; ll[j] = (_Float16)(gv[j] - (float)hv);
      }
      *(f16x8*)&ATh[ad] = hh;
      *(f16x8*)&ATl[ad] = ll;
    }
  }
  #pragma unroll
  for (int j = 0; j < 8; j++) sgp[rr][col0 + j] = part[j];
  __syncthreads();
  const float fk = (float)k;
  #pragma unroll
  for (int j = 0; j < 4; j++) {
    int cc = tid * 4 + j;
    gap[(size_t)g * DD + cc] = (sgp[0][cc] + sgp[1][cc]) / fk;
  }

  for (int e = tid; e < EPG; e += 256) {
    int ei = g * EPG + e;
    int ok = cm ? cm[ei] : 1;
    int m2 = 0, a = 0, b2 = 0;
    if (ok) {
      int sl = cs[ei] - g * npg, dl = cd[ei] - g * npg;
      int nsl = snp[sl], ndl = snp[dl];
      if (nsl >= 0 && ndl >= 0) { m2 = 1; a = g * k + nsl; b2 = g * k + ndl; }
    }
    ns[ei] = a; nd[ei] = b2; nm[ei] = m2;
  }
}

__global__ __launch_bounds__(256) void zadd_kernel(
    const float* __restrict__ a, const float* __restrict__ b,
    const float* __restrict__ c, float* __restrict__ o)
{
  int i = blockIdx.x * 256 + threadIdx.x;
  o[i] = a[i] + b[i] + c[i];
}

__global__ __launch_bounds__(256) void l2_kernel(
    const float* __restrict__ z2, const float* __restrict__ w,
    const float* __restrict__ b, float* __restrict__ out)
{
  int row = (blockIdx.x * 256 + threadIdx.x) >> 6;
  int lane = threadIdx.x & 63;
  if (row >= 256) return;
  const float* r = z2 + (size_t)row * DD;
  float s = 0.f;
  #pragma unroll 4
  for (int i = lane; i < DD; i += 64) s += r[i] * w[i];
  #pragma unroll
  for (int off = 32; off; off >>= 1) s += __shfl_down(s, off);
  if (lane == 0) out[row] = s + b[0];
}

extern "C" void kernel_launch(void* const* d_in, const int* in_sizes, int n_in,
                              void* d_out, int out_size, void* d_ws, size_t ws_size,
                              hipStream_t stream)
{
  (void)in_sizes; (void)n_in; (void)out_size; (void)ws_size;
  const float* x    = (const float*)d_in[0];
  const int*   eidx = (const int*)d_in[2];
  const float* g1W = (const float*)d_in[4];
  const float* g1as= (const float*)d_in[5];
  const float* g1ad= (const float*)d_in[6];
  const float* g1b = (const float*)d_in[7];
  const float* t1W = (const float*)d_in[8];
  const float* t1b = (const float*)d_in[9];
  const float* p1  = (const float*)d_in[10];
  const float* g2W = (const float*)d_in[11];
  const float* g2as= (const float*)d_in[12];
  const float* g2ad= (const float*)d_in[13];
  const float* g2b = (const float*)d_in[14];
  const float* t2W = (const float*)d_in[15];
  const float* t2b = (const float*)d_in[16];
  const float* p2  = (const float*)d_in[17];
  const float* g3W = (const float*)d_in[18];
  const float* g3as= (const float*)d_in[19];
  const float* g3ad= (const float*)d_in[20];
  const float* g3b = (const float*)d_in[21];
  const float* t3W = (const float*)d_in[22];
  const float* t3b = (const float*)d_in[23];
  const float* p3  = (const float*)d_in[24];
  const float* l1W = (const float*)d_in[25];
  const float* l1b = (const float*)d_in[26];
  const float* l2W = (const float*)d_in[27];
  const float* l2b = (const float*)d_in[28];
  float* outp = (float*)d_out;

  float* W = (float*)d_ws;
  size_t o = 0;
  float* bufA = W + o; o += (size_t)8192 * HC;          // g-GEMM C (fp32)
  float* bufB = W + o; o += (size_t)8192 * DD;          // t-GEMM C (fp32)
  _Float16* ATh = (_Float16*)(W + o); o += (size_t)96 * 8192 * 32 / 2;  // split A (h)
  _Float16* ATl = (_Float16*)(W + o); o += (size_t)96 * 8192 * 32 / 2;  // split A (l)
  float* ALSp = W + o; o += 8192 * 48;
  float* ALDp = W + o; o += 8192 * 48;
  float* SCp  = W + o; o += 8192 * 16;
  float* NRM = W + o; o += 4;
  float* X1  = W + o; o += 256 * DD;
  float* X2  = W + o; o += 256 * DD;
  float* X3  = W + o; o += 256 * DD;
  float* ZB  = W + o; o += 256 * DD;
  float* Z2  = W + o; o += 256 * DD;
  int* E0s = (int*)(W + o); o += 40960;
  int* E0d = (int*)(W + o); o += 40960;
  int* E0m = (int*)(W + o); o += 40960;
  int* E1s = (int*)(W + o); o += 40960;
  int* E1d = (int*)(W + o); o += 40960;
  int* E1m = (int*)(W + o); o += 40960;
  _Float16* WTH = (_Float16*)(W + o); o += (3200 * 1024) / 2;
  _Float16* WTL = (_Float16*)(W + o); o += (3200 * 1024) / 2;

  const int* es1 = eidx;
  const int* ed1 = eidx + 40960;

  norm_kernel<<<3, 256, 0, stream>>>(p1, p2, p3, NRM);

  // -------- stage 1: M=8192, npg=32 -> k=26 --------
  xsplit_kernel<<<32, 256, 0, stream>>>(x, ATh, ATl, 8192);
  wtrans_kernel<<<dim3(96, 1), dim3(32, 8), 0, stream>>>(g1W, WTH, WTL, 30, HC);
  mfma_gemm<<<dim3(24, 64), 256, 0, stream>>>(ATh, ATl, WTH, WTL, nullptr, bufA, 8192, HC, 30,
                                              g1as, g1ad, ALSp, ALDp, nullptr, nullptr);
  gat_agg<<<dim3(256, 6), 256, 0, stream>>>(bufA, ALSp, ALDp, es1, ed1, nullptr, g1b,
                                            ATh, ATl, 32, 8192);
  wtrans_kernel<<<dim3(32, 96), dim3(32, 8), 0, stream>>>(t1W, WTH, WTL, HC, DD);
  mfma_gemm<<<dim3(8, 64), 256, 0, stream>>>(ATh, ATl, WTH, WTL, t1b, bufB, 8192, DD, HC,
                                             nullptr, nullptr, nullptr, nullptr, p1, SCp);
  pool_kernel<<<256, 256, 0, stream>>>(bufB, SCp, es1, ed1, nullptr, 32, 26, 6656,
                                       ATh, ATl, X1, E0s, E0d, E0m, NRM, 0);

  // -------- stage 2: M=6656, npg=26 -> k=13 --------
  wtrans_kernel<<<dim3(96, 32), dim3(32, 8), 0, stream>>>(g2W, WTH, WTL, DD, HC);
  mfma_gemm<<<dim3(24, 52), 256, 0, stream>>>(ATh, ATl, WTH, WTL, nullptr, bufA, 6656, HC, DD,
                                              g2as, g2ad, ALSp, ALDp, nullptr, nullptr);
  gat_agg<<<dim3(256, 6), 256, 0, stream>>>(bufA, ALSp, ALDp, E0s, E0d, E0m, g2b,
                                            ATh, ATl, 26, 6656);
  wtrans_kernel<<<dim3(32, 96), dim3(32, 8), 0, stream>>>(t2W, WTH, WTL, HC, DD);
  mfma_gemm<<<dim3(8, 52), 256, 0, stream>>>(ATh, ATl, WTH, WTL, t2b, bufB, 6656, DD, HC,
                                             nullptr, nullptr, nullptr, nullptr, p2, SCp);
  pool_kernel<<<256, 256, 0, stream>>>(bufB, SCp, E0s, E0d, E0m, 26, 13, 3328,
                                       ATh, ATl, X2, E1s, E1d, E1m, NRM, 1);

  // -------- stage 3: M=3328, npg=13 -> k=4 --------
  wtrans_kernel<<<dim3(96, 32), dim3(32, 8), 0, stream>>>(g3W, WTH, WTL, DD, HC);
  mfma_gemm<<<dim3(24, 26), 256, 0, stream>>>(ATh, ATl, WTH, WTL, nullptr, bufA, 3328, HC, DD,
                                              g3as, g3ad, ALSp, ALDp, nullptr, nullptr);
  gat_agg<<<dim3(256, 6), 256, 0, stream>>>(bufA, ALSp, ALDp, E1s, E1d, E1m, g3b,
                                            ATh, ATl, 13, 3328);
  wtrans_kernel<<<dim3(32, 96), dim3(32, 8), 0, stream>>>(t3W, WTH, WTL, HC, DD);
  mfma_gemm<<<dim3(8, 26), 256, 0, stream>>>(ATh, ATl, WTH, WTL, t3b, bufB, 3328, DD, HC,
                                             nullptr, nullptr, nullptr, nullptr, p3, SCp);
  pool_kernel<<<256, 256, 0, stream>>>(bufB, SCp, E1s, E1d, E1m, 13, 4, 1024,
                                       nullptr, nullptr, X3, E0s, E0d, E0m, NRM, 2);

  // -------- head --------
  zadd_kernel<<<1024, 256, 0, stream>>>(X1, X2, X3, ZB);
  sgemm_kernel<<<dim3(8, 2), 256, 0, stream>>>(ZB, l1W, l1b, Z2, 256, DD, DD, 1);
  l2_kernel<<<64, 256, 0, stream>>>(Z2, l2W, l2b, outp);
}

// Round 8
// 954.076 us; speedup vs baseline: 1.3958x; 1.0794x over previous
//
#include <hip/hip_runtime.h>
#include <cstdint>
#include <cstddef>

#define EPG 160
#define HC  3072
#define DD  1024

typedef _Float16 f16x8 __attribute__((ext_vector_type(8)));
typedef _Float16 f16x2 __attribute__((ext_vector_type(2)));
typedef float    f32x4 __attribute__((ext_vector_type(4)));

__device__ __forceinline__ unsigned fenc(float f){
  unsigned u = __float_as_uint(f);
  return (u & 0x80000000u) ? ~u : (u | 0x80000000u);
}
__device__ __forceinline__ float fdec(unsigned u){
  return (u & 0x80000000u) ? __uint_as_float(u ^ 0x80000000u) : __uint_as_float(~u);
}

__device__ __forceinline__ void gload16(const void* g, void* l) {
  __builtin_amdgcn_global_load_lds((const __attribute__((address_space(1))) void*)g,
                                   (__attribute__((address_space(3))) void*)l, 16, 0, 0);
}

// ---------------- weight transpose + fp16 split ----------------
// W[K][Nn] fp32 -> WTh/WTl as [K/32 tiles][Nn rows][32 halfs]; 16B chunks pre-swizzled
// at c ^ ((n>>1)&3) so global_load_lds writes linearly while GEMM reads swizzled.
__global__ __launch_bounds__(256) void wtrans_kernel(
    const float* __restrict__ W, _Float16* __restrict__ WTh, _Float16* __restrict__ WTl,
    int K, int Nn)
{
  __shared__ float t[32][33];
  const int tx = threadIdx.x, ty = threadIdx.y;
  const int n0 = blockIdx.x * 32, k0 = blockIdx.y * 32;
  #pragma unroll
  for (int i = 0; i < 4; i++) {
    int k = k0 + ty + i * 8;
    t[ty + i * 8][tx] = (k < K) ? W[(size_t)k * Nn + n0 + tx] : 0.f;
  }
  __syncthreads();
  const int kt = k0 >> 5;
  const int c  = tx >> 3;
  const int w8 = tx & 7;
  #pragma unroll
  for (int i = 0; i < 4; i++) {
    int n = n0 + ty + i * 8;
    float v = t[tx][ty + i * 8];
    _Float16 h = (_Float16)v;
    float r = v - (float)h;
    int c2 = c ^ ((n >> 1) & 3);
    size_t addr = ((size_t)kt * Nn + n) * 32 + c2 * 8 + w8;
    WTh[addr] = h;
    WTl[addr] = (_Float16)r;
  }
}

// ---------------- split input x into pre-swizzled fp16 h/l (K=30 padded to 32) ----------------
__global__ __launch_bounds__(256) void xsplit_kernel(
    const float* __restrict__ x, _Float16* __restrict__ ATh, _Float16* __restrict__ ATl, int M)
{
  int r = blockIdx.x * 256 + threadIdx.x;
  if (r >= M) return;
  const float* xr = x + (size_t)r * 30;
  float v[32];
  #pragma unroll
  for (int j = 0; j < 32; j++) v[j] = (j < 30) ? xr[j] : 0.f;
  const int sz = (r >> 1) & 3;
  #pragma unroll
  for (int ch = 0; ch < 4; ch++) {
    int c2 = ch ^ sz;
    f16x8 hh, ll;
    #pragma unroll
    for (int j = 0; j < 8; j++) {
      float vv = v[ch * 8 + j];
      _Float16 hv = (_Float16)vv;
      hh[j] = hv; ll[j] = (_Float16)(vv - (float)hv);
    }
    *(f16x8*)&ATh[(size_t)r * 32 + c2 * 8] = hh;
    *(f16x8*)&ATl[(size_t)r * 32 + c2 * 8] = ll;
  }
}

// ---------------- split-fp16 MFMA GEMM: 128x128 tile, 4 waves, 2-deep counted-vmcnt ----------------
__global__ __launch_bounds__(256) void mfma_gemm(
    const _Float16* __restrict__ ATh, const _Float16* __restrict__ ATl,
    const _Float16* __restrict__ BTh, const _Float16* __restrict__ BTl,
    const float* __restrict__ bias, float* __restrict__ C,
    int M, int N, int K,
    const float* __restrict__ avs, const float* __restrict__ avd,
    float* __restrict__ alsp, float* __restrict__ aldp,
    const float* __restrict__ pvec, float* __restrict__ scp)
{
  // per 32KB buffer: Ah +0, Al +8192, Bh +16384, Bl +24576
  __shared__ __align__(16) char smem[2 * 32768];

  const int gx = N >> 7, gy = M >> 7;
  const int lid = blockIdx.x + gx * blockIdx.y;
  int vx, vy;
  const int G = gy & ~7;
  if (lid < gx * G) {
    const int sub = lid & 7, rest = lid >> 3;
    vx = rest % gx; vy = (rest / gx) * 8 + sub;
  } else {
    const int r = lid - gx * G;
    vx = r % gx; vy = G + r / gx;
  }
  const int brow = vy << 7, bcol = vx << 7;

  const int tid  = threadIdx.x;
  const int lane = tid & 63;
  const int w    = tid >> 6;          // 0..3
  const int wr   = (w >> 1) << 6, wc = (w & 1) << 6;
  const int wn   = w & 1;
  const int fr   = lane & 15, g4 = lane >> 4;

  f32x4 acc[4][4];
  #pragma unroll
  for (int m = 0; m < 4; m++)
    #pragma unroll
    for (int n = 0; n < 4; n++) acc[m][n] = (f32x4)0.0f;

  int aoff[4], boff[4];
  #pragma unroll
  for (int m = 0; m < 4; m++) {
    int r = wr + m * 16 + fr;
    aoff[m] = r * 64 + ((g4 ^ ((r >> 1) & 3)) << 4);
  }
  #pragma unroll
  for (int n = 0; n < 4; n++) {
    int r = wc + n * 16 + fr;
    boff[n] = r * 64 + ((g4 ^ ((r >> 1) & 3)) << 4);
  }

  const int ktiles = (K + 31) >> 5;

#define STAGE(ktv, buf)                                                    \
  do {                                                                     \
    char* bse = (buf);                                                     \
    const size_t ab = ((size_t)(ktv) * M + brow) << 6;                     \
    const size_t bb = ((size_t)(ktv) * N + bcol) << 6;                     \
    const char* gah = (const char*)ATh + ab + tid * 16;                    \
    const char* gal = (const char*)ATl + ab + tid * 16;                    \
    const char* gbh = (const char*)BTh + bb + tid * 16;                    \
    const char* gbl = (const char*)BTl + bb + tid * 16;                    \
    gload16(gah,        bse + tid * 16);                                   \
    gload16(gah + 4096, bse + tid * 16 + 4096);                            \
    gload16(gal,        bse + 8192 + tid * 16);                            \
    gload16(gal + 4096, bse + 8192 + tid * 16 + 4096);                     \
    gload16(gbh,        bse + 16384 + tid * 16);                           \
    gload16(gbh + 4096, bse + 16384 + tid * 16 + 4096);                    \
    gload16(gbl,        bse + 24576 + tid * 16);                           \
    gload16(gbl + 4096, bse + 24576 + tid * 16 + 4096);                    \
  } while (0)

  STAGE(0, smem);
  if (ktiles > 1) STAGE(1, smem + 32768);

  for (int kt = 0; kt < ktiles; kt++) {
    char* curb = smem + ((kt & 1) << 15);
    if (kt + 1 < ktiles) {
      asm volatile("s_waitcnt vmcnt(8)" ::: "memory");   // tile kt's 8 loads landed
    } else {
      asm volatile("s_waitcnt vmcnt(0)" ::: "memory");
    }
    __builtin_amdgcn_s_barrier();      // tile kt visible block-wide
    asm volatile("" ::: "memory");

    f16x8 ah[4], al[4], bh[4], bl[4];
    #pragma unroll
    for (int n = 0; n < 4; n++) {
      bh[n] = *(const f16x8*)(curb + 16384 + boff[n]);
      bl[n] = *(const f16x8*)(curb + 24576 + boff[n]);
    }
    #pragma unroll
    for (int m = 0; m < 4; m++) {
      ah[m] = *(const f16x8*)(curb + aoff[m]);
      al[m] = *(const f16x8*)(curb + 8192 + aoff[m]);
    }
    asm volatile("s_waitcnt lgkmcnt(0)" ::: "memory");   // this wave's LDS reads retired
    __builtin_amdgcn_sched_barrier(0);
    __builtin_amdgcn_s_barrier();      // all waves done reading curb -> safe to overwrite
    asm volatile("" ::: "memory");

    if (kt + 2 < ktiles) STAGE(kt + 2, curb);  // hides under the MFMA cluster below

    __builtin_amdgcn_s_setprio(1);
    #pragma unroll
    for (int m = 0; m < 4; m++) {
      #pragma unroll
      for (int n = 0; n < 4; n++) {
        acc[m][n] = __builtin_amdgcn_mfma_f32_16x16x32_f16(ah[m], bh[n], acc[m][n], 0, 0, 0);
        acc[m][n] = __builtin_amdgcn_mfma_f32_16x16x32_f16(al[m], bh[n], acc[m][n], 0, 0, 0);
        acc[m][n] = __builtin_amdgcn_mfma_f32_16x16x32_f16(ah[m], bl[n], acc[m][n], 0, 0, 0);
      }
    }
    __builtin_amdgcn_s_setprio(0);
    asm volatile("" ::: "memory");
  }
#undef STAGE

  // ---- epilogue: C/D layout col=lane&15, row=(lane>>4)*4+q ----
  const int crow0 = brow + wr + g4 * 4;
  const int ccol0 = bcol + wc + fr;
  #pragma unroll
  for (int n = 0; n < 4; n++) {
    const int col = ccol0 + n * 16;
    const float bv = bias ? bias[col] : 0.f;
    #pragma unroll
    for (int m = 0; m < 4; m++) {
      const int row = crow0 + m * 16;
      #pragma unroll
      for (int q = 0; q < 4; q++)
        C[(size_t)(row + q) * N + col] = acc[m][n][q] + bv;
    }
  }

  // ---- deterministic fused attention-dot partials (g-GEMMs, N=3072) ----
  if (alsp) {
    const int h3 = bcol >> 10;
    const int slot = ((bcol & 1023) >> 6) + wn;   // 16 strips of 64 cols per head
    #pragma unroll
    for (int m = 0; m < 4; m++) {
      #pragma unroll
      for (int q = 0; q < 4; q++) {
        float ps = 0.f, pd = 0.f;
        #pragma unroll
        for (int n = 0; n < 4; n++) {
          const int col = ccol0 + n * 16;
          const float v = acc[m][n][q];
          ps += v * avs[col]; pd += v * avd[col];
        }
        #pragma unroll
        for (int mk = 1; mk <= 8; mk <<= 1) {
          ps += __shfl_xor(ps, mk);
          pd += __shfl_xor(pd, mk);
        }
        if (fr == 0) {
          const int row = crow0 + m * 16 + q;
          alsp[row * 48 + h3 * 16 + slot] = ps;
          aldp[row * 48 + h3 * 16 + slot] = pd;
        }
      }
    }
  }
  // ---- deterministic fused score-dot partials (t-GEMMs, N=1024) ----
  if (scp) {
    const int slot = (bcol >> 6) + wn;            // 16 strips of 64 cols
    #pragma unroll
    for (int m = 0; m < 4; m++) {
      #pragma unroll
      for (int q = 0; q < 4; q++) {
        float pp = 0.f;
        #pragma unroll
        for (int n = 0; n < 4; n++) {
          const int col = ccol0 + n * 16;
          pp += (acc[m][n][q] + bias[col]) * pvec[col];
        }
        #pragma unroll
        for (int mk = 1; mk <= 8; mk <<= 1) pp += __shfl_xor(pp, mk);
        if (fr == 0) scp[(crow0 + m * 16 + q) * 16 + slot] = pp;
      }
    }
  }
}

// ---------------- ||p_i|| ----------------
__global__ __launch_bounds__(256) void norm_kernel(
    const float* __restrict__ p1, const float* __restrict__ p2,
    const float* __restrict__ p3, float* __restrict__ nrm)
{
  const float* p = blockIdx.x == 0 ? p1 : (blockIdx.x == 1 ? p2 : p3);
  __shared__ float red[4];
  int tid = threadIdx.x;
  float s = 0.f;
  for (int i = tid; i < DD; i += 256) { float v = p[i]; s += v * v; }
  #pragma unroll
  for (int off = 32; off; off >>= 1) s += __shfl_down(s, off);
  if ((tid & 63) == 0) red[tid >> 6] = s;
  __syncthreads();
  if (tid == 0) nrm[blockIdx.x] = sqrtf(red[0] + red[1] + red[2] + red[3]);
}

// ---------------- fused GAT attention + aggregation (column-half blocks, 2/CU) --------------
__global__ __launch_bounds__(256) void gat_agg(
    const float* __restrict__ xl, const float* __restrict__ alsp, const float* __restrict__ aldp,
    const int* __restrict__ esrc, const int* __restrict__ edst, const int* __restrict__ emask,
    const float* __restrict__ gbias, _Float16* __restrict__ ATh, _Float16* __restrict__ ATl,
    int npg, int Mtot)
{
  const int g = blockIdx.x;
  const int h = blockIdx.y >> 1;
  const int half = blockIdx.y & 1;
  const int tid = threadIdx.x;
  const int base = g * npg;
  __shared__ float sxl[32 * 512];        // 64KB -> 2 blocks/CU
  __shared__ float s_as[32], s_ad[32], s_mx[32], s_den[32], s_self[32];
  __shared__ unsigned s_mxu[32];
  __shared__ float s_alpha[EPG];
  __shared__ int s_srcl[EPG];
  __shared__ int s_start[33];
  __shared__ int s_cnt[32], s_cur[32];
  __shared__ int s_list[EPG];

  const int colb = h * DD + (half << 9);
  for (int n = 0; n < npg; n++) {
    *(float2*)&sxl[(n << 9) + (tid << 1)] =
        *(const float2*)&xl[(size_t)(base + n) * HC + colb + (tid << 1)];
  }

  if (tid < npg) {
    const float* ps = alsp + (size_t)(base + tid) * 48 + h * 16;
    const float* pdp = aldp + (size_t)(base + tid) * 48 + h * 16;
    float ss = 0.f, dd2 = 0.f;
    #pragma unroll
    for (int s = 0; s < 16; s++) { ss += ps[s]; dd2 += pdp[s]; }
    s_as[tid] = ss;
    s_ad[tid] = dd2;
    s_mxu[tid] = 0u;
    s_den[tid] = 0.f;
    s_cnt[tid] = 0;
    s_cur[tid] = 0;
  }
  __syncthreads();

  int ok = 0, dl = 0;
  float lg = 0.f;
  if (tid < EPG) {
    int ei = g * EPG + tid;
    ok = emask ? emask[ei] : 1;
    if (ok) {
      int sl = esrc[ei] - base;
      dl = edst[ei] - base;
      s_srcl[tid] = sl;
      float v = s_as[sl] + s_ad[dl];
      lg = v > 0.f ? v : 0.2f * v;
      atomicMax(&s_mxu[dl], fenc(lg));
      atomicAdd(&s_cnt[dl], 1);
    }
  }
  float slg = 0.f;
  if (tid < npg) {
    float v = s_as[tid] + s_ad[tid];
    slg = v > 0.f ? v : 0.2f * v;
    atomicMax(&s_mxu[tid], fenc(slg));
  }
  __syncthreads();

  if (tid < npg) s_mx[tid] = fdec(s_mxu[tid]);
  if (tid == 0) {
    int run = 0;
    for (int n = 0; n < npg; n++) { s_start[n] = run; run += s_cnt[n]; }
    s_start[npg] = run;
  }
  __syncthreads();

  float ex = 0.f;
  if (tid < EPG && ok) {
    ex = expf(lg - s_mx[dl]);
    atomicAdd(&s_den[dl], ex);
    int p = s_start[dl] + atomicAdd(&s_cur[dl], 1);
    s_list[p] = tid;
  }
  if (tid < npg) {
    float e2 = expf(slg - s_mx[tid]);
    s_self[tid] = e2;
    atomicAdd(&s_den[tid], e2);
  }
  __syncthreads();

  if (tid < EPG && ok) s_alpha[tid] = ex / s_den[dl];
  if (tid < npg) s_self[tid] = s_self[tid] / s_den[tid];
  __syncthreads();

  const int c = colb + (tid << 1);
  const float b0 = gbias[c], b1 = gbias[c + 1];
  const int kt = c >> 5;
  const int ch = (c >> 3) & 3;
  const int j2 = c & 7;
  for (int n = 0; n < npg; n++) {
    const float2 v = *(const float2*)&sxl[(n << 9) + (tid << 1)];
    float a0 = s_self[n];
    float ax = a0 * v.x, ay = a0 * v.y;
    const int st = s_start[n], en = s_start[n + 1];
    for (int q = st; q < en; q++) {
      int e = s_list[q];
      float a = s_alpha[e];
      const float2 u = *(const float2*)&sxl[(s_srcl[e] << 9) + (tid << 1)];
      ax += a * u.x; ay += a * u.y;
    }
    ax += b0; ay += b1;
    const int R = base + n;
    const int c2 = ch ^ ((R >> 1) & 3);
    const size_t ad = ((size_t)kt * Mtot + R) * 32 + c2 * 8 + j2;
    f16x2 hh, ll;
    _Float16 h0 = (_Float16)ax; hh[0] = h0; ll[0] = (_Float16)(ax - (float)h0);
    _Float16 h1 = (_Float16)ay; hh[1] = h1; ll[1] = (_Float16)(ay - (float)h1);
    *(f16x2*)&ATh[ad] = hh;
    *(f16x2*)&ATl[ad] = ll;
  }
}

// ---------------- TopK pool: scores, stable sort, gate -> split fp16 A for next g-GEMM ----------------
__global__ __launch_bounds__(256) void pool_kernel(
    const float* __restrict__ hbuf, const float* __restrict__ scp,
    const int* __restrict__ cs, const int* __restrict__ cd, const int* __restrict__ cm,
    int npg, int k, int Mnext,
    _Float16* __restrict__ ATh, _Float16* __restrict__ ATl,
    float* __restrict__ gap,
    int* __restrict__ ns, int* __restrict__ nd, int* __restrict__ nm,
    const float* __restrict__ nrm, int stage)
{
  int g = blockIdx.x, tid = threadIdx.x;
  __shared__ float ssc[32];
  __shared__ int sord[32];
  __shared__ int snp[32];
  __shared__ float sgp[2][1024];
  if (tid < npg) {
    const float* sp = scp + (size_t)(g * npg + tid) * 16;
    float s = 0.f;
    #pragma unroll
    for (int q = 0; q < 16; q++) s += sp[q];
    ssc[tid] = tanhf(s / nrm[stage]);
  }
  __syncthreads();
  if (tid == 0) {
    for (int i = 0; i < npg; i++) sord[i] = i;
    for (int i = 1; i < npg; i++) {
      int oi = sord[i]; float v = ssc[oi]; int j = i - 1;
      while (j >= 0 && ssc[sord[j]] < v) { sord[j + 1] = sord[j]; j--; }
      sord[j + 1] = oi;
    }
  }
  __syncthreads();
  if (tid < npg) snp[tid] = -1;
  __syncthreads();
  if (tid < k) snp[sord[tid]] = tid;
  __syncthreads();

  const int col0 = (tid & 127) << 3;
  const int rr = tid >> 7;
  const int kt = col0 >> 5;
  const int ch = (col0 >> 3) & 3;
  float part[8];
  #pragma unroll
  for (int j = 0; j < 8; j++) part[j] = 0.f;
  for (int r = rr; r < k; r += 2) {
    int ol = sord[r];
    float s = ssc[ol];
    const float* hr = hbuf + (size_t)(g * npg + ol) * DD + col0;
    float4 v0 = *(const float4*)hr;
    float4 v1 = *(const float4*)(hr + 4);
    float gv[8] = {v0.x * s, v0.y * s, v0.z * s, v0.w * s,
                   v1.x * s, v1.y * s, v1.z * s, v1.w * s};
    #pragma unroll
    for (int j = 0; j < 8; j++) part[j] += gv[j];
    if (ATh) {
      int R = g * k + r;
      int c2 = ch ^ ((R >> 1) & 3);
      size_t ad = ((size_t)kt * Mnext + R) * 32 + c2 * 8;
      f16x8 hh, ll;
      #pragma unroll
      for (int j = 0; j < 8; j++) {
        _Float16 hv = (_Float16)gv[j];
        hh[j] = hv; ll[j] = (_Float16)(gv[j] - (float)hv);
      }
      *(f16x8*)&ATh[ad] = hh;
      *(f16x8*)&ATl[ad] = ll;
    }
  }
  #pragma unroll
  for (int j = 0; j < 8; j++) sgp[rr][col0 + j] = part[j];
  __syncthreads();
  const float fk = (float)k;
  #pragma unroll
  for (int j = 0; j < 4; j++) {
    int cc = tid * 4 + j;
    gap[(size_t)g * DD + cc] = (sgp[0][cc] + sgp[1][cc]) / fk;
  }

  for (int e = tid; e < EPG; e += 256) {
    int ei = g * EPG + e;
    int ok = cm ? cm[ei] : 1;
    int m2 = 0, a = 0, b2 = 0;
    if (ok) {
      int sl = cs[ei] - g * npg, dl = cd[ei] - g * npg;
      int nsl = snp[sl], ndl = snp[dl];
      if (nsl >= 0 && ndl >= 0) { m2 = 1; a = g * k + nsl; b2 = g * k + ndl; }
    }
    ns[ei] = a; nd[ei] = b2; nm[ei] = m2;
  }
}

// ---------------- fused head: z=X1+X2+X3; z2=relu(z@l1W+b); partial dot with l2W ----------------
// grid (4 colgroups, 64 rowgroups), 256 threads. partial[row*4+cg], deterministic.
__global__ __launch_bounds__(256) void head_kernel(
    const float* __restrict__ X1, const float* __restrict__ X2, const float* __restrict__ X3,
    const float* __restrict__ l1W, const float* __restrict__ l1b,
    const float* __restrict__ l2W, float* __restrict__ partial)
{
  __shared__ float a[4][1024];
  __shared__ float red[4][4];            // [wave][row]
  const int tid = threadIdx.x;
  const int cg = blockIdx.x, rg = blockIdx.y;
  const int row0 = rg << 2;
  #pragma unroll
  for (int r = 0; r < 4; r++) {
    const size_t ro = (size_t)(row0 + r) << 10;
    #pragma unroll
    for (int jj = 0; jj < 4; jj++) {
      int j = tid + jj * 256;
      a[r][j] = X1[ro + j] + X2[ro + j] + X3[ro + j];
    }
  }
  __syncthreads();

  const int col = (cg << 8) + tid;
  float acc0 = 0.f, acc1 = 0.f, acc2 = 0.f, acc3 = 0.f;
  #pragma unroll 8
  for (int k = 0; k < 1024; k++) {
    float wv = l1W[((size_t)k << 10) + col];
    acc0 += a[0][k] * wv;
    acc1 += a[1][k] * wv;
    acc2 += a[2][k] * wv;
    acc3 += a[3][k] * wv;
  }
  const float bv = l1b[col], lw = l2W[col];
  float v0 = fmaxf(acc0 + bv, 0.f) * lw;
  float v1 = fmaxf(acc1 + bv, 0.f) * lw;
  float v2 = fmaxf(acc2 + bv, 0.f) * lw;
  float v3 = fmaxf(acc3 + bv, 0.f) * lw;
  #pragma unroll
  for (int off = 32; off; off >>= 1) {
    v0 += __shfl_down(v0, off);
    v1 += __shfl_down(v1, off);
    v2 += __shfl_down(v2, off);
    v3 += __shfl_down(v3, off);
  }
  const int lane = tid & 63, wid = tid >> 6;
  if (lane == 0) { red[wid][0] = v0; red[wid][1] = v1; red[wid][2] = v2; red[wid][3] = v3; }
  __syncthreads();
  if (tid < 4)
    partial[(size_t)(row0 + tid) * 4 + cg] =
        red[0][tid] + red[1][tid] + red[2][tid] + red[3][tid];
}

__global__ __launch_bounds__(256) void head2_kernel(
    const float* __restrict__ partial, const float* __restrict__ l2b,
    float* __restrict__ out)
{
  int r = threadIdx.x;
  out[r] = partial[r * 4 + 0] + partial[r * 4 + 1] +
           partial[r * 4 + 2] + partial[r * 4 + 3] + l2b[0];
}

extern "C" void kernel_launch(void* const* d_in, const int* in_sizes, int n_in,
                              void* d_out, int out_size, void* d_ws, size_t ws_size,
                              hipStream_t stream)
{
  (void)in_sizes; (void)n_in; (void)out_size; (void)ws_size;
  const float* x    = (const float*)d_in[0];
  const int*   eidx = (const int*)d_in[2];
  const float* g1W = (const float*)d_in[4];
  const float* g1as= (const float*)d_in[5];
  const float* g1ad= (const float*)d_in[6];
  const float* g1b = (const float*)d_in[7];
  const float* t1W = (const float*)d_in[8];
  const float* t1b = (const float*)d_in[9];
  const float* p1  = (const float*)d_in[10];
  const float* g2W = (const float*)d_in[11];
  const float* g2as= (const float*)d_in[12];
  const float* g2ad= (const float*)d_in[13];
  const float* g2b = (const float*)d_in[14];
  const float* t2W = (const float*)d_in[15];
  const float* t2b = (const float*)d_in[16];
  const float* p2  = (const float*)d_in[17];
  const float* g3W = (const float*)d_in[18];
  const float* g3as= (const float*)d_in[19];
  const float* g3ad= (const float*)d_in[20];
  const float* g3b = (const float*)d_in[21];
  const float* t3W = (const float*)d_in[22];
  const float* t3b = (const float*)d_in[23];
  const float* p3  = (const float*)d_in[24];
  const float* l1W = (const float*)d_in[25];
  const float* l1b = (const float*)d_in[26];
  const float* l2W = (const float*)d_in[27];
  const float* l2b = (const float*)d_in[28];
  float* outp = (float*)d_out;

  float* W = (float*)d_ws;
  size_t o = 0;
  float* bufA = W + o; o += (size_t)8192 * HC;          // g-GEMM C (fp32)
  float* bufB = W + o; o += (size_t)8192 * DD;          // t-GEMM C (fp32)
  _Float16* ATh = (_Float16*)(W + o); o += (size_t)96 * 8192 * 32 / 2;  // split A (h)
  _Float16* ATl = (_Float16*)(W + o); o += (size_t)96 * 8192 * 32 / 2;  // split A (l)
  float* ALSp = W + o; o += 8192 * 48;
  float* ALDp = W + o; o += 8192 * 48;
  float* SCp  = W + o; o += 8192 * 16;
  float* NRM = W + o; o += 4;
  float* X1  = W + o; o += 256 * DD;
  float* X2  = W + o; o += 256 * DD;
  float* X3  = W + o; o += 256 * DD;
  float* HP  = W + o; o += 256 * 4;                      // head partials
  int* E0s = (int*)(W + o); o += 40960;
  int* E0d = (int*)(W + o); o += 40960;
  int* E0m = (int*)(W + o); o += 40960;
  int* E1s = (int*)(W + o); o += 40960;
  int* E1d = (int*)(W + o); o += 40960;
  int* E1m = (int*)(W + o); o += 40960;
  _Float16* WTH = (_Float16*)(W + o); o += (3200 * 1024) / 2;
  _Float16* WTL = (_Float16*)(W + o); o += (3200 * 1024) / 2;

  const int* es1 = eidx;
  const int* ed1 = eidx + 40960;

  norm_kernel<<<3, 256, 0, stream>>>(p1, p2, p3, NRM);

  // -------- stage 1: M=8192, npg=32 -> k=26 --------
  xsplit_kernel<<<32, 256, 0, stream>>>(x, ATh, ATl, 8192);
  wtrans_kernel<<<dim3(96, 1), dim3(32, 8), 0, stream>>>(g1W, WTH, WTL, 30, HC);
  mfma_gemm<<<dim3(24, 64), 256, 0, stream>>>(ATh, ATl, WTH, WTL, nullptr, bufA, 8192, HC, 30,
                                              g1as, g1ad, ALSp, ALDp, nullptr, nullptr);
  gat_agg<<<dim3(256, 6), 256, 0, stream>>>(bufA, ALSp, ALDp, es1, ed1, nullptr, g1b,
                                            ATh, ATl, 32, 8192);
  wtrans_kernel<<<dim3(32, 96), dim3(32, 8), 0, stream>>>(t1W, WTH, WTL, HC, DD);
  mfma_gemm<<<dim3(8, 64), 256, 0, stream>>>(ATh, ATl, WTH, WTL, t1b, bufB, 8192, DD, HC,
                                             nullptr, nullptr, nullptr, nullptr, p1, SCp);
  pool_kernel<<<256, 256, 0, stream>>>(bufB, SCp, es1, ed1, nullptr, 32, 26, 6656,
                                       ATh, ATl, X1, E0s, E0d, E0m, NRM, 0);

  // -------- stage 2: M=6656, npg=26 -> k=13 --------
  wtrans_kernel<<<dim3(96, 32), dim3(32, 8), 0, stream>>>(g2W, WTH, WTL, DD, HC);
  mfma_gemm<<<dim3(24, 52), 256, 0, stream>>>(ATh, ATl, WTH, WTL, nullptr, bufA, 6656, HC, DD,
                                              g2as, g2ad, ALSp, ALDp, nullptr, nullptr);
  gat_agg<<<dim3(256, 6), 256, 0, stream>>>(bufA, ALSp, ALDp, E0s, E0d, E0m, g2b,
                                            ATh, ATl, 26, 6656);
  wtrans_kernel<<<dim3(32, 96), dim3(32, 8), 0, stream>>>(t2W, WTH, WTL, HC, DD);
  mfma_gemm<<<dim3(8, 52), 256, 0, stream>>>(ATh, ATl, WTH, WTL, t2b, bufB, 6656, DD, HC,
                                             nullptr, nullptr, nullptr, nullptr, p2, SCp);
  pool_kernel<<<256, 256, 0, stream>>>(bufB, SCp, E0s, E0d, E0m, 26, 13, 3328,
                                       ATh, ATl, X2, E1s, E1d, E1m, NRM, 1);

  // -------- stage 3: M=3328, npg=13 -> k=4 --------
  wtrans_kernel<<<dim3(96, 32), dim3(32, 8), 0, stream>>>(g3W, WTH, WTL, DD, HC);
  mfma_gemm<<<dim3(24, 26), 256, 0, stream>>>(ATh, ATl, WTH, WTL, nullptr, bufA, 3328, HC, DD,
                                              g3as, g3ad, ALSp, ALDp, nullptr, nullptr);
  gat_agg<<<dim3(256, 6), 256, 0, stream>>>(bufA, ALSp, ALDp, E1s, E1d, E1m, g3b,
                                            ATh, ATl, 13, 3328);
  wtrans_kernel<<<dim3(32, 96), dim3(32, 8), 0, stream>>>(t3W, WTH, WTL, HC, DD);
  mfma_gemm<<<dim3(8, 26), 256, 0, stream>>>(ATh, ATl, WTH, WTL, t3b, bufB, 3328, DD, HC,
                                             nullptr, nullptr, nullptr, nullptr, p3, SCp);
  pool_kernel<<<256, 256, 0, stream>>>(bufB, SCp, E1s, E1d, E1m, 13, 4, 1024,
                                       nullptr, nullptr, X3, E0s, E0d, E0m, NRM, 2);

  // -------- fused head --------
  head_kernel<<<dim3(4, 64), 256, 0, stream>>>(X1, X2, X3, l1W, l1b, l2W, HP);
  head2_kernel<<<1, 256, 0, stream>>>(HP, l2b, outp);
}

// Round 9
// 946.775 us; speedup vs baseline: 1.4066x; 1.0077x over previous
//
#include <hip/hip_runtime.h>
#include <cstdint>
#include <cstddef>

#define EPG 160
#define HC  3072
#define DD  1024

typedef _Float16 f16x8 __attribute__((ext_vector_type(8)));
typedef _Float16 f16x2 __attribute__((ext_vector_type(2)));
typedef float    f32x4 __attribute__((ext_vector_type(4)));

__device__ __forceinline__ unsigned fenc(float f){
  unsigned u = __float_as_uint(f);
  return (u & 0x80000000u) ? ~u : (u | 0x80000000u);
}
__device__ __forceinline__ float fdec(unsigned u){
  return (u & 0x80000000u) ? __uint_as_float(u ^ 0x80000000u) : __uint_as_float(~u);
}

__device__ __forceinline__ void gload16(const void* g, void* l) {
  __builtin_amdgcn_global_load_lds((const __attribute__((address_space(1))) void*)g,
                                   (__attribute__((address_space(3))) void*)l, 16, 0, 0);
}

// ---------------- weight transpose + fp16 split ----------------
// W[K][Nn] fp32 -> WTh/WTl as [K/32 tiles][Nn rows][32 halfs]; 16B chunks pre-swizzled
// at c ^ ((n>>1)&3) so global_load_lds writes linearly while GEMM reads swizzled.
__global__ __launch_bounds__(256) void wtrans_kernel(
    const float* __restrict__ W, _Float16* __restrict__ WTh, _Float16* __restrict__ WTl,
    int K, int Nn)
{
  __shared__ float t[32][33];
  const int tx = threadIdx.x, ty = threadIdx.y;
  const int n0 = blockIdx.x * 32, k0 = blockIdx.y * 32;
  #pragma unroll
  for (int i = 0; i < 4; i++) {
    int k = k0 + ty + i * 8;
    t[ty + i * 8][tx] = (k < K) ? W[(size_t)k * Nn + n0 + tx] : 0.f;
  }
  __syncthreads();
  const int kt = k0 >> 5;
  const int c  = tx >> 3;
  const int w8 = tx & 7;
  #pragma unroll
  for (int i = 0; i < 4; i++) {
    int n = n0 + ty + i * 8;
    float v = t[tx][ty + i * 8];
    _Float16 h = (_Float16)v;
    float r = v - (float)h;
    int c2 = c ^ ((n >> 1) & 3);
    size_t addr = ((size_t)kt * Nn + n) * 32 + c2 * 8 + w8;
    WTh[addr] = h;
    WTl[addr] = (_Float16)r;
  }
}

// ---------------- prep: ||p_i|| and w_as/w_ad = g1W . a_{src,dst} per head ----------------
// grid 9: b<3 -> nrm[b]; b in 3..8 -> (h=(b-3)>>1, sel=(b-3)&1) 30-vector.
__global__ __launch_bounds__(256) void prep_kernel(
    const float* __restrict__ p1, const float* __restrict__ p2, const float* __restrict__ p3,
    const float* __restrict__ g1W, const float* __restrict__ g1as, const float* __restrict__ g1ad,
    float* __restrict__ nrm, float* __restrict__ was, float* __restrict__ wad)
{
  const int b = blockIdx.x;
  const int tid = threadIdx.x;
  __shared__ float red[4];
  if (b < 3) {
    const float* p = b == 0 ? p1 : (b == 1 ? p2 : p3);
    float s = 0.f;
    for (int i = tid; i < DD; i += 256) { float v = p[i]; s += v * v; }
    #pragma unroll
    for (int off = 32; off; off >>= 1) s += __shfl_down(s, off);
    if ((tid & 63) == 0) red[tid >> 6] = s;
    __syncthreads();
    if (tid == 0) nrm[b] = sqrtf(red[0] + red[1] + red[2] + red[3]);
  } else {
    const int idx = b - 3;
    const int h = idx >> 1;
    const float* av = (idx & 1) ? g1ad : g1as;
    float* outv = (idx & 1) ? wad : was;
    for (int j = 0; j < 30; j++) {
      float s = 0.f;
      for (int c = tid; c < DD; c += 256)
        s += g1W[(size_t)j * HC + h * DD + c] * av[h * DD + c];
      #pragma unroll
      for (int off = 32; off; off >>= 1) s += __shfl_down(s, off);
      if ((tid & 63) == 0) red[tid >> 6] = s;
      __syncthreads();
      if (tid == 0) outv[h * 32 + j] = red[0] + red[1] + red[2] + red[3];
      __syncthreads();
    }
    if (tid == 0) { outv[h * 32 + 30] = 0.f; outv[h * 32 + 31] = 0.f; }
  }
}

// ---------------- fused stage-1: g1 projection (K=30, in regs) + attention + aggregation ----------------
// grid (256 graphs, 6 = head*2 + colhalf). Writes split fp16 A for the t1-GEMM directly.
__global__ __launch_bounds__(256) void gat_fused1(
    const float* __restrict__ x, const float* __restrict__ g1W,
    const float* __restrict__ was, const float* __restrict__ wad,
    const int* __restrict__ esrc, const int* __restrict__ edst,
    const float* __restrict__ gbias,
    _Float16* __restrict__ ATh, _Float16* __restrict__ ATl, int Mtot)
{
  const int g = blockIdx.x;
  const int h = blockIdx.y >> 1;
  const int half = blockIdx.y & 1;
  const int tid = threadIdx.x;
  const int base = g << 5;                // npg = 32
  __shared__ float sx[32][32];            // x rows (cols padded 30->32)
  __shared__ float sP[32][33];            // attention matrix (dst x src), +self
  __shared__ float s_as[32], s_ad[32], s_mx[32], s_den[32];
  __shared__ unsigned s_mxu[32];

  for (int i = tid; i < 1024; i += 256) {
    int n = i >> 5, j = i & 31;
    sx[n][j] = (j < 30) ? x[(size_t)(base + n) * 30 + j] : 0.f;
  }
  for (int i = tid; i < 32 * 33; i += 256) ((float*)sP)[i] = 0.f;
  if (tid < 32) { s_mxu[tid] = 0u; s_den[tid] = 0.f; }
  __syncthreads();

  // this thread's 2 columns of g1W in registers (static-indexed)
  const int colb = h * DD + (half << 9);
  const int c = colb + (tid << 1);
  float w0[30], w1[30];
  #pragma unroll
  for (int j = 0; j < 30; j++) {
    float2 wv = *(const float2*)&g1W[(size_t)j * HC + c];
    w0[j] = wv.x; w1[j] = wv.y;
  }

  // attention dots per node via precomputed w_as/w_ad (K=30)
  if (tid < 32) {
    float ps = 0.f, pd2 = 0.f;
    #pragma unroll
    for (int j = 0; j < 30; j++) {
      float xv = sx[tid][j];
      ps  += xv * was[h * 32 + j];
      pd2 += xv * wad[h * 32 + j];
    }
    s_as[tid] = ps; s_ad[tid] = pd2;
  }
  __syncthreads();

  int sl = 0, dl = 0;
  float lg = 0.f;
  if (tid < EPG) {
    int ei = g * EPG + tid;
    sl = esrc[ei] - base; dl = edst[ei] - base;
    float v = s_as[sl] + s_ad[dl];
    lg = v > 0.f ? v : 0.2f * v;
    atomicMax(&s_mxu[dl], fenc(lg));
  }
  float slg = 0.f;
  if (tid < 32) {
    float v = s_as[tid] + s_ad[tid];
    slg = v > 0.f ? v : 0.2f * v;
    atomicMax(&s_mxu[tid], fenc(slg));
  }
  __syncthreads();
  if (tid < 32) s_mx[tid] = fdec(s_mxu[tid]);
  __syncthreads();
  float ex = 0.f;
  if (tid < EPG) { ex = expf(lg - s_mx[dl]); atomicAdd(&s_den[dl], ex); }
  float exs = 0.f;
  if (tid < 32) { exs = expf(slg - s_mx[tid]); atomicAdd(&s_den[tid], exs); }
  __syncthreads();
  if (tid < EPG) atomicAdd(&sP[dl][sl], ex / s_den[dl]);
  if (tid < 32)  atomicAdd(&sP[tid][tid], exs / s_den[tid]);

  // xl columns for all 32 nodes, in registers (fully unrolled -> static indexing)
  float xl0[32], xl1[32];
  #pragma unroll
  for (int n = 0; n < 32; n++) {
    float a0 = 0.f, a1 = 0.f;
    #pragma unroll
    for (int j = 0; j < 30; j++) {
      float xv = sx[n][j];
      a0 += xv * w0[j]; a1 += xv * w1[j];
    }
    xl0[n] = a0; xl1[n] = a1;
  }
  __syncthreads();   // sP final

  // out[n] = sum_m P[n][m] * xl[m] (+bias), split-fp16 pre-swizzled write
  const float b0 = gbias[c], b1 = gbias[c + 1];
  const int kt = c >> 5;
  const int ch = (c >> 3) & 3;
  const int j2 = c & 7;
  for (int n = 0; n < 32; n++) {
    float a0 = 0.f, a1 = 0.f;
    #pragma unroll
    for (int m = 0; m < 32; m++) {
      float p = sP[n][m];
      a0 += p * xl0[m]; a1 += p * xl1[m];
    }
    a0 += b0; a1 += b1;
    const int R = base + n;
    const int c2 = ch ^ ((R >> 1) & 3);
    const size_t ad = ((size_t)kt * Mtot + R) * 32 + c2 * 8 + j2;
    f16x2 hh, ll;
    _Float16 h0 = (_Float16)a0; hh[0] = h0; ll[0] = (_Float16)(a0 - (float)h0);
    _Float16 h1 = (_Float16)a1; hh[1] = h1; ll[1] = (_Float16)(a1 - (float)h1);
    *(f16x2*)&ATh[ad] = hh;
    *(f16x2*)&ATl[ad] = ll;
  }
}

// ---------------- split-fp16 MFMA GEMM: 128x128 tile, 4 waves, 2-deep counted-vmcnt ----------------
__global__ __launch_bounds__(256) void mfma_gemm(
    const _Float16* __restrict__ ATh, const _Float16* __restrict__ ATl,
    const _Float16* __restrict__ BTh, const _Float16* __restrict__ BTl,
    const float* __restrict__ bias, float* __restrict__ C,
    int M, int N, int K,
    const float* __restrict__ avs, const float* __restrict__ avd,
    float* __restrict__ alsp, float* __restrict__ aldp,
    const float* __restrict__ pvec, float* __restrict__ scp)
{
  // per 32KB buffer: Ah +0, Al +8192, Bh +16384, Bl +24576
  __shared__ __align__(16) char smem[2 * 32768];

  const int gx = N >> 7, gy = M >> 7;
  const int lid = blockIdx.x + gx * blockIdx.y;
  int vx, vy;
  const int G = gy & ~7;
  if (lid < gx * G) {
    const int sub = lid & 7, rest = lid >> 3;
    vx = rest % gx; vy = (rest / gx) * 8 + sub;
  } else {
    const int r = lid - gx * G;
    vx = r % gx; vy = G + r / gx;
  }
  const int brow = vy << 7, bcol = vx << 7;

  const int tid  = threadIdx.x;
  const int lane = tid & 63;
  const int w    = tid >> 6;          // 0..3
  const int wr   = (w >> 1) << 6, wc = (w & 1) << 6;
  const int wn   = w & 1;
  const int fr   = lane & 15, g4 = lane >> 4;

  f32x4 acc[4][4];
  #pragma unroll
  for (int m = 0; m < 4; m++)
    #pragma unroll
    for (int n = 0; n < 4; n++) acc[m][n] = (f32x4)0.0f;

  int aoff[4], boff[4];
  #pragma unroll
  for (int m = 0; m < 4; m++) {
    int r = wr + m * 16 + fr;
    aoff[m] = r * 64 + ((g4 ^ ((r >> 1) & 3)) << 4);
  }
  #pragma unroll
  for (int n = 0; n < 4; n++) {
    int r = wc + n * 16 + fr;
    boff[n] = r * 64 + ((g4 ^ ((r >> 1) & 3)) << 4);
  }

  const int ktiles = (K + 31) >> 5;

#define STAGE(ktv, buf)                                                    \
  do {                                                                     \
    char* bse = (buf);                                                     \
    const size_t ab = ((size_t)(ktv) * M + brow) << 6;                     \
    const size_t bb = ((size_t)(ktv) * N + bcol) << 6;                     \
    const char* gah = (const char*)ATh + ab + tid * 16;                    \
    const char* gal = (const char*)ATl + ab + tid * 16;                    \
    const char* gbh = (const char*)BTh + bb + tid * 16;                    \
    const char* gbl = (const char*)BTl + bb + tid * 16;                    \
    gload16(gah,        bse + tid * 16);                                   \
    gload16(gah + 4096, bse + tid * 16 + 4096);                            \
    gload16(gal,        bse + 8192 + tid * 16);                            \
    gload16(gal + 4096, bse + 8192 + tid * 16 + 4096);                     \
    gload16(gbh,        bse + 16384 + tid * 16);                           \
    gload16(gbh + 4096, bse + 16384 + tid * 16 + 4096);                    \
    gload16(gbl,        bse + 24576 + tid * 16);                           \
    gload16(gbl + 4096, bse + 24576 + tid * 16 + 4096);                    \
  } while (0)

  STAGE(0, smem);
  if (ktiles > 1) STAGE(1, smem + 32768);

  for (int kt = 0; kt < ktiles; kt++) {
    char* curb = smem + ((kt & 1) << 15);
    if (kt + 1 < ktiles) {
      asm volatile("s_waitcnt vmcnt(8)" ::: "memory");   // tile kt's 8 loads landed
    } else {
      asm volatile("s_waitcnt vmcnt(0)" ::: "memory");
    }
    __builtin_amdgcn_s_barrier();      // tile kt visible block-wide
    asm volatile("" ::: "memory");

    f16x8 ah[4], al[4], bh[4], bl[4];
    #pragma unroll
    for (int n = 0; n < 4; n++) {
      bh[n] = *(const f16x8*)(curb + 16384 + boff[n]);
      bl[n] = *(const f16x8*)(curb + 24576 + boff[n]);
    }
    #pragma unroll
    for (int m = 0; m < 4; m++) {
      ah[m] = *(const f16x8*)(curb + aoff[m]);
      al[m] = *(const f16x8*)(curb + 8192 + aoff[m]);
    }
    asm volatile("s_waitcnt lgkmcnt(0)" ::: "memory");   // this wave's LDS reads retired
    __builtin_amdgcn_sched_barrier(0);
    __builtin_amdgcn_s_barrier();      // all waves done reading curb -> safe to overwrite
    asm volatile("" ::: "memory");

    if (kt + 2 < ktiles) STAGE(kt + 2, curb);  // hides under the MFMA cluster below

    __builtin_amdgcn_s_setprio(1);
    #pragma unroll
    for (int m = 0; m < 4; m++) {
      #pragma unroll
      for (int n = 0; n < 4; n++) {
        acc[m][n] = __builtin_amdgcn_mfma_f32_16x16x32_f16(ah[m], bh[n], acc[m][n], 0, 0, 0);
        acc[m][n] = __builtin_amdgcn_mfma_f32_16x16x32_f16(al[m], bh[n], acc[m][n], 0, 0, 0);
        acc[m][n] = __builtin_amdgcn_mfma_f32_16x16x32_f16(ah[m], bl[n], acc[m][n], 0, 0, 0);
      }
    }
    __builtin_amdgcn_s_setprio(0);
    asm volatile("" ::: "memory");
  }
#undef STAGE

  // ---- epilogue: C/D layout col=lane&15, row=(lane>>4)*4+q ----
  const int crow0 = brow + wr + g4 * 4;
  const int ccol0 = bcol + wc + fr;
  #pragma unroll
  for (int n = 0; n < 4; n++) {
    const int col = ccol0 + n * 16;
    const float bv = bias ? bias[col] : 0.f;
    #pragma unroll
    for (int m = 0; m < 4; m++) {
      const int row = crow0 + m * 16;
      #pragma unroll
      for (int q = 0; q < 4; q++)
        C[(size_t)(row + q) * N + col] = acc[m][n][q] + bv;
    }
  }

  // ---- deterministic fused attention-dot partials (g-GEMMs, N=3072) ----
  if (alsp) {
    const int h3 = bcol >> 10;
    const int slot = ((bcol & 1023) >> 6) + wn;   // 16 strips of 64 cols per head
    #pragma unroll
    for (int m = 0; m < 4; m++) {
      #pragma unroll
      for (int q = 0; q < 4; q++) {
        float ps = 0.f, pd = 0.f;
        #pragma unroll
        for (int n = 0; n < 4; n++) {
          const int col = ccol0 + n * 16;
          const float v = acc[m][n][q];
          ps += v * avs[col]; pd += v * avd[col];
        }
        #pragma unroll
        for (int mk = 1; mk <= 8; mk <<= 1) {
          ps += __shfl_xor(ps, mk);
          pd += __shfl_xor(pd, mk);
        }
        if (fr == 0) {
          const int row = crow0 + m * 16 + q;
          alsp[row * 48 + h3 * 16 + slot] = ps;
          aldp[row * 48 + h3 * 16 + slot] = pd;
        }
      }
    }
  }
  // ---- deterministic fused score-dot partials (t-GEMMs, N=1024) ----
  if (scp) {
    const int slot = (bcol >> 6) + wn;            // 16 strips of 64 cols
    #pragma unroll
    for (int m = 0; m < 4; m++) {
      #pragma unroll
      for (int q = 0; q < 4; q++) {
        float pp = 0.f;
        #pragma unroll
        for (int n = 0; n < 4; n++) {
          const int col = ccol0 + n * 16;
          pp += (acc[m][n][q] + bias[col]) * pvec[col];
        }
        #pragma unroll
        for (int mk = 1; mk <= 8; mk <<= 1) pp += __shfl_xor(pp, mk);
        if (fr == 0) scp[(crow0 + m * 16 + q) * 16 + slot] = pp;
      }
    }
  }
}

// ---------------- fused GAT attention + aggregation (stages 2/3; column-half blocks) -----------
__global__ __launch_bounds__(256) void gat_agg(
    const float* __restrict__ xl, const float* __restrict__ alsp, const float* __restrict__ aldp,
    const int* __restrict__ esrc, const int* __restrict__ edst, const int* __restrict__ emask,
    const float* __restrict__ gbias, _Float16* __restrict__ ATh, _Float16* __restrict__ ATl,
    int npg, int Mtot)
{
  const int g = blockIdx.x;
  const int h = blockIdx.y >> 1;
  const int half = blockIdx.y & 1;
  const int tid = threadIdx.x;
  const int base = g * npg;
  __shared__ float sxl[32 * 512];        // 64KB -> 2 blocks/CU
  __shared__ float s_as[32], s_ad[32], s_mx[32], s_den[32], s_self[32];
  __shared__ unsigned s_mxu[32];
  __shared__ float s_alpha[EPG];
  __shared__ int s_srcl[EPG];
  __shared__ int s_start[33];
  __shared__ int s_cnt[32], s_cur[32];
  __shared__ int s_list[EPG];

  const int colb = h * DD + (half << 9);
  for (int n = 0; n < npg; n++) {
    *(float2*)&sxl[(n << 9) + (tid << 1)] =
        *(const float2*)&xl[(size_t)(base + n) * HC + colb + (tid << 1)];
  }

  if (tid < npg) {
    const float* ps = alsp + (size_t)(base + tid) * 48 + h * 16;
    const float* pdp = aldp + (size_t)(base + tid) * 48 + h * 16;
    float ss = 0.f, dd2 = 0.f;
    #pragma unroll
    for (int s = 0; s < 16; s++) { ss += ps[s]; dd2 += pdp[s]; }
    s_as[tid] = ss;
    s_ad[tid] = dd2;
    s_mxu[tid] = 0u;
    s_den[tid] = 0.f;
    s_cnt[tid] = 0;
    s_cur[tid] = 0;
  }
  __syncthreads();

  int ok = 0, dl = 0;
  float lg = 0.f;
  if (tid < EPG) {
    int ei = g * EPG + tid;
    ok = emask ? emask[ei] : 1;
    if (ok) {
      int sl = esrc[ei] - base;
      dl = edst[ei] - base;
      s_srcl[tid] = sl;
      float v = s_as[sl] + s_ad[dl];
      lg = v > 0.f ? v : 0.2f * v;
      atomicMax(&s_mxu[dl], fenc(lg));
      atomicAdd(&s_cnt[dl], 1);
    }
  }
  float slg = 0.f;
  if (tid < npg) {
    float v = s_as[tid] + s_ad[tid];
    slg = v > 0.f ? v : 0.2f * v;
    atomicMax(&s_mxu[tid], fenc(slg));
  }
  __syncthreads();

  if (tid < npg) s_mx[tid] = fdec(s_mxu[tid]);
  if (tid == 0) {
    int run = 0;
    for (int n = 0; n < npg; n++) { s_start[n] = run; run += s_cnt[n]; }
    s_start[npg] = run;
  }
  __syncthreads();

  float ex = 0.f;
  if (tid < EPG && ok) {
    ex = expf(lg - s_mx[dl]);
    atomicAdd(&s_den[dl], ex);
    int p = s_start[dl] + atomicAdd(&s_cur[dl], 1);
    s_list[p] = tid;
  }
  if (tid < npg) {
    float e2 = expf(slg - s_mx[tid]);
    s_self[tid] = e2;
    atomicAdd(&s_den[tid], e2);
  }
  __syncthreads();

  if (tid < EPG && ok) s_alpha[tid] = ex / s_den[dl];
  if (tid < npg) s_self[tid] = s_self[tid] / s_den[tid];
  __syncthreads();

  const int c = colb + (tid << 1);
  const float b0 = gbias[c], b1 = gbias[c + 1];
  const int kt = c >> 5;
  const int ch = (c >> 3) & 3;
  const int j2 = c & 7;
  for (int n = 0; n < npg; n++) {
    const float2 v = *(const float2*)&sxl[(n << 9) + (tid << 1)];
    float a0 = s_self[n];
    float ax = a0 * v.x, ay = a0 * v.y;
    const int st = s_start[n], en = s_start[n + 1];
    for (int q = st; q < en; q++) {
      int e = s_list[q];
      float a = s_alpha[e];
      const float2 u = *(const float2*)&sxl[(s_srcl[e] << 9) + (tid << 1)];
      ax += a * u.x; ay += a * u.y;
    }
    ax += b0; ay += b1;
    const int R = base + n;
    const int c2 = ch ^ ((R >> 1) & 3);
    const size_t ad = ((size_t)kt * Mtot + R) * 32 + c2 * 8 + j2;
    f16x2 hh, ll;
    _Float16 h0 = (_Float16)ax; hh[0] = h0; ll[0] = (_Float16)(ax - (float)h0);
    _Float16 h1 = (_Float16)ay; hh[1] = h1; ll[1] = (_Float16)(ay - (float)h1);
    *(f16x2*)&ATh[ad] = hh;
    *(f16x2*)&ATl[ad] = ll;
  }
}

// ---------------- TopK pool: scores, stable sort, gate -> split fp16 A for next g-GEMM ----------------
__global__ __launch_bounds__(256) void pool_kernel(
    const float* __restrict__ hbuf, const float* __restrict__ scp,
    const int* __restrict__ cs, const int* __restrict__ cd, const int* __restrict__ cm,
    int npg, int k, int Mnext,
    _Float16* __restrict__ ATh, _Float16* __restrict__ ATl,
    float* __restrict__ gap,
    int* __restrict__ ns, int* __restrict__ nd, int* __restrict__ nm,
    const float* __restrict__ nrm, int stage)
{
  int g = blockIdx.x, tid = threadIdx.x;
  __shared__ float ssc[32];
  __shared__ int sord[32];
  __shared__ int snp[32];
  __shared__ float sgp[2][1024];
  if (tid < npg) {
    const float* sp = scp + (size_t)(g * npg + tid) * 16;
    float s = 0.f;
    #pragma unroll
    for (int q = 0; q < 16; q++) s += sp[q];
    ssc[tid] = tanhf(s / nrm[stage]);
  }
  __syncthreads();
  if (tid == 0) {
    for (int i = 0; i < npg; i++) sord[i] = i;
    for (int i = 1; i < npg; i++) {
      int oi = sord[i]; float v = ssc[oi]; int j = i - 1;
      while (j >= 0 && ssc[sord[j]] < v) { sord[j + 1] = sord[j]; j--; }
      sord[j + 1] = oi;
    }
  }
  __syncthreads();
  if (tid < npg) snp[tid] = -1;
  __syncthreads();
  if (tid < k) snp[sord[tid]] = tid;
  __syncthreads();

  const int col0 = (tid & 127) << 3;
  const int rr = tid >> 7;
  const int kt = col0 >> 5;
  const int ch = (col0 >> 3) & 3;
  float part[8];
  #pragma unroll
  for (int j = 0; j < 8; j++) part[j] = 0.f;
  for (int r = rr; r < k; r += 2) {
    int ol = sord[r];
    float s = ssc[ol];
    const float* hr = hbuf + (size_t)(g * npg + ol) * DD + col0;
    float4 v0 = *(const float4*)hr;
    float4 v1 = *(const float4*)(hr + 4);
    float gv[8] = {v0.x * s, v0.y * s, v0.z * s, v0.w * s,
                   v1.x * s, v1.y * s, v1.z * s, v1.w * s};
    #pragma unroll
    for (int j = 0; j < 8; j++) part[j] += gv[j];
    if (ATh) {
      int R = g * k + r;
      int c2 = ch ^ ((R >> 1) & 3);
      size_t ad = ((size_t)kt * Mnext + R) * 32 + c2 * 8;
      f16x8 hh, ll;
      #pragma unroll
      for (int j = 0; j < 8; j++) {
        _Float16 hv = (_Float16)gv[j];
        hh[j] = hv; ll[j] = (_Float16)(gv[j] - (float)hv);
      }
      *(f16x8*)&ATh[ad] = hh;
      *(f16x8*)&ATl[ad] = ll;
    }
  }
  #pragma unroll
  for (int j = 0; j < 8; j++) sgp[rr][col0 + j] = part[j];
  __syncthreads();
  const float fk = (float)k;
  #pragma unroll
  for (int j = 0; j < 4; j++) {
    int cc = tid * 4 + j;
    gap[(size_t)g * DD + cc] = (sgp[0][cc] + sgp[1][cc]) / fk;
  }

  for (int e = tid; e < EPG; e += 256) {
    int ei = g * EPG + e;
    int ok = cm ? cm[ei] : 1;
    int m2 = 0, a = 0, b2 = 0;
    if (ok) {
      int sl = cs[ei] - g * npg, dl = cd[ei] - g * npg;
      int nsl = snp[sl], ndl = snp[dl];
      if (nsl >= 0 && ndl >= 0) { m2 = 1; a = g * k + nsl; b2 = g * k + ndl; }
    }
    ns[ei] = a; nd[ei] = b2; nm[ei] = m2;
  }
}

// ---------------- fused head: z=X1+X2+X3; z2=relu(z@l1W+b); partial dot with l2W ----------------
__global__ __launch_bounds__(256) void head_kernel(
    const float* __restrict__ X1, const float* __restrict__ X2, const float* __restrict__ X3,
    const float* __restrict__ l1W, const float* __restrict__ l1b,
    const float* __restrict__ l2W, float* __restrict__ partial)
{
  __shared__ float a[4][1024];
  __shared__ float red[4][4];            // [wave][row]
  const int tid = threadIdx.x;
  const int cg = blockIdx.x, rg = blockIdx.y;
  const int row0 = rg << 2;
  #pragma unroll
  for (int r = 0; r < 4; r++) {
    const size_t ro = (size_t)(row0 + r) << 10;
    #pragma unroll
    for (int jj = 0; jj < 4; jj++) {
      int j = tid + jj * 256;
      a[r][j] = X1[ro + j] + X2[ro + j] + X3[ro + j];
    }
  }
  __syncthreads();

  const int col = (cg << 8) + tid;
  float acc0 = 0.f, acc1 = 0.f, acc2 = 0.f, acc3 = 0.f;
  #pragma unroll 8
  for (int k = 0; k < 1024; k++) {
    float wv = l1W[((size_t)k << 10) + col];
    acc0 += a[0][k] * wv;
    acc1 += a[1][k] * wv;
    acc2 += a[2][k] * wv;
    acc3 += a[3][k] * wv;
  }
  const float bv = l1b[col], lw = l2W[col];
  float v0 = fmaxf(acc0 + bv, 0.f) * lw;
  float v1 = fmaxf(acc1 + bv, 0.f) * lw;
  float v2 = fmaxf(acc2 + bv, 0.f) * lw;
  float v3 = fmaxf(acc3 + bv, 0.f) * lw;
  #pragma unroll
  for (int off = 32; off; off >>= 1) {
    v0 += __shfl_down(v0, off);
    v1 += __shfl_down(v1, off);
    v2 += __shfl_down(v2, off);
    v3 += __shfl_down(v3, off);
  }
  const int lane = tid & 63, wid = tid >> 6;
  if (lane == 0) { red[wid][0] = v0; red[wid][1] = v1; red[wid][2] = v2; red[wid][3] = v3; }
  __syncthreads();
  if (tid < 4)
    partial[(size_t)(row0 + tid) * 4 + cg] =
        red[0][tid] + red[1][tid] + red[2][tid] + red[3][tid];
}

__global__ __launch_bounds__(256) void head2_kernel(
    const float* __restrict__ partial, const float* __restrict__ l2b,
    float* __restrict__ out)
{
  int r = threadIdx.x;
  out[r] = partial[r * 4 + 0] + partial[r * 4 + 1] +
           partial[r * 4 + 2] + partial[r * 4 + 3] + l2b[0];
}

extern "C" void kernel_launch(void* const* d_in, const int* in_sizes, int n_in,
                              void* d_out, int out_size, void* d_ws, size_t ws_size,
                              hipStream_t stream)
{
  (void)in_sizes; (void)n_in; (void)out_size; (void)ws_size;
  const float* x    = (const float*)d_in[0];
  const int*   eidx = (const int*)d_in[2];
  const float* g1W = (const float*)d_in[4];
  const float* g1as= (const float*)d_in[5];
  const float* g1ad= (const float*)d_in[6];
  const float* g1b = (const float*)d_in[7];
  const float* t1W = (const float*)d_in[8];
  const float* t1b = (const float*)d_in[9];
  const float* p1  = (const float*)d_in[10];
  const float* g2W = (const float*)d_in[11];
  const float* g2as= (const float*)d_in[12];
  const float* g2ad= (const float*)d_in[13];
  const float* g2b = (const float*)d_in[14];
  const float* t2W = (const float*)d_in[15];
  const float* t2b = (const float*)d_in[16];
  const float* p2  = (const float*)d_in[17];
  const float* g3W = (const float*)d_in[18];
  const float* g3as= (const float*)d_in[19];
  const float* g3ad= (const float*)d_in[20];
  const float* g3b = (const float*)d_in[21];
  const float* t3W = (const float*)d_in[22];
  const float* t3b = (const float*)d_in[23];
  const float* p3  = (const float*)d_in[24];
  const float* l1W = (const float*)d_in[25];
  const float* l1b = (const float*)d_in[26];
  const float* l2W = (const float*)d_in[27];
  const float* l2b = (const float*)d_in[28];
  float* outp = (float*)d_out;

  float* W = (float*)d_ws;
  size_t o = 0;
  float* bufA = W + o; o += (size_t)8192 * HC;          // g-GEMM C (fp32), stages 2/3
  float* bufB = W + o; o += (size_t)8192 * DD;          // t-GEMM C (fp32)
  _Float16* ATh = (_Float16*)(W + o); o += (size_t)96 * 8192 * 32 / 2;  // split A (h)
  _Float16* ATl = (_Float16*)(W + o); o += (size_t)96 * 8192 * 32 / 2;  // split A (l)
  float* ALSp = W + o; o += 8192 * 48;
  float* ALDp = W + o; o += 8192 * 48;
  float* SCp  = W + o; o += 8192 * 16;
  float* NRM = W + o; o += 4;
  float* WAS = W + o; o += 96;                           // w_as [3][32]
  float* WAD = W + o; o += 96;                           // w_ad [3][32]
  float* X1  = W + o; o += 256 * DD;
  float* X2  = W + o; o += 256 * DD;
  float* X3  = W + o; o += 256 * DD;
  float* HP  = W + o; o += 256 * 4;                      // head partials
  int* E0s = (int*)(W + o); o += 40960;
  int* E0d = (int*)(W + o); o += 40960;
  int* E0m = (int*)(W + o); o += 40960;
  int* E1s = (int*)(W + o); o += 40960;
  int* E1d = (int*)(W + o); o += 40960;
  int* E1m = (int*)(W + o); o += 40960;
  _Float16* WTH = (_Float16*)(W + o); o += (3200 * 1024) / 2;
  _Float16* WTL = (_Float16*)(W + o); o += (3200 * 1024) / 2;

  const int* es1 = eidx;
  const int* ed1 = eidx + 40960;

  // -------- stage 1: M=8192, npg=32 -> k=26 (fused g1+attention) --------
  prep_kernel<<<9, 256, 0, stream>>>(p1, p2, p3, g1W, g1as, g1ad, NRM, WAS, WAD);
  gat_fused1<<<dim3(256, 6), 256, 0, stream>>>(x, g1W, WAS, WAD, es1, ed1, g1b,
                                               ATh, ATl, 8192);
  wtrans_kernel<<<dim3(32, 96), dim3(32, 8), 0, stream>>>(t1W, WTH, WTL, HC, DD);
  mfma_gemm<<<dim3(8, 64), 256, 0, stream>>>(ATh, ATl, WTH, WTL, t1b, bufB, 8192, DD, HC,
                                             nullptr, nullptr, nullptr, nullptr, p1, SCp);
  pool_kernel<<<256, 256, 0, stream>>>(bufB, SCp, es1, ed1, nullptr, 32, 26, 6656,
                                       ATh, ATl, X1, E0s, E0d, E0m, NRM, 0);

  // -------- stage 2: M=6656, npg=26 -> k=13 --------
  wtrans_kernel<<<dim3(96, 32), dim3(32, 8), 0, stream>>>(g2W, WTH, WTL, DD, HC);
  mfma_gemm<<<dim3(24, 52), 256, 0, stream>>>(ATh, ATl, WTH, WTL, nullptr, bufA, 6656, HC, DD,
                                              g2as, g2ad, ALSp, ALDp, nullptr, nullptr);
  gat_agg<<<dim3(256, 6), 256, 0, stream>>>(bufA, ALSp, ALDp, E0s, E0d, E0m, g2b,
                                            ATh, ATl, 26, 6656);
  wtrans_kernel<<<dim3(32, 96), dim3(32, 8), 0, stream>>>(t2W, WTH, WTL, HC, DD);
  mfma_gemm<<<dim3(8, 52), 256, 0, stream>>>(ATh, ATl, WTH, WTL, t2b, bufB, 6656, DD, HC,
                                             nullptr, nullptr, nullptr, nullptr, p2, SCp);
  pool_kernel<<<256, 256, 0, stream>>>(bufB, SCp, E0s, E0d, E0m, 26, 13, 3328,
                                       ATh, ATl, X2, E1s, E1d, E1m, NRM, 1);

  // -------- stage 3: M=3328, npg=13 -> k=4 --------
  wtrans_kernel<<<dim3(96, 32), dim3(32, 8), 0, stream>>>(g3W, WTH, WTL, DD, HC);
  mfma_gemm<<<dim3(24, 26), 256, 0, stream>>>(ATh, ATl, WTH, WTL, nullptr, bufA, 3328, HC, DD,
                                              g3as, g3ad, ALSp, ALDp, nullptr, nullptr);
  gat_agg<<<dim3(256, 6), 256, 0, stream>>>(bufA, ALSp, ALDp, E1s, E1d, E1m, g3b,
                                            ATh, ATl, 13, 3328);
  wtrans_kernel<<<dim3(32, 96), dim3(32, 8), 0, stream>>>(t3W, WTH, WTL, HC, DD);
  mfma_gemm<<<dim3(8, 26), 256, 0, stream>>>(ATh, ATl, WTH, WTL, t3b, bufB, 3328, DD, HC,
                                             nullptr, nullptr, nullptr, nullptr, p3, SCp);
  pool_kernel<<<256, 256, 0, stream>>>(bufB, SCp, E1s, E1d, E1m, 13, 4, 1024,
                                       nullptr, nullptr, X3, E0s, E0d, E0m, NRM, 2);

  // -------- fused head --------
  head_kernel<<<dim3(4, 64), 256, 0, stream>>>(X1, X2, X3, l1W, l1b, l2W, HP);
  head2_kernel<<<1, 256, 0, stream>>>(HP, l2b, outp);
}

// Round 11
// 944.448 us; speedup vs baseline: 1.4100x; 1.0025x over previous
//
#include <hip/hip_runtime.h>
#include <cstdint>
#include <cstddef>

#define EPG 160
#define HC  3072
#define DD  1024

typedef _Float16 f16x8 __attribute__((ext_vector_type(8)));
typedef _Float16 f16x2 __attribute__((ext_vector_type(2)));
typedef float    f32x4 __attribute__((ext_vector_type(4)));

__device__ __forceinline__ unsigned fenc(float f){
  unsigned u = __float_as_uint(f);
  return (u & 0x80000000u) ? ~u : (u | 0x80000000u);
}
__device__ __forceinline__ float fdec(unsigned u){
  return (u & 0x80000000u) ? __uint_as_float(u ^ 0x80000000u) : __uint_as_float(~u);
}

__device__ __forceinline__ void gload16(const void* g, void* l) {
  __builtin_amdgcn_global_load_lds((const __attribute__((address_space(1))) void*)g,
                                   (__attribute__((address_space(3))) void*)l, 16, 0, 0);
}

// ---------------- weight transpose + fp16 split (pre-swizzled chunks) ----------------
__global__ __launch_bounds__(256) void wtrans_kernel(
    const float* __restrict__ W, _Float16* __restrict__ WTh, _Float16* __restrict__ WTl,
    int K, int Nn)
{
  __shared__ float t[32][33];
  const int tx = threadIdx.x, ty = threadIdx.y;
  const int n0 = blockIdx.x * 32, k0 = blockIdx.y * 32;
  #pragma unroll
  for (int i = 0; i < 4; i++) {
    int k = k0 + ty + i * 8;
    t[ty + i * 8][tx] = (k < K) ? W[(size_t)k * Nn + n0 + tx] : 0.f;
  }
  __syncthreads();
  const int kt = k0 >> 5;
  const int c  = tx >> 3;
  const int w8 = tx & 7;
  #pragma unroll
  for (int i = 0; i < 4; i++) {
    int n = n0 + ty + i * 8;
    float v = t[tx][ty + i * 8];
    _Float16 h = (_Float16)v;
    float r = v - (float)h;
    int c2 = c ^ ((n >> 1) & 3);
    size_t addr = ((size_t)kt * Nn + n) * 32 + c2 * 8 + w8;
    WTh[addr] = h;
    WTl[addr] = (_Float16)r;
  }
}

// ---------------- prep: ||p_i||, w_as/w_ad = g1W . a_{src,dst}, bp_i = t_ib . p_i ----------------
__global__ __launch_bounds__(256) void prep_kernel(
    const float* __restrict__ p1, const float* __restrict__ p2, const float* __restrict__ p3,
    const float* __restrict__ g1W, const float* __restrict__ g1as, const float* __restrict__ g1ad,
    const float* __restrict__ t1b, const float* __restrict__ t2b, const float* __restrict__ t3b,
    float* __restrict__ nrm, float* __restrict__ was, float* __restrict__ wad,
    float* __restrict__ bp)
{
  const int b = blockIdx.x;
  const int tid = threadIdx.x;
  __shared__ float red[4];
  if (b < 3) {
    const float* p = b == 0 ? p1 : (b == 1 ? p2 : p3);
    float s = 0.f;
    for (int i = tid; i < DD; i += 256) { float v = p[i]; s += v * v; }
    #pragma unroll
    for (int off = 32; off; off >>= 1) s += __shfl_down(s, off);
    if ((tid & 63) == 0) red[tid >> 6] = s;
    __syncthreads();
    if (tid == 0) nrm[b] = sqrtf(red[0] + red[1] + red[2] + red[3]);
  } else if (b < 9) {
    const int idx = b - 3;
    const int h = idx >> 1;
    const float* av = (idx & 1) ? g1ad : g1as;
    float* outv = (idx & 1) ? wad : was;
    for (int j = 0; j < 30; j++) {
      float s = 0.f;
      for (int c = tid; c < DD; c += 256)
        s += g1W[(size_t)j * HC + h * DD + c] * av[h * DD + c];
      #pragma unroll
      for (int off = 32; off; off >>= 1) s += __shfl_down(s, off);
      if ((tid & 63) == 0) red[tid >> 6] = s;
      __syncthreads();
      if (tid == 0) outv[h * 32 + j] = red[0] + red[1] + red[2] + red[3];
      __syncthreads();
    }
    if (tid == 0) { outv[h * 32 + 30] = 0.f; outv[h * 32 + 31] = 0.f; }
  } else {
    const int i = b - 9;
    const float* tb = i == 0 ? t1b : (i == 1 ? t2b : t3b);
    const float* p = i == 0 ? p1 : (i == 1 ? p2 : p3);
    float s = 0.f;
    for (int c = tid; c < DD; c += 256) s += tb[c] * p[c];
    #pragma unroll
    for (int off = 32; off; off >>= 1) s += __shfl_down(s, off);
    if ((tid & 63) == 0) red[tid >> 6] = s;
    __syncthreads();
    if (tid == 0) bp[i] = red[0] + red[1] + red[2] + red[3];
  }
}

// ---------------- vproj: V[i][j] = sum_d t_iW[j][d] * p_i[d] ----------------
__global__ __launch_bounds__(64) void vproj_kernel(
    const float* __restrict__ t1W, const float* __restrict__ t2W, const float* __restrict__ t3W,
    const float* __restrict__ p1, const float* __restrict__ p2, const float* __restrict__ p3,
    float* __restrict__ V)
{
  const int j = blockIdx.x;
  const int i = blockIdx.y;
  const float* Wm = i == 0 ? t1W : (i == 1 ? t2W : t3W);
  const float* p  = i == 0 ? p1 : (i == 1 ? p2 : p3);
  const int lane = threadIdx.x;
  const float* row = Wm + (size_t)j * DD;
  float s = 0.f;
  #pragma unroll 4
  for (int c = lane; c < DD; c += 64) s += row[c] * p[c];
  #pragma unroll
  for (int off = 32; off; off >>= 1) s += __shfl_down(s, off);
  if (lane == 0) V[i * HC + j] = s;
}

// ---------------- fused stage-1: g1 projection (K=30) + attention + aggregation + score ----
__global__ __launch_bounds__(256) void gat_fused1(
    const float* __restrict__ x, const float* __restrict__ g1W,
    const float* __restrict__ was, const float* __restrict__ wad,
    const int* __restrict__ esrc, const int* __restrict__ edst,
    const float* __restrict__ gbias,
    _Float16* __restrict__ ATh, _Float16* __restrict__ ATl, int Mtot,
    const float* __restrict__ V, float* __restrict__ scp)
{
  const int g = blockIdx.x;
  const int h = blockIdx.y >> 1;
  const int half = blockIdx.y & 1;
  const int tid = threadIdx.x;
  const int base = g << 5;
  __shared__ float sx[32][32];
  __shared__ float sP[32][33];
  __shared__ float s_as[32], s_ad[32], s_mx[32], s_den[32];
  __shared__ unsigned s_mxu[32];

  for (int i = tid; i < 1024; i += 256) {
    int n = i >> 5, j = i & 31;
    sx[n][j] = (j < 30) ? x[(size_t)(base + n) * 30 + j] : 0.f;
  }
  for (int i = tid; i < 32 * 33; i += 256) ((float*)sP)[i] = 0.f;
  if (tid < 32) { s_mxu[tid] = 0u; s_den[tid] = 0.f; }
  __syncthreads();

  const int colb = h * DD + (half << 9);
  const int c = colb + (tid << 1);
  float w0[30], w1[30];
  #pragma unroll
  for (int j = 0; j < 30; j++) {
    float2 wv = *(const float2*)&g1W[(size_t)j * HC + c];
    w0[j] = wv.x; w1[j] = wv.y;
  }

  if (tid < 32) {
    float ps = 0.f, pd2 = 0.f;
    #pragma unroll
    for (int j = 0; j < 30; j++) {
      float xv = sx[tid][j];
      ps  += xv * was[h * 32 + j];
      pd2 += xv * wad[h * 32 + j];
    }
    s_as[tid] = ps; s_ad[tid] = pd2;
  }
  __syncthreads();

  int sl = 0, dl = 0;
  float lg = 0.f;
  if (tid < EPG) {
    int ei = g * EPG + tid;
    sl = esrc[ei] - base; dl = edst[ei] - base;
    float v = s_as[sl] + s_ad[dl];
    lg = v > 0.f ? v : 0.2f * v;
    atomicMax(&s_mxu[dl], fenc(lg));
  }
  float slg = 0.f;
  if (tid < 32) {
    float v = s_as[tid] + s_ad[tid];
    slg = v > 0.f ? v : 0.2f * v;
    atomicMax(&s_mxu[tid], fenc(slg));
  }
  __syncthreads();
  if (tid < 32) s_mx[tid] = fdec(s_mxu[tid]);
  __syncthreads();
  float ex = 0.f;
  if (tid < EPG) { ex = expf(lg - s_mx[dl]); atomicAdd(&s_den[dl], ex); }
  float exs = 0.f;
  if (tid < 32) { exs = expf(slg - s_mx[tid]); atomicAdd(&s_den[tid], exs); }
  __syncthreads();
  if (tid < EPG) atomicAdd(&sP[dl][sl], ex / s_den[dl]);
  if (tid < 32)  atomicAdd(&sP[tid][tid], exs / s_den[tid]);

  float xl0[32], xl1[32];
  #pragma unroll
  for (int n = 0; n < 32; n++) {
    float a0 = 0.f, a1 = 0.f;
    #pragma unroll
    for (int j = 0; j < 30; j++) {
      float xv = sx[n][j];
      a0 += xv * w0[j]; a1 += xv * w1[j];
    }
    xl0[n] = a0; xl1[n] = a1;
  }
  __syncthreads();   // sP final

  const float b0 = gbias[c], b1 = gbias[c + 1];
  const float v0c = V[c], v1c = V[c + 1];
  const int slot = blockIdx.y * 4 + (tid >> 6);
  const int kt = c >> 5;
  const int ch = (c >> 3) & 3;
  const int j2 = c & 7;
  for (int n = 0; n < 32; n++) {
    float a0 = 0.f, a1 = 0.f;
    #pragma unroll
    for (int m = 0; m < 32; m++) {
      float p = sP[n][m];
      a0 += p * xl0[m]; a1 += p * xl1[m];
    }
    a0 += b0; a1 += b1;
    float sc = a0 * v0c + a1 * v1c;
    #pragma unroll
    for (int off = 32; off; off >>= 1) sc += __shfl_xor(sc, off);
    if ((tid & 63) == 0) scp[(size_t)(base + n) * 24 + slot] = sc;
    const int R = base + n;
    const int c2 = ch ^ ((R >> 1) & 3);
    const size_t ad = ((size_t)kt * Mtot + R) * 32 + c2 * 8 + j2;
    f16x2 hh, ll;
    _Float16 h0 = (_Float16)a0; hh[0] = h0; ll[0] = (_Float16)(a0 - (float)h0);
    _Float16 h1 = (_Float16)a1; hh[1] = h1; ll[1] = (_Float16)(a1 - (float)h1);
    *(f16x2*)&ATh[ad] = hh;
    *(f16x2*)&ATl[ad] = ll;
  }
}

// ---------------- split-fp16 MFMA GEMM (g-mode: alsp; t-mode: rowmap gather + gated epilogue) ----
// Gather handles the chunk swizzle: source row r's chunks are stored at c ^ ((r>>1)&3);
// the LDS-local row lr expects c ^ ((lr>>1)&3) -> source chunk = (tid&3) ^ ((lr>>1)&3) ^ ((r>>1)&3).
__global__ __launch_bounds__(256) void mfma_gemm(
    const _Float16* __restrict__ ATh, const _Float16* __restrict__ ATl,
    const _Float16* __restrict__ BTh, const _Float16* __restrict__ BTl,
    const float* __restrict__ bias, float* __restrict__ C,
    int M, int N, int K, int Msrc,
    const float* __restrict__ avs, const float* __restrict__ avd,
    float* __restrict__ alsp, float* __restrict__ aldp,
    const int* __restrict__ rowmap, const float* __restrict__ scores,
    _Float16* __restrict__ AXh, _Float16* __restrict__ AXl)
{
  __shared__ __align__(16) char smem[2 * 32768];

  const int gx = N >> 7, gy = M >> 7;
  const int lid = blockIdx.x + gx * blockIdx.y;
  int vx, vy;
  const int G = gy & ~7;
  if (lid < gx * G) {
    const int sub = lid & 7, rest = lid >> 3;
    vx = rest % gx; vy = (rest / gx) * 8 + sub;
  } else {
    const int r = lid - gx * G;
    vx = r % gx; vy = G + r / gx;
  }
  const int brow = vy << 7, bcol = vx << 7;

  const int tid  = threadIdx.x;
  const int lane = tid & 63;
  const int w    = tid >> 6;
  const int wr   = (w >> 1) << 6, wc = (w & 1) << 6;
  const int wn   = w & 1;
  const int fr   = lane & 15, g4 = lane >> 4;

  const int lr0 = tid >> 2;
  int r0g, r1g;
  if (rowmap) {
    r0g = rowmap[brow + lr0];
    r1g = rowmap[brow + 64 + lr0];
  } else {
    r0g = brow + lr0;
    r1g = brow + 64 + lr0;
  }
  const int ch0 = (((tid & 3) ^ ((lr0 >> 1) & 3) ^ ((r0g >> 1) & 3)) << 4);
  const int ch1 = (((tid & 3) ^ ((lr0 >> 1) & 3) ^ ((r1g >> 1) & 3)) << 4);

  f32x4 acc[4][4];
  #pragma unroll
  for (int m = 0; m < 4; m++)
    #pragma unroll
    for (int n = 0; n < 4; n++) acc[m][n] = (f32x4)0.0f;

  int aoff[4], boff[4];
  #pragma unroll
  for (int m = 0; m < 4; m++) {
    int r = wr + m * 16 + fr;
    aoff[m] = r * 64 + ((g4 ^ ((r >> 1) & 3)) << 4);
  }
  #pragma unroll
  for (int n = 0; n < 4; n++) {
    int r = wc + n * 16 + fr;
    boff[n] = r * 64 + ((g4 ^ ((r >> 1) & 3)) << 4);
  }

  const int ktiles = (K + 31) >> 5;

#define STAGE(ktv, buf)                                                        \
  do {                                                                         \
    char* bse = (buf);                                                         \
    const size_t a0ad = (((size_t)(ktv) * Msrc + r0g) << 6) + ch0;             \
    const size_t a1ad = (((size_t)(ktv) * Msrc + r1g) << 6) + ch1;             \
    const size_t bb = (((size_t)(ktv) * N + bcol) << 6) + tid * 16;            \
    gload16((const char*)ATh + a0ad, bse + tid * 16);                          \
    gload16((const char*)ATh + a1ad, bse + tid * 16 + 4096);                   \
    gload16((const char*)ATl + a0ad, bse + 8192 + tid * 16);                   \
    gload16((const char*)ATl + a1ad, bse + 8192 + tid * 16 + 4096);            \
    gload16((const char*)BTh + bb,        bse + 16384 + tid * 16);             \
    gload16((const char*)BTh + bb + 4096, bse + 16384 + tid * 16 + 4096);      \
    gload16((const char*)BTl + bb,        bse + 24576 + tid * 16);             \
    gload16((const char*)BTl + bb + 4096, bse + 24576 + tid * 16 + 4096);      \
  } while (0)

  STAGE(0, smem);
  if (ktiles > 1) STAGE(1, smem + 32768);

  for (int kt = 0; kt < ktiles; kt++) {
    char* curb = smem + ((kt & 1) << 15);
    if (kt + 1 < ktiles) {
      asm volatile("s_waitcnt vmcnt(8)" ::: "memory");
    } else {
      asm volatile("s_waitcnt vmcnt(0)" ::: "memory");
    }
    __builtin_amdgcn_s_barrier();
    asm volatile("" ::: "memory");

    f16x8 ah[4], al[4], bh[4], bl[4];
    #pragma unroll
    for (int n = 0; n < 4; n++) {
      bh[n] = *(const f16x8*)(curb + 16384 + boff[n]);
      bl[n] = *(const f16x8*)(curb + 24576 + boff[n]);
    }
    #pragma unroll
    for (int m = 0; m < 4; m++) {
      ah[m] = *(const f16x8*)(curb + aoff[m]);
      al[m] = *(const f16x8*)(curb + 8192 + aoff[m]);
    }
    asm volatile("s_waitcnt lgkmcnt(0)" ::: "memory");
    __builtin_amdgcn_sched_barrier(0);
    __builtin_amdgcn_s_barrier();
    asm volatile("" ::: "memory");

    if (kt + 2 < ktiles) STAGE(kt + 2, curb);

    __builtin_amdgcn_s_setprio(1);
    #pragma unroll
    for (int m = 0; m < 4; m++) {
      #pragma unroll
      for (int n = 0; n < 4; n++) {
        acc[m][n] = __builtin_amdgcn_mfma_f32_16x16x32_f16(ah[m], bh[n], acc[m][n], 0, 0, 0);
        acc[m][n] = __builtin_amdgcn_mfma_f32_16x16x32_f16(al[m], bh[n], acc[m][n], 0, 0, 0);
        acc[m][n] = __builtin_amdgcn_mfma_f32_16x16x32_f16(ah[m], bl[n], acc[m][n], 0, 0, 0);
      }
    }
    __builtin_amdgcn_s_setprio(0);
    asm volatile("" ::: "memory");
  }
#undef STAGE

  const int crow0 = brow + wr + g4 * 4;
  const int ccol0 = bcol + wc + fr;

  if (scores) {
    #pragma unroll
    for (int m = 0; m < 4; m++) {
      #pragma unroll
      for (int q = 0; q < 4; q++) {
        const int row = crow0 + m * 16 + q;
        const float s = scores[row];
        #pragma unroll
        for (int n = 0; n < 4; n++) {
          const int col = ccol0 + n * 16;
          const float gv = (acc[m][n][q] + bias[col]) * s;
          C[(size_t)row * N + col] = gv;
          if (AXh) {
            const int c2 = ((col >> 3) & 3) ^ ((row >> 1) & 3);
            const size_t ad = ((size_t)(col >> 5) * M + row) * 32 + c2 * 8 + (col & 7);
            _Float16 hv = (_Float16)gv;
            AXh[ad] = hv;
            AXl[ad] = (_Float16)(gv - (float)hv);
          }
        }
      }
    }
  } else {
    #pragma unroll
    for (int n = 0; n < 4; n++) {
      const int col = ccol0 + n * 16;
      const float bv = bias ? bias[col] : 0.f;
      #pragma unroll
      for (int m = 0; m < 4; m++) {
        const int row = crow0 + m * 16;
        #pragma unroll
        for (int q = 0; q < 4; q++)
          C[(size_t)(row + q) * N + col] = acc[m][n][q] + bv;
      }
    }
  }

  if (alsp) {
    const int h3 = bcol >> 10;
    const int slot = ((bcol & 1023) >> 6) + wn;
    #pragma unroll
    for (int m = 0; m < 4; m++) {
      #pragma unroll
      for (int q = 0; q < 4; q++) {
        float ps = 0.f, pd = 0.f;
        #pragma unroll
        for (int n = 0; n < 4; n++) {
          const int col = ccol0 + n * 16;
          const float v = acc[m][n][q];
          ps += v * avs[col]; pd += v * avd[col];
        }
        #pragma unroll
        for (int mk = 1; mk <= 8; mk <<= 1) {
          ps += __shfl_xor(ps, mk);
          pd += __shfl_xor(pd, mk);
        }
        if (fr == 0) {
          const int row = crow0 + m * 16 + q;
          alsp[row * 48 + h3 * 16 + slot] = ps;
          aldp[row * 48 + h3 * 16 + slot] = pd;
        }
      }
    }
  }
}

// ---------------- fused GAT attention + aggregation (stages 2/3) + score partials ------------
__global__ __launch_bounds__(256) void gat_agg(
    const float* __restrict__ xl, const float* __restrict__ alsp, const float* __restrict__ aldp,
    const int* __restrict__ esrc, const int* __restrict__ edst, const int* __restrict__ emask,
    const float* __restrict__ gbias, _Float16* __restrict__ ATh, _Float16* __restrict__ ATl,
    int npg, int Mtot, const float* __restrict__ V, float* __restrict__ scp)
{
  const int g = blockIdx.x;
  const int h = blockIdx.y >> 1;
  const int half = blockIdx.y & 1;
  const int tid = threadIdx.x;
  const int base = g * npg;
  __shared__ float sxl[32 * 512];
  __shared__ float s_as[32], s_ad[32], s_mx[32], s_den[32], s_self[32];
  __shared__ unsigned s_mxu[32];
  __shared__ float s_alpha[EPG];
  __shared__ int s_srcl[EPG];
  __shared__ int s_start[33];
  __shared__ int s_cnt[32], s_cur[32];
  __shared__ int s_list[EPG];

  const int colb = h * DD + (half << 9);
  for (int n = 0; n < npg; n++) {
    *(float2*)&sxl[(n << 9) + (tid << 1)] =
        *(const float2*)&xl[(size_t)(base + n) * HC + colb + (tid << 1)];
  }

  if (tid < npg) {
    const float* ps = alsp + (size_t)(base + tid) * 48 + h * 16;
    const float* pdp = aldp + (size_t)(base + tid) * 48 + h * 16;
    float ss = 0.f, dd2 = 0.f;
    #pragma unroll
    for (int s = 0; s < 16; s++) { ss += ps[s]; dd2 += pdp[s]; }
    s_as[tid] = ss;
    s_ad[tid] = dd2;
    s_mxu[tid] = 0u;
    s_den[tid] = 0.f;
    s_cnt[tid] = 0;
    s_cur[tid] = 0;
  }
  __syncthreads();

  int ok = 0, dl = 0;
  float lg = 0.f;
  if (tid < EPG) {
    int ei = g * EPG + tid;
    ok = emask ? emask[ei] : 1;
    if (ok) {
      int sl = esrc[ei] - base;
      dl = edst[ei] - base;
      s_srcl[tid] = sl;
      float v = s_as[sl] + s_ad[dl];
      lg = v > 0.f ? v : 0.2f * v;
      atomicMax(&s_mxu[dl], fenc(lg));
      atomicAdd(&s_cnt[dl], 1);
    }
  }
  float slg = 0.f;
  if (tid < npg) {
    float v = s_as[tid] + s_ad[tid];
    slg = v > 0.f ? v : 0.2f * v;
    atomicMax(&s_mxu[tid], fenc(slg));
  }
  __syncthreads();

  if (tid < npg) s_mx[tid] = fdec(s_mxu[tid]);
  if (tid == 0) {
    int run = 0;
    for (int n = 0; n < npg; n++) { s_start[n] = run; run += s_cnt[n]; }
    s_start[npg] = run;
  }
  __syncthreads();

  float ex = 0.f;
  if (tid < EPG && ok) {
    ex = expf(lg - s_mx[dl]);
    atomicAdd(&s_den[dl], ex);
    int p = s_start[dl] + atomicAdd(&s_cur[dl], 1);
    s_list[p] = tid;
  }
  if (tid < npg) {
    float e2 = expf(slg - s_mx[tid]);
    s_self[tid] = e2;
    atomicAdd(&s_den[tid], e2);
  }
  __syncthreads();

  if (tid < EPG && ok) s_alpha[tid] = ex / s_den[dl];
  if (tid < npg) s_self[tid] = s_self[tid] / s_den[tid];
  __syncthreads();

  const int c = colb + (tid << 1);
  const float b0 = gbias[c], b1 = gbias[c + 1];
  const float v0c = V[c], v1c = V[c + 1];
  const int slot = blockIdx.y * 4 + (tid >> 6);
  const int kt = c >> 5;
  const int ch = (c >> 3) & 3;
  const int j2 = c & 7;
  for (int n = 0; n < npg; n++) {
    const float2 v = *(const float2*)&sxl[(n << 9) + (tid << 1)];
    float a0 = s_self[n];
    float ax = a0 * v.x, ay = a0 * v.y;
    const int st = s_start[n], en = s_start[n + 1];
    for (int q = st; q < en; q++) {
      int e = s_list[q];
      float a = s_alpha[e];
      const float2 u = *(const float2*)&sxl[(s_srcl[e] << 9) + (tid << 1)];
      ax += a * u.x; ay += a * u.y;
    }
    ax += b0; ay += b1;
    float sc = ax * v0c + ay * v1c;
    #pragma unroll
    for (int off = 32; off; off >>= 1) sc += __shfl_xor(sc, off);
    if ((tid & 63) == 0) scp[(size_t)(base + n) * 24 + slot] = sc;
    const int R = base + n;
    const int c2 = ch ^ ((R >> 1) & 3);
    const size_t ad = ((size_t)kt * Mtot + R) * 32 + c2 * 8 + j2;
    f16x2 hh, ll;
    _Float16 h0 = (_Float16)ax; hh[0] = h0; ll[0] = (_Float16)(ax - (float)h0);
    _Float16 h1 = (_Float16)ay; hh[1] = h1; ll[1] = (_Float16)(ay - (float)h1);
    *(f16x2*)&ATh[ad] = hh;
    *(f16x2*)&ATl[ad] = ll;
  }
}

// ---------------- select: scores -> stable top-k, rowmap + gating scores + edge remap --------
__global__ __launch_bounds__(256) void select_kernel(
    const float* __restrict__ scp, const float* __restrict__ nrm,
    const float* __restrict__ bp, int stage,
    const int* __restrict__ cs, const int* __restrict__ cd, const int* __restrict__ cm,
    int npg, int k,
    int* __restrict__ rowmap, float* __restrict__ scores,
    int* __restrict__ ns, int* __restrict__ nd, int* __restrict__ nm)
{
  int g = blockIdx.x, tid = threadIdx.x;
  __shared__ float ssc[32];
  __shared__ int sord[32];
  __shared__ int snp[32];
  if (tid < npg) {
    const float* sp = scp + (size_t)(g * npg + tid) * 24;
    float s = 0.f;
    #pragma unroll
    for (int q = 0; q < 24; q++) s += sp[q];
    ssc[tid] = tanhf((s + bp[stage]) / nrm[stage]);
  }
  __syncthreads();
  if (tid == 0) {
    for (int i = 0; i < npg; i++) sord[i] = i;
    for (int i = 1; i < npg; i++) {
      int oi = sord[i]; float v = ssc[oi]; int j = i - 1;
      while (j >= 0 && ssc[sord[j]] < v) { sord[j + 1] = sord[j]; j--; }
      sord[j + 1] = oi;
    }
  }
  __syncthreads();
  if (tid < npg) snp[tid] = -1;
  __syncthreads();
  if (tid < k) {
    snp[sord[tid]] = tid;
    rowmap[g * k + tid] = g * npg + sord[tid];
    scores[g * k + tid] = ssc[sord[tid]];
  }
  __syncthreads();

  for (int e = tid; e < EPG; e += 256) {
    int ei = g * EPG + e;
    int ok = cm ? cm[ei] : 1;
    int m2 = 0, a = 0, b2 = 0;
    if (ok) {
      int sl = cs[ei] - g * npg, dl = cd[ei] - g * npg;
      int nsl = snp[sl], ndl = snp[dl];
      if (nsl >= 0 && ndl >= 0) { m2 = 1; a = g * k + nsl; b2 = g * k + ndl; }
    }
    ns[ei] = a; nd[ei] = b2; nm[ei] = m2;
  }
}

// ---------------- gap: mean of k gated rows per graph ----------------
__global__ __launch_bounds__(256) void gap_kernel(
    const float* __restrict__ xb, int k, float* __restrict__ gap)
{
  const int g = blockIdx.x, tid = threadIdx.x;
  float a0 = 0.f, a1 = 0.f, a2 = 0.f, a3 = 0.f;
  for (int r = 0; r < k; r++) {
    const float4 v = *(const float4*)&xb[(((size_t)(g * k + r)) << 10) + (tid << 2)];
    a0 += v.x; a1 += v.y; a2 += v.z; a3 += v.w;
  }
  const float fk = (float)k;
  float4 o = make_float4(a0 / fk, a1 / fk, a2 / fk, a3 / fk);
  *(float4*)&gap[((size_t)g << 10) + (tid << 2)] = o;
}

// ---------------- fused head ----------------
__global__ __launch_bounds__(256) void head_kernel(
    const float* __restrict__ X1, const float* __restrict__ X2, const float* __restrict__ X3,
    const float* __restrict__ l1W, const float* __restrict__ l1b,
    const float* __restrict__ l2W, float* __restrict__ partial)
{
  __shared__ float a[4][1024];
  __shared__ float red[4][4];
  const int tid = threadIdx.x;
  const int cg = blockIdx.x, rg = blockIdx.y;
  const int row0 = rg << 2;
  #pragma unroll
  for (int r = 0; r < 4; r++) {
    const size_t ro = (size_t)(row0 + r) << 10;
    #pragma unroll
    for (int jj = 0; jj < 4; jj++) {
      int j = tid + jj * 256;
      a[r][j] = X1[ro + j] + X2[ro + j] + X3[ro + j];
    }
  }
  __syncthreads();

  const int col = (cg << 8) + tid;
  float acc0 = 0.f, acc1 = 0.f, acc2 = 0.f, acc3 = 0.f;
  #pragma unroll 8
  for (int k = 0; k < 1024; k++) {
    float wv = l1W[((size_t)k << 10) + col];
    acc0 += a[0][k] * wv;
    acc1 += a[1][k] * wv;
    acc2 += a[2][k] * wv;
    acc3 += a[3][k] * wv;
  }
  const float bv = l1b[col], lw = l2W[col];
  float v0 = fmaxf(acc0 + bv, 0.f) * lw;
  float v1 = fmaxf(acc1 + bv, 0.f) * lw;
  float v2 = fmaxf(acc2 + bv, 0.f) * lw;
  float v3 = fmaxf(acc3 + bv, 0.f) * lw;
  #pragma unroll
  for (int off = 32; off; off >>= 1) {
    v0 += __shfl_down(v0, off);
    v1 += __shfl_down(v1, off);
    v2 += __shfl_down(v2, off);
    v3 += __shfl_down(v3, off);
  }
  const int lane = tid & 63, wid = tid >> 6;
  if (lane == 0) { red[wid][0] = v0; red[wid][1] = v1; red[wid][2] = v2; red[wid][3] = v3; }
  __syncthreads();
  if (tid < 4)
    partial[(size_t)(row0 + tid) * 4 + cg] =
        red[0][tid] + red[1][tid] + red[2][tid] + red[3][tid];
}

__global__ __launch_bounds__(256) void head2_kernel(
    const float* __restrict__ partial, const float* __restrict__ l2b,
    float* __restrict__ out)
{
  int r = threadIdx.x;
  out[r] = partial[r * 4 + 0] + partial[r * 4 + 1] +
           partial[r * 4 + 2] + partial[r * 4 + 3] + l2b[0];
}

extern "C" void kernel_launch(void* const* d_in, const int* in_sizes, int n_in,
                              void* d_out, int out_size, void* d_ws, size_t ws_size,
                              hipStream_t stream)
{
  (void)in_sizes; (void)n_in; (void)out_size; (void)ws_size;
  const float* x    = (const float*)d_in[0];
  const int*   eidx = (const int*)d_in[2];
  const float* g1W = (const float*)d_in[4];
  const float* g1as= (const float*)d_in[5];
  const float* g1ad= (const float*)d_in[6];
  const float* g1b = (const float*)d_in[7];
  const float* t1W = (const float*)d_in[8];
  const float* t1b = (const float*)d_in[9];
  const float* p1  = (const float*)d_in[10];
  const float* g2W = (const float*)d_in[11];
  const float* g2as= (const float*)d_in[12];
  const float* g2ad= (const float*)d_in[13];
  const float* g2b = (const float*)d_in[14];
  const float* t2W = (const float*)d_in[15];
  const float* t2b = (const float*)d_in[16];
  const float* p2  = (const float*)d_in[17];
  const float* g3W = (const float*)d_in[18];
  const float* g3as= (const float*)d_in[19];
  const float* g3ad= (const float*)d_in[20];
  const float* g3b = (const float*)d_in[21];
  const float* t3W = (const float*)d_in[22];
  const float* t3b = (const float*)d_in[23];
  const float* p3  = (const float*)d_in[24];
  const float* l1W = (const float*)d_in[25];
  const float* l1b = (const float*)d_in[26];
  const float* l2W = (const float*)d_in[27];
  const float* l2b = (const float*)d_in[28];
  float* outp = (float*)d_out;

  float* W = (float*)d_ws;
  size_t o = 0;
  float* bufA = W + o;                                   // g-GEMM fp32 C (<=6656*3072)
  float* bufB = bufA;                                    // ALIAS: t output (<=6656*1024),
  o += (size_t)6656 * HC;                                // temporally disjoint with bufA
  _Float16* ATAh = (_Float16*)(W + o); o += (size_t)96 * 8192 * 32 / 2; // agg split h (K=3072)
  _Float16* ATAl = (_Float16*)(W + o); o += (size_t)96 * 8192 * 32 / 2; // agg split l
  _Float16* AXh  = (_Float16*)(W + o); o += (size_t)32 * 6656 * 32 / 2; // x_new split h (K=1024)
  _Float16* AXl  = (_Float16*)(W + o); o += (size_t)32 * 6656 * 32 / 2; // x_new split l
  float* ALSp = W + o; o += 8192 * 48;
  float* ALDp = W + o; o += 8192 * 48;
  float* SCP  = W + o; o += 8192 * 24;
  float* NRM = W + o; o += 4;
  float* BP  = W + o; o += 4;
  float* WAS = W + o; o += 96;
  float* WAD = W + o; o += 96;
  float* V   = W + o; o += 3 * HC;
  float* X1  = W + o; o += 256 * DD;
  float* X2  = W + o; o += 256 * DD;
  float* X3  = W + o; o += 256 * DD;
  float* HP  = W + o; o += 256 * 4;
  float* SSEL = W + o; o += 6656;
  int* RMAP = (int*)(W + o); o += 6656;
  int* E0s = (int*)(W + o); o += 40960;
  int* E0d = (int*)(W + o); o += 40960;
  int* E0m = (int*)(W + o); o += 40960;
  int* E1s = (int*)(W + o); o += 40960;
  int* E1d = (int*)(W + o); o += 40960;
  int* E1m = (int*)(W + o); o += 40960;
  _Float16* WTH = (_Float16*)(W + o); o += (3200 * 1024) / 2;
  _Float16* WTL = (_Float16*)(W + o); o += (3200 * 1024) / 2;

  const int* es1 = eidx;
  const int* ed1 = eidx + 40960;

  prep_kernel<<<12, 256, 0, stream>>>(p1, p2, p3, g1W, g1as, g1ad, t1b, t2b, t3b,
                                      NRM, WAS, WAD, BP);
  vproj_kernel<<<dim3(HC, 3), 64, 0, stream>>>(t1W, t2W, t3W, p1, p2, p3, V);

  // -------- stage 1: 8192 rows, npg=32 -> k=26 (select-before-project) --------
  gat_fused1<<<dim3(256, 6), 256, 0, stream>>>(x, g1W, WAS, WAD, es1, ed1, g1b,
                                               ATAh, ATAl, 8192, V, SCP);
  select_kernel<<<256, 256, 0, stream>>>(SCP, NRM, BP, 0, es1, ed1, nullptr, 32, 26,
                                         RMAP, SSEL, E0s, E0d, E0m);
  wtrans_kernel<<<dim3(32, 96), dim3(32, 8), 0, stream>>>(t1W, WTH, WTL, HC, DD);
  mfma_gemm<<<dim3(8, 52), 256, 0, stream>>>(ATAh, ATAl, WTH, WTL, t1b, bufB,
                                             6656, DD, HC, 8192,
                                             nullptr, nullptr, nullptr, nullptr,
                                             RMAP, SSEL, AXh, AXl);
  gap_kernel<<<256, 256, 0, stream>>>(bufB, 26, X1);

  // -------- stage 2: M=6656, npg=26 -> k=13 --------
  wtrans_kernel<<<dim3(96, 32), dim3(32, 8), 0, stream>>>(g2W, WTH, WTL, DD, HC);
  mfma_gemm<<<dim3(24, 52), 256, 0, stream>>>(AXh, AXl, WTH, WTL, nullptr, bufA,
                                              6656, HC, DD, 6656,
                                              g2as, g2ad, ALSp, ALDp,
                                              nullptr, nullptr, nullptr, nullptr);
  gat_agg<<<dim3(256, 6), 256, 0, stream>>>(bufA, ALSp, ALDp, E0s, E0d, E0m, g2b,
                                            ATAh, ATAl, 26, 6656, V + HC, SCP);
  select_kernel<<<256, 256, 0, stream>>>(SCP, NRM, BP, 1, E0s, E0d, E0m, 26, 13,
                                         RMAP, SSEL, E1s, E1d, E1m);
  wtrans_kernel<<<dim3(32, 96), dim3(32, 8), 0, stream>>>(t2W, WTH, WTL, HC, DD);
  mfma_gemm<<<dim3(8, 26), 256, 0, stream>>>(ATAh, ATAl, WTH, WTL, t2b, bufB,
                                             3328, DD, HC, 6656,
                                             nullptr, nullptr, nullptr, nullptr,
                                             RMAP, SSEL, AXh, AXl);
  gap_kernel<<<256, 256, 0, stream>>>(bufB, 13, X2);

  // -------- stage 3: M=3328, npg=13 -> k=4 --------
  wtrans_kernel<<<dim3(96, 32), dim3(32, 8), 0, stream>>>(g3W, WTH, WTL, DD, HC);
  mfma_gemm<<<dim3(24, 26), 256, 0, stream>>>(AXh, AXl, WTH, WTL, nullptr, bufA,
                                              3328, HC, DD, 3328,
                                              g3as, g3ad, ALSp, ALDp,
                                              nullptr, nullptr, nullptr, nullptr);
  gat_agg<<<dim3(256, 6), 256, 0, stream>>>(bufA, ALSp, ALDp, E1s, E1d, E1m, g3b,
                                            ATAh, ATAl, 13, 3328, V + 2 * HC, SCP);
  select_kernel<<<256, 256, 0, stream>>>(SCP, NRM, BP, 2, E1s, E1d, E1m, 13, 4,
                                         RMAP, SSEL, E0s, E0d, E0m);
  wtrans_kernel<<<dim3(32, 96), dim3(32, 8), 0, stream>>>(t3W, WTH, WTL, HC, DD);
  mfma_gemm<<<dim3(8, 8), 256, 0, stream>>>(ATAh, ATAl, WTH, WTL, t3b, bufB,
                                            1024, DD, HC, 3328,
                                            nullptr, nullptr, nullptr, nullptr,
                                            RMAP, SSEL, nullptr, nullptr);
  gap_kernel<<<256, 256, 0, stream>>>(bufB, 4, X3);

  // -------- fused head --------
  head_kernel<<<dim3(4, 64), 256, 0, stream>>>(X1, X2, X3, l1W, l1b, l2W, HP);
  head2_kernel<<<1, 256, 0, stream>>>(HP, l2b, outp);
}